// Round 1
// baseline (788.519 us; speedup 1.0000x reference)
//
#include <hip/hip_runtime.h>

#define THREADS 256

static __device__ __forceinline__ float elu_f(float x) {
    return x > 0.f ? x : expm1f(x);
}

// ---------------- graph preprocessing ----------------

__global__ void k_init(float* __restrict__ deg, int* __restrict__ cnt, int N) {
    int i = blockIdx.x * blockDim.x + threadIdx.x;
    if (i < N) { deg[i] = 1.0f; cnt[i] = 0; }   // self-loop weight 1
}

__global__ void k_deg_cnt(const int* __restrict__ col, const float* __restrict__ w,
                          float* __restrict__ deg, int* __restrict__ cnt, int E) {
    int e = blockIdx.x * blockDim.x + threadIdx.x;
    if (e < E) {
        int c = col[e];
        atomicAdd(&deg[c], w[e]);
        atomicAdd(&cnt[c], 1);
    }
}

__global__ void k_dinv(const float* __restrict__ deg, float* __restrict__ dinv, int N) {
    int i = blockIdx.x * blockDim.x + threadIdx.x;
    if (i < N) {
        float d = deg[i];
        dinv[i] = d > 0.f ? rsqrtf(d) : 0.f;
    }
}

// single-block exclusive scan of cnt[N] -> off[N+1]; also copies into cur[]
__global__ void k_scan(const int* __restrict__ cnt, int* __restrict__ off,
                       int* __restrict__ cur, int N) {
    __shared__ int wsum[16];
    const int lane = threadIdx.x & 63;
    const int wid  = threadIdx.x >> 6;   // 16 waves of 64 in a 1024 block
    int carry = 0;
    for (int base = 0; base < N; base += 1024) {
        int i = base + threadIdx.x;
        int v = (i < N) ? cnt[i] : 0;
        int s = v;
        #pragma unroll
        for (int d = 1; d < 64; d <<= 1) {
            int t = __shfl_up(s, d);
            if (lane >= d) s += t;
        }
        if (lane == 63) wsum[wid] = s;
        __syncthreads();
        if (wid == 0) {
            int x = (lane < 16) ? wsum[lane] : 0;
            #pragma unroll
            for (int d = 1; d < 16; d <<= 1) {
                int t = __shfl_up(x, d);
                if (lane >= d) x += t;
            }
            if (lane < 16) wsum[lane] = x;
        }
        __syncthreads();
        int wbase = (wid > 0) ? wsum[wid - 1] : 0;
        int incl  = s + wbase + carry;
        int excl  = incl - v;
        if (i < N) { off[i] = excl; cur[i] = excl; }
        carry += wsum[15];
        __syncthreads();   // protect wsum before next chunk overwrites
    }
    if (threadIdx.x == 0) off[N] = carry;
}

__global__ void k_csr_fill(const int* __restrict__ row, const int* __restrict__ col,
                           const float* __restrict__ w, const float* __restrict__ dinv,
                           int* __restrict__ cur, int* __restrict__ src,
                           float* __restrict__ wgt, int E) {
    int e = blockIdx.x * blockDim.x + threadIdx.x;
    if (e < E) {
        int r = row[e], c = col[e];
        int pos = atomicAdd(&cur[c], 1);
        src[pos] = r;
        wgt[pos] = dinv[r] * w[e] * dinv[c];
    }
}

// ---------------- dense matmul: out[N,H] = X[N,K] @ W[K,H] (+bias)(+elu) ----------------
// W staged in LDS. 256 threads = 2 groups of 128; each group handles one node
// per iteration, thread j computes output column j (j < H).
__global__ void k_matmul(const float* __restrict__ X, const float* __restrict__ W,
                         const float* __restrict__ bias, float* __restrict__ out,
                         int N, int K, int H, int act) {
    extern __shared__ float Wl[];
    const int tid = threadIdx.x;
    const int KH = K * H;
    for (int i = tid; i < KH; i += THREADS) Wl[i] = W[i];
    __syncthreads();
    const int grp = tid >> 7;     // 0..1
    const int j   = tid & 127;    // output column
    if (j >= H) return;
    const float b = bias ? bias[j] : 0.f;
    for (int n = blockIdx.x * 2 + grp; n < N; n += gridDim.x * 2) {
        const float* xr = X + (size_t)n * K;
        float acc = b;
        for (int k = 0; k < K; k += 4) {
            float4 xv = *reinterpret_cast<const float4*>(xr + k);
            acc = fmaf(xv.x, Wl[(k + 0) * H + j], acc);
            acc = fmaf(xv.y, Wl[(k + 1) * H + j], acc);
            acc = fmaf(xv.z, Wl[(k + 2) * H + j], acc);
            acc = fmaf(xv.w, Wl[(k + 3) * H + j], acc);
        }
        if (act) acc = elu_f(acc);
        out[(size_t)n * H + j] = acc;
    }
}

// ---------------- aggregation: out = elu(seg_sum(norm*tmp[src]) + self + bias)(+addsrc) --
// thread = (node, float4 chunk of the 96 features); CSR gather, no atomics.
__global__ void k_aggregate(const float* __restrict__ tmp, const int* __restrict__ off,
                            const int* __restrict__ src, const float* __restrict__ wgt,
                            const float* __restrict__ dinv, const float* __restrict__ bias,
                            const float* __restrict__ addsrc, float* __restrict__ out, int N) {
    int t = blockIdx.x * blockDim.x + threadIdx.x;
    int n = t / 24;
    if (n >= N) return;
    int c = (t % 24) * 4;
    float di = dinv[n];
    float sn = di * di;    // self-loop norm = dinv * 1 * dinv
    float4 hv0 = *reinterpret_cast<const float4*>(tmp + (size_t)n * 96 + c);
    float ax = sn * hv0.x, ay = sn * hv0.y, az = sn * hv0.z, aw = sn * hv0.w;
    int e1 = off[n + 1];
    for (int e = off[n]; e < e1; ++e) {
        int s = src[e];
        float wv = wgt[e];
        float4 hv = *reinterpret_cast<const float4*>(tmp + (size_t)s * 96 + c);
        ax = fmaf(wv, hv.x, ax);
        ay = fmaf(wv, hv.y, ay);
        az = fmaf(wv, hv.z, az);
        aw = fmaf(wv, hv.w, aw);
    }
    float4 bv = *reinterpret_cast<const float4*>(bias + c);
    ax = elu_f(ax + bv.x);
    ay = elu_f(ay + bv.y);
    az = elu_f(az + bv.z);
    aw = elu_f(aw + bv.w);
    if (addsrc) {
        float4 rv = *reinterpret_cast<const float4*>(addsrc + (size_t)n * 96 + c);
        ax += rv.x; ay += rv.y; az += rv.z; aw += rv.w;
    }
    float4 o = make_float4(ax, ay, az, aw);
    *reinterpret_cast<float4*>(out + (size_t)n * 96 + c) = o;
}

// ---------------- final: logits = h @ W2 + b2; log_softmax ----------------
// one wave per node; lane = class (40 active of 64)
__global__ void k_lin2_lsm(const float* __restrict__ h, const float* __restrict__ W2,
                           const float* __restrict__ b2, float* __restrict__ out, int N) {
    __shared__ float Wl[96 * 40];
    for (int i = threadIdx.x; i < 96 * 40; i += THREADS) Wl[i] = W2[i];
    __syncthreads();
    const int lane = threadIdx.x & 63;
    const int wid  = threadIdx.x >> 6;   // 4 waves per block
    for (int n = blockIdx.x * 4 + wid; n < N; n += gridDim.x * 4) {
        const float* hr = h + (size_t)n * 96;
        float acc = 0.f;
        if (lane < 40) {
            acc = b2[lane];
            for (int k = 0; k < 96; ++k) acc = fmaf(hr[k], Wl[k * 40 + lane], acc);
        }
        float m = (lane < 40) ? acc : -INFINITY;
        #pragma unroll
        for (int d = 32; d > 0; d >>= 1) m = fmaxf(m, __shfl_xor(m, d));
        float ex = (lane < 40) ? expf(acc - m) : 0.f;
        float ssum = ex;
        #pragma unroll
        for (int d = 32; d > 0; d >>= 1) ssum += __shfl_xor(ssum, d);
        if (lane < 40) out[(size_t)n * 40 + lane] = acc - m - logf(ssum);
    }
}

// ---------------- launch ----------------

extern "C" void kernel_launch(void* const* d_in, const int* in_sizes, int n_in,
                              void* d_out, int out_size, void* d_ws, size_t ws_size,
                              hipStream_t stream) {
    const float* x   = (const float*)d_in[0];
    const int*   ei  = (const int*)d_in[1];
    const float* ew  = (const float*)d_in[2];
    const float* Wc1 = (const float*)d_in[3];
    const float* bc1 = (const float*)d_in[4];
    const float* Wc2 = (const float*)d_in[5];
    const float* bc2 = (const float*)d_in[6];
    const float* Wc3 = (const float*)d_in[7];
    const float* bc3 = (const float*)d_in[8];
    const float* Wl1 = (const float*)d_in[9];
    const float* bl1 = (const float*)d_in[10];
    const float* Wl2 = (const float*)d_in[11];
    const float* bl2 = (const float*)d_in[12];

    const int FIN = 128, HID = 96;
    const int N = in_sizes[0] / FIN;
    const int E = in_sizes[2];
    const int* row = ei;
    const int* col = ei + E;

    char* ws = (char*)d_ws;
    size_t o = 0;
    auto alloc = [&](size_t bytes) -> void* {
        void* p = ws + o;
        o += (bytes + 255) & ~(size_t)255;
        return p;
    };
    float* deg     = (float*)alloc((size_t)N * 4);
    float* dinv    = (float*)alloc((size_t)N * 4);
    int*   cnt     = (int*)  alloc((size_t)N * 4);
    int*   off     = (int*)  alloc((size_t)(N + 1) * 4);
    int*   cur     = (int*)  alloc((size_t)N * 4);
    int*   csr_src = (int*)  alloc((size_t)E * 4);
    float* csr_w   = (float*)alloc((size_t)E * 4);
    float* A       = (float*)alloc((size_t)N * HID * 4);   // matmul output / conv messages
    float* B       = (float*)alloc((size_t)N * HID * 4);   // x1 (residual)
    float* C       = (float*)alloc((size_t)N * HID * 4);   // running h

    const int gN = (N + THREADS - 1) / THREADS;
    const int gE = (E + THREADS - 1) / THREADS;
    const int gAgg = (N * 24 + THREADS - 1) / THREADS;

    // graph prep
    k_init<<<gN, THREADS, 0, stream>>>(deg, cnt, N);
    k_deg_cnt<<<gE, THREADS, 0, stream>>>(col, ew, deg, cnt, E);
    k_dinv<<<gN, THREADS, 0, stream>>>(deg, dinv, N);
    k_scan<<<1, 1024, 0, stream>>>(cnt, off, cur, N);
    k_csr_fill<<<gE, THREADS, 0, stream>>>(row, col, ew, dinv, cur, csr_src, csr_w, E);

    // conv1: x1 = elu(agg(x@Wc1) + b1)  -> B
    k_matmul<<<2048, THREADS, FIN * HID * 4, stream>>>(x, Wc1, nullptr, A, N, FIN, HID, 0);
    k_aggregate<<<gAgg, THREADS, 0, stream>>>(A, off, csr_src, csr_w, dinv, bc1, nullptr, B, N);

    // lin1: h = elu(x@Wl1 + bl1) -> C
    k_matmul<<<2048, THREADS, FIN * HID * 4, stream>>>(x, Wl1, bl1, C, N, FIN, HID, 1);

    // conv2: h = elu(agg(h@Wc2) + b2) -> C
    k_matmul<<<2048, THREADS, HID * HID * 4, stream>>>(C, Wc2, nullptr, A, N, HID, HID, 0);
    k_aggregate<<<gAgg, THREADS, 0, stream>>>(A, off, csr_src, csr_w, dinv, bc2, nullptr, C, N);

    // conv3: h = x1 + elu(agg(h@Wc3) + b3) -> C
    k_matmul<<<2048, THREADS, HID * HID * 4, stream>>>(C, Wc3, nullptr, A, N, HID, HID, 0);
    k_aggregate<<<gAgg, THREADS, 0, stream>>>(A, off, csr_src, csr_w, dinv, bc3, B, C, N);

    // lin2 + log_softmax -> d_out
    k_lin2_lsm<<<2048, THREADS, 0, stream>>>(C, Wl2, bl2, (float*)d_out, N);
}

// Round 2
// 730.011 us; speedup vs baseline: 1.0801x; 1.0801x over previous
//
#include <hip/hip_runtime.h>

#define THREADS 256
#define MMB 192   // matmul threads per block: 2 groups x 96 cols

static __device__ __forceinline__ float elu_f(float x) {
    return x > 0.f ? x : expm1f(x);
}

// ---------------- graph preprocessing ----------------

__global__ void k_init(float* __restrict__ deg, int* __restrict__ cnt, int N) {
    int i = blockIdx.x * blockDim.x + threadIdx.x;
    if (i < N) { deg[i] = 1.0f; cnt[i] = 0; }   // self-loop weight 1
}

__global__ void k_deg_cnt(const int* __restrict__ col, const float* __restrict__ w,
                          float* __restrict__ deg, int* __restrict__ cnt, int E) {
    int e = blockIdx.x * blockDim.x + threadIdx.x;
    if (e < E) {
        int c = col[e];
        atomicAdd(&deg[c], w[e]);
        atomicAdd(&cnt[c], 1);
    }
}

__global__ void k_dinv(const float* __restrict__ deg, float* __restrict__ dinv, int N) {
    int i = blockIdx.x * blockDim.x + threadIdx.x;
    if (i < N) {
        float d = deg[i];
        dinv[i] = d > 0.f ? rsqrtf(d) : 0.f;
    }
}

// single-block exclusive scan of cnt[N] -> off[N+1]; also copies into cur[]
__global__ void k_scan(const int* __restrict__ cnt, int* __restrict__ off,
                       int* __restrict__ cur, int N) {
    __shared__ int wsum[16];
    const int lane = threadIdx.x & 63;
    const int wid  = threadIdx.x >> 6;   // 16 waves of 64 in a 1024 block
    int carry = 0;
    for (int base = 0; base < N; base += 1024) {
        int i = base + threadIdx.x;
        int v = (i < N) ? cnt[i] : 0;
        int s = v;
        #pragma unroll
        for (int d = 1; d < 64; d <<= 1) {
            int t = __shfl_up(s, d);
            if (lane >= d) s += t;
        }
        if (lane == 63) wsum[wid] = s;
        __syncthreads();
        if (wid == 0) {
            int x = (lane < 16) ? wsum[lane] : 0;
            #pragma unroll
            for (int d = 1; d < 16; d <<= 1) {
                int t = __shfl_up(x, d);
                if (lane >= d) x += t;
            }
            if (lane < 16) wsum[lane] = x;
        }
        __syncthreads();
        int wbase = (wid > 0) ? wsum[wid - 1] : 0;
        int incl  = s + wbase + carry;
        int excl  = incl - v;
        if (i < N) { off[i] = excl; cur[i] = excl; }
        carry += wsum[15];
        __syncthreads();   // protect wsum before next chunk overwrites
    }
    if (threadIdx.x == 0) off[N] = carry;
}

__global__ void k_csr_fill(const int* __restrict__ row, const int* __restrict__ col,
                           const float* __restrict__ w, const float* __restrict__ dinv,
                           int* __restrict__ cur, int* __restrict__ src,
                           float* __restrict__ wgt, int E) {
    int e = blockIdx.x * blockDim.x + threadIdx.x;
    if (e < E) {
        int r = row[e], c = col[e];
        int pos = atomicAdd(&cur[c], 1);
        src[pos] = r;
        wgt[pos] = dinv[r] * w[e] * dinv[c];
    }
}

// ---------------- dense matmul: out[N,96] = X[N,K] @ W[K,96] (+bias)(+elu) ----------------
// W staged in LDS. 192 threads = 2 groups x 96 columns. Each group processes 8
// nodes per iteration: each W value loaded from LDS once is reused across the
// 8 node accumulators (LDS bytes/FMA drops 8x vs one-node-per-thread).
// x rows are read with uniform-address float4 loads (L1 broadcast, read once).
__global__ void k_matmul(const float* __restrict__ X, const float* __restrict__ W,
                         const float* __restrict__ bias, float* __restrict__ out,
                         int N, int K, int act) {
    extern __shared__ float Wl[];
    const int tid = threadIdx.x;
    const int K96 = K * 96;
    for (int i = tid; i < K96; i += MMB) Wl[i] = W[i];
    __syncthreads();
    const int grp = tid / 96;        // 0 or 1
    const int j   = tid % 96;        // output column
    const float b = bias ? bias[j] : 0.f;
    const int stride = gridDim.x * 16;
    for (int n0 = blockIdx.x * 16 + grp * 8; n0 < N; n0 += stride) {
        const float* xr = X + (size_t)n0 * K;
        float acc[8];
        #pragma unroll
        for (int t = 0; t < 8; ++t) acc[t] = b;
        if (n0 + 8 <= N) {
            for (int k = 0; k < K; k += 4) {
                const float w0 = Wl[(k + 0) * 96 + j];
                const float w1 = Wl[(k + 1) * 96 + j];
                const float w2 = Wl[(k + 2) * 96 + j];
                const float w3 = Wl[(k + 3) * 96 + j];
                #pragma unroll
                for (int t = 0; t < 8; ++t) {
                    float4 xv = *reinterpret_cast<const float4*>(xr + (size_t)t * K + k);
                    acc[t] = fmaf(xv.w, w3, fmaf(xv.z, w2, fmaf(xv.y, w1, fmaf(xv.x, w0, acc[t]))));
                }
            }
            #pragma unroll
            for (int t = 0; t < 8; ++t) {
                float a = acc[t];
                if (act) a = elu_f(a);
                out[(size_t)(n0 + t) * 96 + j] = a;
            }
        } else {
            const int rem = N - n0;
            for (int k = 0; k < K; k += 4) {
                const float w0 = Wl[(k + 0) * 96 + j];
                const float w1 = Wl[(k + 1) * 96 + j];
                const float w2 = Wl[(k + 2) * 96 + j];
                const float w3 = Wl[(k + 3) * 96 + j];
                for (int t = 0; t < rem; ++t) {
                    float4 xv = *reinterpret_cast<const float4*>(xr + (size_t)t * K + k);
                    acc[t] = fmaf(xv.w, w3, fmaf(xv.z, w2, fmaf(xv.y, w1, fmaf(xv.x, w0, acc[t]))));
                }
            }
            for (int t = 0; t < rem; ++t) {
                float a = acc[t];
                if (act) a = elu_f(a);
                out[(size_t)(n0 + t) * 96 + j] = a;
            }
        }
    }
}

// ---------------- aggregation: out = elu(seg_sum(norm*tmp[src]) + self + bias)(+addsrc) --
// thread = (node, float4 chunk of the 96 features); CSR gather, no atomics.
__global__ void k_aggregate(const float* __restrict__ tmp, const int* __restrict__ off,
                            const int* __restrict__ src, const float* __restrict__ wgt,
                            const float* __restrict__ dinv, const float* __restrict__ bias,
                            const float* __restrict__ addsrc, float* __restrict__ out, int N) {
    int t = blockIdx.x * blockDim.x + threadIdx.x;
    int n = t / 24;
    if (n >= N) return;
    int c = (t % 24) * 4;
    float di = dinv[n];
    float sn = di * di;    // self-loop norm = dinv * 1 * dinv
    float4 hv0 = *reinterpret_cast<const float4*>(tmp + (size_t)n * 96 + c);
    float ax = sn * hv0.x, ay = sn * hv0.y, az = sn * hv0.z, aw = sn * hv0.w;
    int e1 = off[n + 1];
    for (int e = off[n]; e < e1; ++e) {
        int s = src[e];
        float wv = wgt[e];
        float4 hv = *reinterpret_cast<const float4*>(tmp + (size_t)s * 96 + c);
        ax = fmaf(wv, hv.x, ax);
        ay = fmaf(wv, hv.y, ay);
        az = fmaf(wv, hv.z, az);
        aw = fmaf(wv, hv.w, aw);
    }
    float4 bv = *reinterpret_cast<const float4*>(bias + c);
    ax = elu_f(ax + bv.x);
    ay = elu_f(ay + bv.y);
    az = elu_f(az + bv.z);
    aw = elu_f(aw + bv.w);
    if (addsrc) {
        float4 rv = *reinterpret_cast<const float4*>(addsrc + (size_t)n * 96 + c);
        ax += rv.x; ay += rv.y; az += rv.z; aw += rv.w;
    }
    float4 o = make_float4(ax, ay, az, aw);
    *reinterpret_cast<float4*>(out + (size_t)n * 96 + c) = o;
}

// ---------------- final: logits = h @ W2 + b2; log_softmax ----------------
// one wave per node; lane = class (40 active of 64)
__global__ void k_lin2_lsm(const float* __restrict__ h, const float* __restrict__ W2,
                           const float* __restrict__ b2, float* __restrict__ out, int N) {
    __shared__ float Wl[96 * 40];
    for (int i = threadIdx.x; i < 96 * 40; i += THREADS) Wl[i] = W2[i];
    __syncthreads();
    const int lane = threadIdx.x & 63;
    const int wid  = threadIdx.x >> 6;   // 4 waves per block
    for (int n = blockIdx.x * 4 + wid; n < N; n += gridDim.x * 4) {
        const float* hr = h + (size_t)n * 96;
        float acc = 0.f;
        if (lane < 40) {
            acc = b2[lane];
            for (int k = 0; k < 96; ++k) acc = fmaf(hr[k], Wl[k * 40 + lane], acc);
        }
        float m = (lane < 40) ? acc : -INFINITY;
        #pragma unroll
        for (int d = 32; d > 0; d >>= 1) m = fmaxf(m, __shfl_xor(m, d));
        float ex = (lane < 40) ? expf(acc - m) : 0.f;
        float ssum = ex;
        #pragma unroll
        for (int d = 32; d > 0; d >>= 1) ssum += __shfl_xor(ssum, d);
        if (lane < 40) out[(size_t)n * 40 + lane] = acc - m - logf(ssum);
    }
}

// ---------------- launch ----------------

extern "C" void kernel_launch(void* const* d_in, const int* in_sizes, int n_in,
                              void* d_out, int out_size, void* d_ws, size_t ws_size,
                              hipStream_t stream) {
    const float* x   = (const float*)d_in[0];
    const int*   ei  = (const int*)d_in[1];
    const float* ew  = (const float*)d_in[2];
    const float* Wc1 = (const float*)d_in[3];
    const float* bc1 = (const float*)d_in[4];
    const float* Wc2 = (const float*)d_in[5];
    const float* bc2 = (const float*)d_in[6];
    const float* Wc3 = (const float*)d_in[7];
    const float* bc3 = (const float*)d_in[8];
    const float* Wl1 = (const float*)d_in[9];
    const float* bl1 = (const float*)d_in[10];
    const float* Wl2 = (const float*)d_in[11];
    const float* bl2 = (const float*)d_in[12];

    const int FIN = 128, HID = 96;
    const int N = in_sizes[0] / FIN;
    const int E = in_sizes[2];
    const int* row = ei;
    const int* col = ei + E;

    char* ws = (char*)d_ws;
    size_t o = 0;
    auto alloc = [&](size_t bytes) -> void* {
        void* p = ws + o;
        o += (bytes + 255) & ~(size_t)255;
        return p;
    };
    float* deg     = (float*)alloc((size_t)N * 4);
    float* dinv    = (float*)alloc((size_t)N * 4);
    int*   cnt     = (int*)  alloc((size_t)N * 4);
    int*   off     = (int*)  alloc((size_t)(N + 1) * 4);
    int*   cur     = (int*)  alloc((size_t)N * 4);
    int*   csr_src = (int*)  alloc((size_t)E * 4);
    float* csr_w   = (float*)alloc((size_t)E * 4);
    float* A       = (float*)alloc((size_t)N * HID * 4);   // matmul output / conv messages
    float* B       = (float*)alloc((size_t)N * HID * 4);   // x1 (residual)
    float* C       = (float*)alloc((size_t)N * HID * 4);   // running h

    const int gN = (N + THREADS - 1) / THREADS;
    const int gE = (E + THREADS - 1) / THREADS;
    const int gAgg = (N * 24 + THREADS - 1) / THREADS;
    const int gMM = 1024;

    // graph prep
    k_init<<<gN, THREADS, 0, stream>>>(deg, cnt, N);
    k_deg_cnt<<<gE, THREADS, 0, stream>>>(col, ew, deg, cnt, E);
    k_dinv<<<gN, THREADS, 0, stream>>>(deg, dinv, N);
    k_scan<<<1, 1024, 0, stream>>>(cnt, off, cur, N);
    k_csr_fill<<<gE, THREADS, 0, stream>>>(row, col, ew, dinv, cur, csr_src, csr_w, E);

    // conv1: x1 = elu(agg(x@Wc1) + b1)  -> B
    k_matmul<<<gMM, MMB, FIN * HID * 4, stream>>>(x, Wc1, nullptr, A, N, FIN, 0);
    k_aggregate<<<gAgg, THREADS, 0, stream>>>(A, off, csr_src, csr_w, dinv, bc1, nullptr, B, N);

    // lin1: h = elu(x@Wl1 + bl1) -> C
    k_matmul<<<gMM, MMB, FIN * HID * 4, stream>>>(x, Wl1, bl1, C, N, FIN, 1);

    // conv2: h = elu(agg(h@Wc2) + b2) -> C
    k_matmul<<<gMM, MMB, HID * HID * 4, stream>>>(C, Wc2, nullptr, A, N, HID, 0);
    k_aggregate<<<gAgg, THREADS, 0, stream>>>(A, off, csr_src, csr_w, dinv, bc2, nullptr, C, N);

    // conv3: h = x1 + elu(agg(h@Wc3) + b3) -> C
    k_matmul<<<gMM, MMB, HID * HID * 4, stream>>>(C, Wc3, nullptr, A, N, HID, 0);
    k_aggregate<<<gAgg, THREADS, 0, stream>>>(A, off, csr_src, csr_w, dinv, bc3, B, C, N);

    // lin2 + log_softmax -> d_out
    k_lin2_lsm<<<2048, THREADS, 0, stream>>>(C, Wl2, bl2, (float*)d_out, N);
}

// Round 3
// 522.202 us; speedup vs baseline: 1.5100x; 1.3979x over previous
//
#include <hip/hip_runtime.h>

#define THREADS 256

static __device__ __forceinline__ float elu_f(float x) {
    return x > 0.f ? x : expm1f(x);
}

// ---------------- graph preprocessing ----------------

__global__ void k_init(float* __restrict__ deg, int* __restrict__ cnt, int N) {
    int i = blockIdx.x * blockDim.x + threadIdx.x;
    if (i < N) { deg[i] = 1.0f; cnt[i] = 0; }   // self-loop weight 1
}

__global__ void k_deg_cnt(const int* __restrict__ col, const float* __restrict__ w,
                          float* __restrict__ deg, int* __restrict__ cnt, int E) {
    int e = blockIdx.x * blockDim.x + threadIdx.x;
    if (e < E) {
        int c = col[e];
        atomicAdd(&deg[c], w[e]);
        atomicAdd(&cnt[c], 1);
    }
}

__global__ void k_dinv(const float* __restrict__ deg, float* __restrict__ dinv, int N) {
    int i = blockIdx.x * blockDim.x + threadIdx.x;
    if (i < N) {
        float d = deg[i];
        dinv[i] = d > 0.f ? rsqrtf(d) : 0.f;
    }
}

// single-block exclusive scan of cnt[N] -> off[N+1]; also copies into cur[]
__global__ void k_scan(const int* __restrict__ cnt, int* __restrict__ off,
                       int* __restrict__ cur, int N) {
    __shared__ int wsum[16];
    const int lane = threadIdx.x & 63;
    const int wid  = threadIdx.x >> 6;   // 16 waves of 64 in a 1024 block
    int carry = 0;
    for (int base = 0; base < N; base += 1024) {
        int i = base + threadIdx.x;
        int v = (i < N) ? cnt[i] : 0;
        int s = v;
        #pragma unroll
        for (int d = 1; d < 64; d <<= 1) {
            int t = __shfl_up(s, d);
            if (lane >= d) s += t;
        }
        if (lane == 63) wsum[wid] = s;
        __syncthreads();
        if (wid == 0) {
            int x = (lane < 16) ? wsum[lane] : 0;
            #pragma unroll
            for (int d = 1; d < 16; d <<= 1) {
                int t = __shfl_up(x, d);
                if (lane >= d) x += t;
            }
            if (lane < 16) wsum[lane] = x;
        }
        __syncthreads();
        int wbase = (wid > 0) ? wsum[wid - 1] : 0;
        int incl  = s + wbase + carry;
        int excl  = incl - v;
        if (i < N) { off[i] = excl; cur[i] = excl; }
        carry += wsum[15];
        __syncthreads();   // protect wsum before next chunk overwrites
    }
    if (threadIdx.x == 0) off[N] = carry;
}

__global__ void k_csr_fill(const int* __restrict__ row, const int* __restrict__ col,
                           const float* __restrict__ w, const float* __restrict__ dinv,
                           int* __restrict__ cur, int* __restrict__ src,
                           float* __restrict__ wgt, int E) {
    int e = blockIdx.x * blockDim.x + threadIdx.x;
    if (e < E) {
        int r = row[e], c = col[e];
        int pos = atomicAdd(&cur[c], 1);
        src[pos] = r;
        wgt[pos] = dinv[r] * w[e] * dinv[c];
    }
}

// ---------------- dense GEMM: out[N,96] = X[N,K] @ W[K,96] (+bias)(+elu) ----------------
// Classic double-buffered LDS tiling. BM=64, BN=96 (full), BK=16.
// 256 threads: compute map (tn=tid&7 -> 8 rows each, tj=tid>>3 -> 3 cols each).
// Xs stored transposed [k][n] so compute reads are 2x ds_read_b128 per thread per k.
// Staging map: sn=tid&63 (row), skq=tid>>6 (k-quarter, float4).
#define GM_BM 64
#define GM_BK 16

__global__ __launch_bounds__(256) void
k_gemm(const float* __restrict__ X, const float* __restrict__ W,
       const float* __restrict__ bias, float* __restrict__ out,
       int N, int K, int act) {
    __shared__ float Xs[2][GM_BK][GM_BM];
    __shared__ float Ws[2][GM_BK][96];

    const int tid = threadIdx.x;
    const int tn  = tid & 7;     // row group: rows tn*8 .. tn*8+7
    const int tj  = tid >> 3;    // col group: cols tj*3 .. tj*3+2
    const int sn  = tid & 63;    // staging row
    const int skq = tid >> 6;    // staging k-quarter
    const int n0  = blockIdx.x * GM_BM;
    const int KT  = K / GM_BK;

    float acc[8][3];
    const float b0 = bias ? bias[tj * 3 + 0] : 0.f;
    const float b1 = bias ? bias[tj * 3 + 1] : 0.f;
    const float b2 = bias ? bias[tj * 3 + 2] : 0.f;
    #pragma unroll
    for (int r = 0; r < 8; ++r) { acc[r][0] = b0; acc[r][1] = b1; acc[r][2] = b2; }

    const int nload = (n0 + sn < N) ? (n0 + sn) : (N - 1);  // clamp tail reads
    const float* xrow = X + (size_t)nload * K;

    // prologue: stage tile 0 into buffer 0
    {
        float4 xv = *reinterpret_cast<const float4*>(xrow + skq * 4);
        Xs[0][skq * 4 + 0][sn] = xv.x;
        Xs[0][skq * 4 + 1][sn] = xv.y;
        Xs[0][skq * 4 + 2][sn] = xv.z;
        Xs[0][skq * 4 + 3][sn] = xv.w;
        #pragma unroll
        for (int p = 0; p < 6; ++p) {
            int i = tid + p * 256;           // 16*96 = 1536 contiguous floats
            (&Ws[0][0][0])[i] = W[i];
        }
    }
    __syncthreads();

    int cur = 0;
    for (int kt = 0; kt < KT; ++kt) {
        const bool more = (kt + 1 < KT);
        float4 xnext;
        float wnext[6];
        if (more) {
            const int k0n = (kt + 1) * GM_BK;
            xnext = *reinterpret_cast<const float4*>(xrow + k0n + skq * 4);
            #pragma unroll
            for (int p = 0; p < 6; ++p)
                wnext[p] = W[k0n * 96 + tid + p * 256];
        }
        #pragma unroll
        for (int ki = 0; ki < GM_BK; ++ki) {
            const float4 xa = *reinterpret_cast<const float4*>(&Xs[cur][ki][tn * 8]);
            const float4 xb = *reinterpret_cast<const float4*>(&Xs[cur][ki][tn * 8 + 4]);
            const float w0 = Ws[cur][ki][tj * 3 + 0];
            const float w1 = Ws[cur][ki][tj * 3 + 1];
            const float w2 = Ws[cur][ki][tj * 3 + 2];
            acc[0][0] = fmaf(xa.x, w0, acc[0][0]);
            acc[0][1] = fmaf(xa.x, w1, acc[0][1]);
            acc[0][2] = fmaf(xa.x, w2, acc[0][2]);
            acc[1][0] = fmaf(xa.y, w0, acc[1][0]);
            acc[1][1] = fmaf(xa.y, w1, acc[1][1]);
            acc[1][2] = fmaf(xa.y, w2, acc[1][2]);
            acc[2][0] = fmaf(xa.z, w0, acc[2][0]);
            acc[2][1] = fmaf(xa.z, w1, acc[2][1]);
            acc[2][2] = fmaf(xa.z, w2, acc[2][2]);
            acc[3][0] = fmaf(xa.w, w0, acc[3][0]);
            acc[3][1] = fmaf(xa.w, w1, acc[3][1]);
            acc[3][2] = fmaf(xa.w, w2, acc[3][2]);
            acc[4][0] = fmaf(xb.x, w0, acc[4][0]);
            acc[4][1] = fmaf(xb.x, w1, acc[4][1]);
            acc[4][2] = fmaf(xb.x, w2, acc[4][2]);
            acc[5][0] = fmaf(xb.y, w0, acc[5][0]);
            acc[5][1] = fmaf(xb.y, w1, acc[5][1]);
            acc[5][2] = fmaf(xb.y, w2, acc[5][2]);
            acc[6][0] = fmaf(xb.z, w0, acc[6][0]);
            acc[6][1] = fmaf(xb.z, w1, acc[6][1]);
            acc[6][2] = fmaf(xb.z, w2, acc[6][2]);
            acc[7][0] = fmaf(xb.w, w0, acc[7][0]);
            acc[7][1] = fmaf(xb.w, w1, acc[7][1]);
            acc[7][2] = fmaf(xb.w, w2, acc[7][2]);
        }
        if (more) {
            const int nb = cur ^ 1;
            Xs[nb][skq * 4 + 0][sn] = xnext.x;
            Xs[nb][skq * 4 + 1][sn] = xnext.y;
            Xs[nb][skq * 4 + 2][sn] = xnext.z;
            Xs[nb][skq * 4 + 3][sn] = xnext.w;
            #pragma unroll
            for (int p = 0; p < 6; ++p)
                (&Ws[nb][0][0])[tid + p * 256] = wnext[p];
            cur = nb;
        }
        __syncthreads();
    }

    // epilogue
    #pragma unroll
    for (int r = 0; r < 8; ++r) {
        const int n = n0 + tn * 8 + r;
        if (n < N) {
            float a0 = acc[r][0], a1 = acc[r][1], a2 = acc[r][2];
            if (act) { a0 = elu_f(a0); a1 = elu_f(a1); a2 = elu_f(a2); }
            float* op = out + (size_t)n * 96 + tj * 3;
            op[0] = a0; op[1] = a1; op[2] = a2;
        }
    }
}

// ---------------- aggregation: out = elu(seg_sum(norm*tmp[src]) + self + bias)(+addsrc) --
// thread = (node, float4 chunk of the 96 features); CSR gather, no atomics.
__global__ void k_aggregate(const float* __restrict__ tmp, const int* __restrict__ off,
                            const int* __restrict__ src, const float* __restrict__ wgt,
                            const float* __restrict__ dinv, const float* __restrict__ bias,
                            const float* __restrict__ addsrc, float* __restrict__ out, int N) {
    int t = blockIdx.x * blockDim.x + threadIdx.x;
    int n = t / 24;
    if (n >= N) return;
    int c = (t % 24) * 4;
    float di = dinv[n];
    float sn = di * di;    // self-loop norm = dinv * 1 * dinv
    float4 hv0 = *reinterpret_cast<const float4*>(tmp + (size_t)n * 96 + c);
    float ax = sn * hv0.x, ay = sn * hv0.y, az = sn * hv0.z, aw = sn * hv0.w;
    int e1 = off[n + 1];
    for (int e = off[n]; e < e1; ++e) {
        int s = src[e];
        float wv = wgt[e];
        float4 hv = *reinterpret_cast<const float4*>(tmp + (size_t)s * 96 + c);
        ax = fmaf(wv, hv.x, ax);
        ay = fmaf(wv, hv.y, ay);
        az = fmaf(wv, hv.z, az);
        aw = fmaf(wv, hv.w, aw);
    }
    float4 bv = *reinterpret_cast<const float4*>(bias + c);
    ax = elu_f(ax + bv.x);
    ay = elu_f(ay + bv.y);
    az = elu_f(az + bv.z);
    aw = elu_f(aw + bv.w);
    if (addsrc) {
        float4 rv = *reinterpret_cast<const float4*>(addsrc + (size_t)n * 96 + c);
        ax += rv.x; ay += rv.y; az += rv.z; aw += rv.w;
    }
    float4 o = make_float4(ax, ay, az, aw);
    *reinterpret_cast<float4*>(out + (size_t)n * 96 + c) = o;
}

// ---------------- final: logits = h @ W2 + b2; log_softmax ----------------
// one wave per node; lane = class (40 active of 64)
__global__ void k_lin2_lsm(const float* __restrict__ h, const float* __restrict__ W2,
                           const float* __restrict__ b2, float* __restrict__ out, int N) {
    __shared__ float Wl[96 * 40];
    for (int i = threadIdx.x; i < 96 * 40; i += THREADS) Wl[i] = W2[i];
    __syncthreads();
    const int lane = threadIdx.x & 63;
    const int wid  = threadIdx.x >> 6;   // 4 waves per block
    for (int n = blockIdx.x * 4 + wid; n < N; n += gridDim.x * 4) {
        const float* hr = h + (size_t)n * 96;
        float acc = 0.f;
        if (lane < 40) {
            acc = b2[lane];
            for (int k = 0; k < 96; ++k) acc = fmaf(hr[k], Wl[k * 40 + lane], acc);
        }
        float m = (lane < 40) ? acc : -INFINITY;
        #pragma unroll
        for (int d = 32; d > 0; d >>= 1) m = fmaxf(m, __shfl_xor(m, d));
        float ex = (lane < 40) ? expf(acc - m) : 0.f;
        float ssum = ex;
        #pragma unroll
        for (int d = 32; d > 0; d >>= 1) ssum += __shfl_xor(ssum, d);
        if (lane < 40) out[(size_t)n * 40 + lane] = acc - m - logf(ssum);
    }
}

// ---------------- launch ----------------

extern "C" void kernel_launch(void* const* d_in, const int* in_sizes, int n_in,
                              void* d_out, int out_size, void* d_ws, size_t ws_size,
                              hipStream_t stream) {
    const float* x   = (const float*)d_in[0];
    const int*   ei  = (const int*)d_in[1];
    const float* ew  = (const float*)d_in[2];
    const float* Wc1 = (const float*)d_in[3];
    const float* bc1 = (const float*)d_in[4];
    const float* Wc2 = (const float*)d_in[5];
    const float* bc2 = (const float*)d_in[6];
    const float* Wc3 = (const float*)d_in[7];
    const float* bc3 = (const float*)d_in[8];
    const float* Wl1 = (const float*)d_in[9];
    const float* bl1 = (const float*)d_in[10];
    const float* Wl2 = (const float*)d_in[11];
    const float* bl2 = (const float*)d_in[12];

    const int FIN = 128, HID = 96;
    const int N = in_sizes[0] / FIN;
    const int E = in_sizes[2];
    const int* row = ei;
    const int* col = ei + E;

    char* ws = (char*)d_ws;
    size_t o = 0;
    auto alloc = [&](size_t bytes) -> void* {
        void* p = ws + o;
        o += (bytes + 255) & ~(size_t)255;
        return p;
    };
    float* deg     = (float*)alloc((size_t)N * 4);
    float* dinv    = (float*)alloc((size_t)N * 4);
    int*   cnt     = (int*)  alloc((size_t)N * 4);
    int*   off     = (int*)  alloc((size_t)(N + 1) * 4);
    int*   cur     = (int*)  alloc((size_t)N * 4);
    int*   csr_src = (int*)  alloc((size_t)E * 4);
    float* csr_w   = (float*)alloc((size_t)E * 4);
    float* A       = (float*)alloc((size_t)N * HID * 4);   // matmul output / conv messages
    float* B       = (float*)alloc((size_t)N * HID * 4);   // x1 (residual)
    float* C       = (float*)alloc((size_t)N * HID * 4);   // running h

    const int gN = (N + THREADS - 1) / THREADS;
    const int gE = (E + THREADS - 1) / THREADS;
    const int gAgg = (N * 24 + THREADS - 1) / THREADS;
    const int gGM = (N + GM_BM - 1) / GM_BM;

    // graph prep
    k_init<<<gN, THREADS, 0, stream>>>(deg, cnt, N);
    k_deg_cnt<<<gE, THREADS, 0, stream>>>(col, ew, deg, cnt, E);
    k_dinv<<<gN, THREADS, 0, stream>>>(deg, dinv, N);
    k_scan<<<1, 1024, 0, stream>>>(cnt, off, cur, N);
    k_csr_fill<<<gE, THREADS, 0, stream>>>(row, col, ew, dinv, cur, csr_src, csr_w, E);

    // conv1: x1 = elu(agg(x@Wc1) + b1)  -> B
    k_gemm<<<gGM, 256, 0, stream>>>(x, Wc1, nullptr, A, N, FIN, 0);
    k_aggregate<<<gAgg, THREADS, 0, stream>>>(A, off, csr_src, csr_w, dinv, bc1, nullptr, B, N);

    // lin1: h = elu(x@Wl1 + bl1) -> C
    k_gemm<<<gGM, 256, 0, stream>>>(x, Wl1, bl1, C, N, FIN, 1);

    // conv2: h = elu(agg(h@Wc2) + b2) -> C
    k_gemm<<<gGM, 256, 0, stream>>>(C, Wc2, nullptr, A, N, HID, 0);
    k_aggregate<<<gAgg, THREADS, 0, stream>>>(A, off, csr_src, csr_w, dinv, bc2, nullptr, C, N);

    // conv3: h = x1 + elu(agg(h@Wc3) + b3) -> C
    k_gemm<<<gGM, 256, 0, stream>>>(C, Wc3, nullptr, A, N, HID, 0);
    k_aggregate<<<gAgg, THREADS, 0, stream>>>(A, off, csr_src, csr_w, dinv, bc3, B, C, N);

    // lin2 + log_softmax -> d_out
    k_lin2_lsm<<<2048, THREADS, 0, stream>>>(C, Wl2, bl2, (float*)d_out, N);
}

// Round 4
// 443.888 us; speedup vs baseline: 1.7764x; 1.1764x over previous
//
#include <hip/hip_runtime.h>
#include <hip/hip_bf16.h>

#define THREADS 256

static __device__ __forceinline__ float elu_f(float x) {
    return x > 0.f ? x : expm1f(x);
}

// ---------------- graph preprocessing ----------------

__global__ void k_zero(int* __restrict__ cnt, int N) {
    int i = blockIdx.x * blockDim.x + threadIdx.x;
    if (i < N) cnt[i] = 0;
}

__global__ void k_count(const int* __restrict__ col, int* __restrict__ cnt, int E) {
    int e = blockIdx.x * blockDim.x + threadIdx.x;
    if (e < E) atomicAdd(&cnt[col[e]], 1);
}

// single-block exclusive scan of cnt[N] -> off[N+1]; also copies into cur[]
__global__ void k_scan(const int* __restrict__ cnt, int* __restrict__ off,
                       int* __restrict__ cur, int N) {
    __shared__ int wsum[16];
    const int lane = threadIdx.x & 63;
    const int wid  = threadIdx.x >> 6;   // 16 waves of 64 in a 1024 block
    int carry = 0;
    for (int base = 0; base < N; base += 1024) {
        int i = base + threadIdx.x;
        int v = (i < N) ? cnt[i] : 0;
        int s = v;
        #pragma unroll
        for (int d = 1; d < 64; d <<= 1) {
            int t = __shfl_up(s, d);
            if (lane >= d) s += t;
        }
        if (lane == 63) wsum[wid] = s;
        __syncthreads();
        if (wid == 0) {
            int x = (lane < 16) ? wsum[lane] : 0;
            #pragma unroll
            for (int d = 1; d < 16; d <<= 1) {
                int t = __shfl_up(x, d);
                if (lane >= d) x += t;
            }
            if (lane < 16) wsum[lane] = x;
        }
        __syncthreads();
        int wbase = (wid > 0) ? wsum[wid - 1] : 0;
        int incl  = s + wbase + carry;
        int excl  = incl - v;
        if (i < N) { off[i] = excl; cur[i] = excl; }
        carry += wsum[15];
        __syncthreads();   // protect wsum before next chunk overwrites
    }
    if (threadIdx.x == 0) off[N] = carry;
}

// fill CSR as packed (src, raw_weight) pairs: ONE 8B scattered write per edge
__global__ void k_fill(const int* __restrict__ row, const int* __restrict__ col,
                       const float* __restrict__ w, int* __restrict__ cur,
                       int2* __restrict__ pairs, int E) {
    int e = blockIdx.x * blockDim.x + threadIdx.x;
    if (e < E) {
        int c = col[e];
        int pos = atomicAdd(&cur[c], 1);
        pairs[pos] = make_int2(row[e], __float_as_int(w[e]));
    }
}

// deg[n] = 1 + sum of raw weights over segment (sequential reads, no atomics)
__global__ void k_deg_dinv(const int2* __restrict__ pairs, const int* __restrict__ off,
                           float* __restrict__ dinv, int N) {
    int n = blockIdx.x * blockDim.x + threadIdx.x;
    if (n >= N) return;
    float d = 1.0f;  // self-loop
    int e1 = off[n + 1];
    for (int e = off[n]; e < e1; ++e) d += __int_as_float(pairs[e].y);
    dinv[n] = rsqrtf(d);   // d >= 1 always
}

// scale stored weights: w <- dinv[src] * w * dinv[dst]
__global__ void k_scale(int2* __restrict__ pairs, const int* __restrict__ off,
                        const float* __restrict__ dinv, int N) {
    int n = blockIdx.x * blockDim.x + threadIdx.x;
    if (n >= N) return;
    const float dn = dinv[n];
    int e1 = off[n + 1];
    for (int e = off[n]; e < e1; ++e) {
        int2 p = pairs[e];
        pairs[e].y = __float_as_int(__int_as_float(p.y) * dinv[p.x] * dn);
    }
}

// ---------------- dense GEMM: out[N,96] = X[N,K] @ W[K,96] (+bias)(+elu) ----------------
// Double-buffered LDS tiling. BM=64, BN=96 (full), BK=16. Output fp32 or bf16.
#define GM_BM 64
#define GM_BK 16

__global__ __launch_bounds__(256) void
k_gemm(const float* __restrict__ X, const float* __restrict__ W,
       const float* __restrict__ bias, void* __restrict__ outp,
       int N, int K, int act, int obf16) {
    __shared__ float Xs[2][GM_BK][GM_BM];
    __shared__ float Ws[2][GM_BK][96];

    const int tid = threadIdx.x;
    const int tn  = tid & 7;     // row group: rows tn*8 .. tn*8+7
    const int tj  = tid >> 3;    // col group: cols tj*3 .. tj*3+2
    const int sn  = tid & 63;    // staging row
    const int skq = tid >> 6;    // staging k-quarter
    const int n0  = blockIdx.x * GM_BM;
    const int KT  = K / GM_BK;

    float acc[8][3];
    const float b0 = bias ? bias[tj * 3 + 0] : 0.f;
    const float b1 = bias ? bias[tj * 3 + 1] : 0.f;
    const float b2 = bias ? bias[tj * 3 + 2] : 0.f;
    #pragma unroll
    for (int r = 0; r < 8; ++r) { acc[r][0] = b0; acc[r][1] = b1; acc[r][2] = b2; }

    const int nload = (n0 + sn < N) ? (n0 + sn) : (N - 1);  // clamp tail reads
    const float* xrow = X + (size_t)nload * K;

    // prologue: stage tile 0 into buffer 0
    {
        float4 xv = *reinterpret_cast<const float4*>(xrow + skq * 4);
        Xs[0][skq * 4 + 0][sn] = xv.x;
        Xs[0][skq * 4 + 1][sn] = xv.y;
        Xs[0][skq * 4 + 2][sn] = xv.z;
        Xs[0][skq * 4 + 3][sn] = xv.w;
        #pragma unroll
        for (int p = 0; p < 6; ++p) {
            int i = tid + p * 256;           // 16*96 = 1536 contiguous floats
            (&Ws[0][0][0])[i] = W[i];
        }
    }
    __syncthreads();

    int cur = 0;
    for (int kt = 0; kt < KT; ++kt) {
        const bool more = (kt + 1 < KT);
        float4 xnext;
        float wnext[6];
        if (more) {
            const int k0n = (kt + 1) * GM_BK;
            xnext = *reinterpret_cast<const float4*>(xrow + k0n + skq * 4);
            #pragma unroll
            for (int p = 0; p < 6; ++p)
                wnext[p] = W[k0n * 96 + tid + p * 256];
        }
        #pragma unroll
        for (int ki = 0; ki < GM_BK; ++ki) {
            const float4 xa = *reinterpret_cast<const float4*>(&Xs[cur][ki][tn * 8]);
            const float4 xb = *reinterpret_cast<const float4*>(&Xs[cur][ki][tn * 8 + 4]);
            const float w0 = Ws[cur][ki][tj * 3 + 0];
            const float w1 = Ws[cur][ki][tj * 3 + 1];
            const float w2 = Ws[cur][ki][tj * 3 + 2];
            acc[0][0] = fmaf(xa.x, w0, acc[0][0]);
            acc[0][1] = fmaf(xa.x, w1, acc[0][1]);
            acc[0][2] = fmaf(xa.x, w2, acc[0][2]);
            acc[1][0] = fmaf(xa.y, w0, acc[1][0]);
            acc[1][1] = fmaf(xa.y, w1, acc[1][1]);
            acc[1][2] = fmaf(xa.y, w2, acc[1][2]);
            acc[2][0] = fmaf(xa.z, w0, acc[2][0]);
            acc[2][1] = fmaf(xa.z, w1, acc[2][1]);
            acc[2][2] = fmaf(xa.z, w2, acc[2][2]);
            acc[3][0] = fmaf(xa.w, w0, acc[3][0]);
            acc[3][1] = fmaf(xa.w, w1, acc[3][1]);
            acc[3][2] = fmaf(xa.w, w2, acc[3][2]);
            acc[4][0] = fmaf(xb.x, w0, acc[4][0]);
            acc[4][1] = fmaf(xb.x, w1, acc[4][1]);
            acc[4][2] = fmaf(xb.x, w2, acc[4][2]);
            acc[5][0] = fmaf(xb.y, w0, acc[5][0]);
            acc[5][1] = fmaf(xb.y, w1, acc[5][1]);
            acc[5][2] = fmaf(xb.y, w2, acc[5][2]);
            acc[6][0] = fmaf(xb.z, w0, acc[6][0]);
            acc[6][1] = fmaf(xb.z, w1, acc[6][1]);
            acc[6][2] = fmaf(xb.z, w2, acc[6][2]);
            acc[7][0] = fmaf(xb.w, w0, acc[7][0]);
            acc[7][1] = fmaf(xb.w, w1, acc[7][1]);
            acc[7][2] = fmaf(xb.w, w2, acc[7][2]);
        }
        if (more) {
            const int nb = cur ^ 1;
            Xs[nb][skq * 4 + 0][sn] = xnext.x;
            Xs[nb][skq * 4 + 1][sn] = xnext.y;
            Xs[nb][skq * 4 + 2][sn] = xnext.z;
            Xs[nb][skq * 4 + 3][sn] = xnext.w;
            #pragma unroll
            for (int p = 0; p < 6; ++p)
                (&Ws[nb][0][0])[tid + p * 256] = wnext[p];
            cur = nb;
        }
        __syncthreads();
    }

    // epilogue
    #pragma unroll
    for (int r = 0; r < 8; ++r) {
        const int n = n0 + tn * 8 + r;
        if (n < N) {
            float a0 = acc[r][0], a1 = acc[r][1], a2 = acc[r][2];
            if (act) { a0 = elu_f(a0); a1 = elu_f(a1); a2 = elu_f(a2); }
            if (obf16) {
                __hip_bfloat16* op = (__hip_bfloat16*)outp + (size_t)n * 96 + tj * 3;
                op[0] = __float2bfloat16(a0);
                op[1] = __float2bfloat16(a1);
                op[2] = __float2bfloat16(a2);
            } else {
                float* op = (float*)outp + (size_t)n * 96 + tj * 3;
                op[0] = a0; op[1] = a1; op[2] = a2;
            }
        }
    }
}

// ---------------- aggregation over bf16 message table ----------------
// out = elu(seg_sum(norm * tmp_bf16[src]) + self + bias) (+addsrc)
// thread = (node, 8-feature chunk); 12 threads/node; 16B uint4 gathers.
static __device__ __forceinline__ void bf8_unpack(uint4 v, float* f) {
    f[0] = __uint_as_float(v.x << 16);
    f[1] = __uint_as_float(v.x & 0xffff0000u);
    f[2] = __uint_as_float(v.y << 16);
    f[3] = __uint_as_float(v.y & 0xffff0000u);
    f[4] = __uint_as_float(v.z << 16);
    f[5] = __uint_as_float(v.z & 0xffff0000u);
    f[6] = __uint_as_float(v.w << 16);
    f[7] = __uint_as_float(v.w & 0xffff0000u);
}

__global__ void k_aggregate(const ushort* __restrict__ tmp, const int* __restrict__ off,
                            const int2* __restrict__ pairs, const float* __restrict__ dinv,
                            const float* __restrict__ bias, const float* __restrict__ addsrc,
                            float* __restrict__ out, int N) {
    int t = blockIdx.x * blockDim.x + threadIdx.x;
    int n = t / 12;
    if (n >= N) return;
    int c = (t % 12) * 8;
    float di = dinv[n];
    float sn = di * di;    // self-loop norm = dinv * 1 * dinv
    float f[8], acc[8];
    uint4 sv = *reinterpret_cast<const uint4*>(tmp + (size_t)n * 96 + c);
    bf8_unpack(sv, f);
    #pragma unroll
    for (int i = 0; i < 8; ++i) acc[i] = sn * f[i];
    int e1 = off[n + 1];
    for (int e = off[n]; e < e1; ++e) {
        int2 p = pairs[e];
        float wv = __int_as_float(p.y);
        uint4 hv = *reinterpret_cast<const uint4*>(tmp + (size_t)p.x * 96 + c);
        bf8_unpack(hv, f);
        #pragma unroll
        for (int i = 0; i < 8; ++i) acc[i] = fmaf(wv, f[i], acc[i]);
    }
    float4 bv0 = *reinterpret_cast<const float4*>(bias + c);
    float4 bv1 = *reinterpret_cast<const float4*>(bias + c + 4);
    acc[0] = elu_f(acc[0] + bv0.x);
    acc[1] = elu_f(acc[1] + bv0.y);
    acc[2] = elu_f(acc[2] + bv0.z);
    acc[3] = elu_f(acc[3] + bv0.w);
    acc[4] = elu_f(acc[4] + bv1.x);
    acc[5] = elu_f(acc[5] + bv1.y);
    acc[6] = elu_f(acc[6] + bv1.z);
    acc[7] = elu_f(acc[7] + bv1.w);
    if (addsrc) {
        float4 r0 = *reinterpret_cast<const float4*>(addsrc + (size_t)n * 96 + c);
        float4 r1 = *reinterpret_cast<const float4*>(addsrc + (size_t)n * 96 + c + 4);
        acc[0] += r0.x; acc[1] += r0.y; acc[2] += r0.z; acc[3] += r0.w;
        acc[4] += r1.x; acc[5] += r1.y; acc[6] += r1.z; acc[7] += r1.w;
    }
    float* op = out + (size_t)n * 96 + c;
    *reinterpret_cast<float4*>(op)     = make_float4(acc[0], acc[1], acc[2], acc[3]);
    *reinterpret_cast<float4*>(op + 4) = make_float4(acc[4], acc[5], acc[6], acc[7]);
}

// ---------------- final: logits = h @ W2 + b2; log_softmax ----------------
// one wave per node; lane = class (40 active of 64)
__global__ void k_lin2_lsm(const float* __restrict__ h, const float* __restrict__ W2,
                           const float* __restrict__ b2, float* __restrict__ out, int N) {
    __shared__ float Wl[96 * 40];
    for (int i = threadIdx.x; i < 96 * 40; i += THREADS) Wl[i] = W2[i];
    __syncthreads();
    const int lane = threadIdx.x & 63;
    const int wid  = threadIdx.x >> 6;   // 4 waves per block
    for (int n = blockIdx.x * 4 + wid; n < N; n += gridDim.x * 4) {
        const float* hr = h + (size_t)n * 96;
        float acc = 0.f;
        if (lane < 40) {
            acc = b2[lane];
            for (int k = 0; k < 96; ++k) acc = fmaf(hr[k], Wl[k * 40 + lane], acc);
        }
        float m = (lane < 40) ? acc : -INFINITY;
        #pragma unroll
        for (int d = 32; d > 0; d >>= 1) m = fmaxf(m, __shfl_xor(m, d));
        float ex = (lane < 40) ? expf(acc - m) : 0.f;
        float ssum = ex;
        #pragma unroll
        for (int d = 32; d > 0; d >>= 1) ssum += __shfl_xor(ssum, d);
        if (lane < 40) out[(size_t)n * 40 + lane] = acc - m - logf(ssum);
    }
}

// ---------------- launch ----------------

extern "C" void kernel_launch(void* const* d_in, const int* in_sizes, int n_in,
                              void* d_out, int out_size, void* d_ws, size_t ws_size,
                              hipStream_t stream) {
    const float* x   = (const float*)d_in[0];
    const int*   ei  = (const int*)d_in[1];
    const float* ew  = (const float*)d_in[2];
    const float* Wc1 = (const float*)d_in[3];
    const float* bc1 = (const float*)d_in[4];
    const float* Wc2 = (const float*)d_in[5];
    const float* bc2 = (const float*)d_in[6];
    const float* Wc3 = (const float*)d_in[7];
    const float* bc3 = (const float*)d_in[8];
    const float* Wl1 = (const float*)d_in[9];
    const float* bl1 = (const float*)d_in[10];
    const float* Wl2 = (const float*)d_in[11];
    const float* bl2 = (const float*)d_in[12];

    const int FIN = 128, HID = 96;
    const int N = in_sizes[0] / FIN;
    const int E = in_sizes[2];
    const int* row = ei;
    const int* col = ei + E;

    char* ws = (char*)d_ws;
    size_t o = 0;
    auto alloc = [&](size_t bytes) -> void* {
        void* p = ws + o;
        o += (bytes + 255) & ~(size_t)255;
        return p;
    };
    float*  dinv  = (float*)alloc((size_t)N * 4);
    int*    cnt   = (int*)  alloc((size_t)N * 4);
    int*    off   = (int*)  alloc((size_t)(N + 1) * 4);
    int*    cur   = (int*)  alloc((size_t)N * 4);
    int2*   pairs = (int2*) alloc((size_t)E * 8);
    ushort* A     = (ushort*)alloc((size_t)N * HID * 2);  // bf16 message table
    float*  B     = (float*)alloc((size_t)N * HID * 4);   // x1 (residual)
    float*  C     = (float*)alloc((size_t)N * HID * 4);   // running h

    const int gN = (N + THREADS - 1) / THREADS;
    const int gE = (E + THREADS - 1) / THREADS;
    const int gAgg = (N * 12 + THREADS - 1) / THREADS;
    const int gGM = (N + GM_BM - 1) / GM_BM;

    // graph prep: count -> scan -> fill pairs -> deg/dinv -> scale
    k_zero<<<gN, THREADS, 0, stream>>>(cnt, N);
    k_count<<<gE, THREADS, 0, stream>>>(col, cnt, E);
    k_scan<<<1, 1024, 0, stream>>>(cnt, off, cur, N);
    k_fill<<<gE, THREADS, 0, stream>>>(row, col, ew, cur, pairs, E);
    k_deg_dinv<<<gN, THREADS, 0, stream>>>(pairs, off, dinv, N);
    k_scale<<<gN, THREADS, 0, stream>>>(pairs, off, dinv, N);

    // conv1: x1 = elu(agg(x@Wc1) + b1)  -> B
    k_gemm<<<gGM, 256, 0, stream>>>(x, Wc1, nullptr, A, N, FIN, 0, 1);
    k_aggregate<<<gAgg, THREADS, 0, stream>>>(A, off, pairs, dinv, bc1, nullptr, B, N);

    // lin1: h = elu(x@Wl1 + bl1) -> C
    k_gemm<<<gGM, 256, 0, stream>>>(x, Wl1, bl1, C, N, FIN, 1, 0);

    // conv2: h = elu(agg(h@Wc2) + b2) -> C
    k_gemm<<<gGM, 256, 0, stream>>>(C, Wc2, nullptr, A, N, HID, 0, 1);
    k_aggregate<<<gAgg, THREADS, 0, stream>>>(A, off, pairs, dinv, bc2, nullptr, C, N);

    // conv3: h = x1 + elu(agg(h@Wc3) + b3) -> C
    k_gemm<<<gGM, 256, 0, stream>>>(C, Wc3, nullptr, A, N, HID, 0, 1);
    k_aggregate<<<gAgg, THREADS, 0, stream>>>(A, off, pairs, dinv, bc3, B, C, N);

    // lin2 + log_softmax -> d_out
    k_lin2_lsm<<<2048, THREADS, 0, stream>>>(C, Wl2, bl2, (float*)d_out, N);
}

// Round 5
// 439.141 us; speedup vs baseline: 1.7956x; 1.0108x over previous
//
#include <hip/hip_runtime.h>
#include <hip/hip_bf16.h>

#define THREADS 256

static __device__ __forceinline__ float elu_f(float x) {
    return x > 0.f ? x : expm1f(x);
}

// ---------------- graph preprocessing ----------------

__global__ void k_count(const int* __restrict__ col, int* __restrict__ cnt, int E) {
    int e = blockIdx.x * blockDim.x + threadIdx.x;
    if (e < E) atomicAdd(&cnt[col[e]], 1);
}

// single-block exclusive scan of cnt[N] -> off[N+1]; also copies into cur[]
__global__ void k_scan(const int* __restrict__ cnt, int* __restrict__ off,
                       int* __restrict__ cur, int N) {
    __shared__ int wsum[16];
    const int lane = threadIdx.x & 63;
    const int wid  = threadIdx.x >> 6;   // 16 waves of 64 in a 1024 block
    int carry = 0;
    for (int base = 0; base < N; base += 1024) {
        int i = base + threadIdx.x;
        int v = (i < N) ? cnt[i] : 0;
        int s = v;
        #pragma unroll
        for (int d = 1; d < 64; d <<= 1) {
            int t = __shfl_up(s, d);
            if (lane >= d) s += t;
        }
        if (lane == 63) wsum[wid] = s;
        __syncthreads();
        if (wid == 0) {
            int x = (lane < 16) ? wsum[lane] : 0;
            #pragma unroll
            for (int d = 1; d < 16; d <<= 1) {
                int t = __shfl_up(x, d);
                if (lane >= d) x += t;
            }
            if (lane < 16) wsum[lane] = x;
        }
        __syncthreads();
        int wbase = (wid > 0) ? wsum[wid - 1] : 0;
        int incl  = s + wbase + carry;
        int excl  = incl - v;
        if (i < N) { off[i] = excl; cur[i] = excl; }
        carry += wsum[15];
        __syncthreads();   // protect wsum before next chunk overwrites
    }
    if (threadIdx.x == 0) off[N] = carry;
}

// fill CSR as packed (src, raw_weight) pairs: ONE 8B scattered write per edge
__global__ void k_fill(const int* __restrict__ row, const int* __restrict__ col,
                       const float* __restrict__ w, int* __restrict__ cur,
                       int2* __restrict__ pairs, int E) {
    int e = blockIdx.x * blockDim.x + threadIdx.x;
    if (e < E) {
        int c = col[e];
        int pos = atomicAdd(&cur[c], 1);
        pairs[pos] = make_int2(row[e], __float_as_int(w[e]));
    }
}

// deg[n] = 1 + sum of raw weights over segment (sequential reads, no atomics)
__global__ void k_deg_dinv(const int2* __restrict__ pairs, const int* __restrict__ off,
                           float* __restrict__ dinv, int N) {
    int n = blockIdx.x * blockDim.x + threadIdx.x;
    if (n >= N) return;
    float d = 1.0f;  // self-loop
    int e1 = off[n + 1];
    for (int e = off[n]; e < e1; ++e) d += __int_as_float(pairs[e].y);
    dinv[n] = rsqrtf(d);   // d >= 1 always
}

// scale stored weights: w <- dinv[src] * w * dinv[dst]
__global__ void k_scale(int2* __restrict__ pairs, const int* __restrict__ off,
                        const float* __restrict__ dinv, int N) {
    int n = blockIdx.x * blockDim.x + threadIdx.x;
    if (n >= N) return;
    const float dn = dinv[n];
    int e1 = off[n + 1];
    for (int e = off[n]; e < e1; ++e) {
        int2 p = pairs[e];
        pairs[e].y = __float_as_int(__int_as_float(p.y) * dinv[p.x] * dn);
    }
}

// ---------------- dense GEMM: out[N,96] = X[N,K] @ W[K,96] (+bias)(+elu) ----------------
// Double-buffered LDS tiling. BM=64, BN=96 (full), BK=16. Output fp32 or bf16.
#define GM_BM 64
#define GM_BK 16

__global__ __launch_bounds__(256) void
k_gemm(const float* __restrict__ X, const float* __restrict__ W,
       const float* __restrict__ bias, void* __restrict__ outp,
       int N, int K, int act, int obf16) {
    __shared__ float Xs[2][GM_BK][GM_BM];
    __shared__ float Ws[2][GM_BK][96];

    const int tid = threadIdx.x;
    const int tn  = tid & 7;     // row group: rows tn*8 .. tn*8+7
    const int tj  = tid >> 3;    // col group: cols tj*3 .. tj*3+2
    const int sn  = tid & 63;    // staging row
    const int skq = tid >> 6;    // staging k-quarter
    const int n0  = blockIdx.x * GM_BM;
    const int KT  = K / GM_BK;

    float acc[8][3];
    const float b0 = bias ? bias[tj * 3 + 0] : 0.f;
    const float b1 = bias ? bias[tj * 3 + 1] : 0.f;
    const float b2 = bias ? bias[tj * 3 + 2] : 0.f;
    #pragma unroll
    for (int r = 0; r < 8; ++r) { acc[r][0] = b0; acc[r][1] = b1; acc[r][2] = b2; }

    const int nload = (n0 + sn < N) ? (n0 + sn) : (N - 1);  // clamp tail reads
    const float* xrow = X + (size_t)nload * K;

    // prologue: stage tile 0 into buffer 0
    {
        float4 xv = *reinterpret_cast<const float4*>(xrow + skq * 4);
        Xs[0][skq * 4 + 0][sn] = xv.x;
        Xs[0][skq * 4 + 1][sn] = xv.y;
        Xs[0][skq * 4 + 2][sn] = xv.z;
        Xs[0][skq * 4 + 3][sn] = xv.w;
        #pragma unroll
        for (int p = 0; p < 6; ++p) {
            int i = tid + p * 256;           // 16*96 = 1536 contiguous floats
            (&Ws[0][0][0])[i] = W[i];
        }
    }
    __syncthreads();

    int cur = 0;
    for (int kt = 0; kt < KT; ++kt) {
        const bool more = (kt + 1 < KT);
        float4 xnext;
        float wnext[6];
        if (more) {
            const int k0n = (kt + 1) * GM_BK;
            xnext = *reinterpret_cast<const float4*>(xrow + k0n + skq * 4);
            #pragma unroll
            for (int p = 0; p < 6; ++p)
                wnext[p] = W[k0n * 96 + tid + p * 256];
        }
        #pragma unroll
        for (int ki = 0; ki < GM_BK; ++ki) {
            const float4 xa = *reinterpret_cast<const float4*>(&Xs[cur][ki][tn * 8]);
            const float4 xb = *reinterpret_cast<const float4*>(&Xs[cur][ki][tn * 8 + 4]);
            const float w0 = Ws[cur][ki][tj * 3 + 0];
            const float w1 = Ws[cur][ki][tj * 3 + 1];
            const float w2 = Ws[cur][ki][tj * 3 + 2];
            acc[0][0] = fmaf(xa.x, w0, acc[0][0]);
            acc[0][1] = fmaf(xa.x, w1, acc[0][1]);
            acc[0][2] = fmaf(xa.x, w2, acc[0][2]);
            acc[1][0] = fmaf(xa.y, w0, acc[1][0]);
            acc[1][1] = fmaf(xa.y, w1, acc[1][1]);
            acc[1][2] = fmaf(xa.y, w2, acc[1][2]);
            acc[2][0] = fmaf(xa.z, w0, acc[2][0]);
            acc[2][1] = fmaf(xa.z, w1, acc[2][1]);
            acc[2][2] = fmaf(xa.z, w2, acc[2][2]);
            acc[3][0] = fmaf(xa.w, w0, acc[3][0]);
            acc[3][1] = fmaf(xa.w, w1, acc[3][1]);
            acc[3][2] = fmaf(xa.w, w2, acc[3][2]);
            acc[4][0] = fmaf(xb.x, w0, acc[4][0]);
            acc[4][1] = fmaf(xb.x, w1, acc[4][1]);
            acc[4][2] = fmaf(xb.x, w2, acc[4][2]);
            acc[5][0] = fmaf(xb.y, w0, acc[5][0]);
            acc[5][1] = fmaf(xb.y, w1, acc[5][1]);
            acc[5][2] = fmaf(xb.y, w2, acc[5][2]);
            acc[6][0] = fmaf(xb.z, w0, acc[6][0]);
            acc[6][1] = fmaf(xb.z, w1, acc[6][1]);
            acc[6][2] = fmaf(xb.z, w2, acc[6][2]);
            acc[7][0] = fmaf(xb.w, w0, acc[7][0]);
            acc[7][1] = fmaf(xb.w, w1, acc[7][1]);
            acc[7][2] = fmaf(xb.w, w2, acc[7][2]);
        }
        if (more) {
            const int nb = cur ^ 1;
            Xs[nb][skq * 4 + 0][sn] = xnext.x;
            Xs[nb][skq * 4 + 1][sn] = xnext.y;
            Xs[nb][skq * 4 + 2][sn] = xnext.z;
            Xs[nb][skq * 4 + 3][sn] = xnext.w;
            #pragma unroll
            for (int p = 0; p < 6; ++p)
                (&Ws[nb][0][0])[tid + p * 256] = wnext[p];
            cur = nb;
        }
        __syncthreads();
    }

    // epilogue
    #pragma unroll
    for (int r = 0; r < 8; ++r) {
        const int n = n0 + tn * 8 + r;
        if (n < N) {
            float a0 = acc[r][0], a1 = acc[r][1], a2 = acc[r][2];
            if (act) { a0 = elu_f(a0); a1 = elu_f(a1); a2 = elu_f(a2); }
            if (obf16) {
                __hip_bfloat16* op = (__hip_bfloat16*)outp + (size_t)n * 96 + tj * 3;
                op[0] = __float2bfloat16(a0);
                op[1] = __float2bfloat16(a1);
                op[2] = __float2bfloat16(a2);
            } else {
                float* op = (float*)outp + (size_t)n * 96 + tj * 3;
                op[0] = a0; op[1] = a1; op[2] = a2;
            }
        }
    }
}

// ---------------- fused FIN GEMM: out1 = bf16(X@W1), out2 = elu(X@W2 + b2) ----------------
// Same structure as k_gemm but two weight matrices share one Xs staging.
__global__ __launch_bounds__(256) void
k_gemm2_fin(const float* __restrict__ X, const float* __restrict__ W1,
            const float* __restrict__ W2, const float* __restrict__ bias2,
            __hip_bfloat16* __restrict__ out1, float* __restrict__ out2, int N) {
    const int K = 128;
    __shared__ float Xs[2][GM_BK][GM_BM];
    __shared__ float Wa[2][GM_BK][96];
    __shared__ float Wb[2][GM_BK][96];

    const int tid = threadIdx.x;
    const int tn  = tid & 7;
    const int tj  = tid >> 3;
    const int sn  = tid & 63;
    const int skq = tid >> 6;
    const int n0  = blockIdx.x * GM_BM;
    const int KT  = K / GM_BK;

    float acc1[8][3], acc2[8][3];
    const float b0 = bias2[tj * 3 + 0];
    const float b1 = bias2[tj * 3 + 1];
    const float b2 = bias2[tj * 3 + 2];
    #pragma unroll
    for (int r = 0; r < 8; ++r) {
        acc1[r][0] = 0.f; acc1[r][1] = 0.f; acc1[r][2] = 0.f;
        acc2[r][0] = b0;  acc2[r][1] = b1;  acc2[r][2] = b2;
    }

    const int nload = (n0 + sn < N) ? (n0 + sn) : (N - 1);
    const float* xrow = X + (size_t)nload * K;

    {
        float4 xv = *reinterpret_cast<const float4*>(xrow + skq * 4);
        Xs[0][skq * 4 + 0][sn] = xv.x;
        Xs[0][skq * 4 + 1][sn] = xv.y;
        Xs[0][skq * 4 + 2][sn] = xv.z;
        Xs[0][skq * 4 + 3][sn] = xv.w;
        #pragma unroll
        for (int p = 0; p < 6; ++p) {
            int i = tid + p * 256;
            (&Wa[0][0][0])[i] = W1[i];
            (&Wb[0][0][0])[i] = W2[i];
        }
    }
    __syncthreads();

    int cur = 0;
    for (int kt = 0; kt < KT; ++kt) {
        const bool more = (kt + 1 < KT);
        float4 xnext;
        float wanext[6], wbnext[6];
        if (more) {
            const int k0n = (kt + 1) * GM_BK;
            xnext = *reinterpret_cast<const float4*>(xrow + k0n + skq * 4);
            #pragma unroll
            for (int p = 0; p < 6; ++p) {
                wanext[p] = W1[k0n * 96 + tid + p * 256];
                wbnext[p] = W2[k0n * 96 + tid + p * 256];
            }
        }
        #pragma unroll
        for (int ki = 0; ki < GM_BK; ++ki) {
            const float4 xa = *reinterpret_cast<const float4*>(&Xs[cur][ki][tn * 8]);
            const float4 xb = *reinterpret_cast<const float4*>(&Xs[cur][ki][tn * 8 + 4]);
            const float wa0 = Wa[cur][ki][tj * 3 + 0];
            const float wa1 = Wa[cur][ki][tj * 3 + 1];
            const float wa2 = Wa[cur][ki][tj * 3 + 2];
            const float wb0 = Wb[cur][ki][tj * 3 + 0];
            const float wb1 = Wb[cur][ki][tj * 3 + 1];
            const float wb2 = Wb[cur][ki][tj * 3 + 2];
            const float xs[8] = {xa.x, xa.y, xa.z, xa.w, xb.x, xb.y, xb.z, xb.w};
            #pragma unroll
            for (int r = 0; r < 8; ++r) {
                acc1[r][0] = fmaf(xs[r], wa0, acc1[r][0]);
                acc1[r][1] = fmaf(xs[r], wa1, acc1[r][1]);
                acc1[r][2] = fmaf(xs[r], wa2, acc1[r][2]);
                acc2[r][0] = fmaf(xs[r], wb0, acc2[r][0]);
                acc2[r][1] = fmaf(xs[r], wb1, acc2[r][1]);
                acc2[r][2] = fmaf(xs[r], wb2, acc2[r][2]);
            }
        }
        if (more) {
            const int nb = cur ^ 1;
            Xs[nb][skq * 4 + 0][sn] = xnext.x;
            Xs[nb][skq * 4 + 1][sn] = xnext.y;
            Xs[nb][skq * 4 + 2][sn] = xnext.z;
            Xs[nb][skq * 4 + 3][sn] = xnext.w;
            #pragma unroll
            for (int p = 0; p < 6; ++p) {
                (&Wa[nb][0][0])[tid + p * 256] = wanext[p];
                (&Wb[nb][0][0])[tid + p * 256] = wbnext[p];
            }
            cur = nb;
        }
        __syncthreads();
    }

    #pragma unroll
    for (int r = 0; r < 8; ++r) {
        const int n = n0 + tn * 8 + r;
        if (n < N) {
            __hip_bfloat16* o1 = out1 + (size_t)n * 96 + tj * 3;
            o1[0] = __float2bfloat16(acc1[r][0]);
            o1[1] = __float2bfloat16(acc1[r][1]);
            o1[2] = __float2bfloat16(acc1[r][2]);
            float* o2 = out2 + (size_t)n * 96 + tj * 3;
            o2[0] = elu_f(acc2[r][0]);
            o2[1] = elu_f(acc2[r][1]);
            o2[2] = elu_f(acc2[r][2]);
        }
    }
}

// ---------------- aggregation over bf16 message table ----------------
static __device__ __forceinline__ void bf8_unpack(uint4 v, float* f) {
    f[0] = __uint_as_float(v.x << 16);
    f[1] = __uint_as_float(v.x & 0xffff0000u);
    f[2] = __uint_as_float(v.y << 16);
    f[3] = __uint_as_float(v.y & 0xffff0000u);
    f[4] = __uint_as_float(v.z << 16);
    f[5] = __uint_as_float(v.z & 0xffff0000u);
    f[6] = __uint_as_float(v.w << 16);
    f[7] = __uint_as_float(v.w & 0xffff0000u);
}

__global__ void k_aggregate(const ushort* __restrict__ tmp, const int* __restrict__ off,
                            const int2* __restrict__ pairs, const float* __restrict__ dinv,
                            const float* __restrict__ bias, const float* __restrict__ addsrc,
                            float* __restrict__ out, int N) {
    int t = blockIdx.x * blockDim.x + threadIdx.x;
    int n = t / 12;
    if (n >= N) return;
    int c = (t % 12) * 8;
    float di = dinv[n];
    float sn = di * di;    // self-loop norm = dinv * 1 * dinv
    float f[8], acc[8];
    uint4 sv = *reinterpret_cast<const uint4*>(tmp + (size_t)n * 96 + c);
    bf8_unpack(sv, f);
    #pragma unroll
    for (int i = 0; i < 8; ++i) acc[i] = sn * f[i];
    int e1 = off[n + 1];
    for (int e = off[n]; e < e1; ++e) {
        int2 p = pairs[e];
        float wv = __int_as_float(p.y);
        uint4 hv = *reinterpret_cast<const uint4*>(tmp + (size_t)p.x * 96 + c);
        bf8_unpack(hv, f);
        #pragma unroll
        for (int i = 0; i < 8; ++i) acc[i] = fmaf(wv, f[i], acc[i]);
    }
    float4 bv0 = *reinterpret_cast<const float4*>(bias + c);
    float4 bv1 = *reinterpret_cast<const float4*>(bias + c + 4);
    acc[0] = elu_f(acc[0] + bv0.x);
    acc[1] = elu_f(acc[1] + bv0.y);
    acc[2] = elu_f(acc[2] + bv0.z);
    acc[3] = elu_f(acc[3] + bv0.w);
    acc[4] = elu_f(acc[4] + bv1.x);
    acc[5] = elu_f(acc[5] + bv1.y);
    acc[6] = elu_f(acc[6] + bv1.z);
    acc[7] = elu_f(acc[7] + bv1.w);
    if (addsrc) {
        float4 r0 = *reinterpret_cast<const float4*>(addsrc + (size_t)n * 96 + c);
        float4 r1 = *reinterpret_cast<const float4*>(addsrc + (size_t)n * 96 + c + 4);
        acc[0] += r0.x; acc[1] += r0.y; acc[2] += r0.z; acc[3] += r0.w;
        acc[4] += r1.x; acc[5] += r1.y; acc[6] += r1.z; acc[7] += r1.w;
    }
    float* op = out + (size_t)n * 96 + c;
    *reinterpret_cast<float4*>(op)     = make_float4(acc[0], acc[1], acc[2], acc[3]);
    *reinterpret_cast<float4*>(op + 4) = make_float4(acc[4], acc[5], acc[6], acc[7]);
}

// ---------------- final: logits = h @ W2 + b2; log_softmax ----------------
// lane = node: 128 threads stage 128 h-rows transposed in LDS; each lane
// computes all 40 logits in registers (W2 reads are wave-uniform -> scalar
// loads on the scalar pipe); softmax entirely per-lane, no shuffles.
__global__ __launch_bounds__(128) void
k_lin2_lsm(const float* __restrict__ h, const float* __restrict__ W2,
           const float* __restrict__ b2, float* __restrict__ out, int N) {
    __shared__ float hsT[96][128];    // 48 KiB; read banks = tid%32 (2-way, free)
    const int tid = threadIdx.x;
    const int n0 = blockIdx.x * 128;
    const int nn = (N - n0 < 128) ? (N - n0) : 128;

    if (tid < nn) {
        const float* hr = h + (size_t)(n0 + tid) * 96;
        #pragma unroll
        for (int q = 0; q < 24; ++q) {
            float4 v = *reinterpret_cast<const float4*>(hr + q * 4);
            hsT[q * 4 + 0][tid] = v.x;
            hsT[q * 4 + 1][tid] = v.y;
            hsT[q * 4 + 2][tid] = v.z;
            hsT[q * 4 + 3][tid] = v.w;
        }
    }
    __syncthreads();

    float acc[40];
    #pragma unroll
    for (int c = 0; c < 40; ++c) acc[c] = b2[c];   // uniform -> scalar
    for (int k = 0; k < 96; ++k) {
        const float hv = hsT[k][tid];
        const float* wr = W2 + k * 40;             // uniform -> s_load
        #pragma unroll
        for (int c = 0; c < 40; ++c) acc[c] = fmaf(hv, wr[c], acc[c]);
    }

    float m = acc[0];
    #pragma unroll
    for (int c = 1; c < 40; ++c) m = fmaxf(m, acc[c]);
    float s = 0.f;
    #pragma unroll
    for (int c = 0; c < 40; ++c) s += expf(acc[c] - m);
    const float lse = m + logf(s);

    if (tid < nn) {
        float* op = out + (size_t)(n0 + tid) * 40;
        #pragma unroll
        for (int q = 0; q < 10; ++q) {
            float4 v = make_float4(acc[q * 4 + 0] - lse, acc[q * 4 + 1] - lse,
                                   acc[q * 4 + 2] - lse, acc[q * 4 + 3] - lse);
            *reinterpret_cast<float4*>(op + q * 4) = v;
        }
    }
}

// ---------------- launch ----------------

extern "C" void kernel_launch(void* const* d_in, const int* in_sizes, int n_in,
                              void* d_out, int out_size, void* d_ws, size_t ws_size,
                              hipStream_t stream) {
    const float* x   = (const float*)d_in[0];
    const int*   ei  = (const int*)d_in[1];
    const float* ew  = (const float*)d_in[2];
    const float* Wc1 = (const float*)d_in[3];
    const float* bc1 = (const float*)d_in[4];
    const float* Wc2 = (const float*)d_in[5];
    const float* bc2 = (const float*)d_in[6];
    const float* Wc3 = (const float*)d_in[7];
    const float* bc3 = (const float*)d_in[8];
    const float* Wl1 = (const float*)d_in[9];
    const float* bl1 = (const float*)d_in[10];
    const float* Wl2 = (const float*)d_in[11];
    const float* bl2 = (const float*)d_in[12];

    const int FIN = 128, HID = 96;
    const int N = in_sizes[0] / FIN;
    const int E = in_sizes[2];
    const int* row = ei;
    const int* col = ei + E;

    char* ws = (char*)d_ws;
    size_t o = 0;
    auto alloc = [&](size_t bytes) -> void* {
        void* p = ws + o;
        o += (bytes + 255) & ~(size_t)255;
        return p;
    };
    float*  dinv  = (float*)alloc((size_t)N * 4);
    int*    cnt   = (int*)  alloc((size_t)N * 4);
    int*    off   = (int*)  alloc((size_t)(N + 1) * 4);
    int*    cur   = (int*)  alloc((size_t)N * 4);
    int2*   pairs = (int2*) alloc((size_t)E * 8);
    ushort* A     = (ushort*)alloc((size_t)N * HID * 2);  // bf16 message table
    float*  B     = (float*)alloc((size_t)N * HID * 4);   // x1 (residual)
    float*  C     = (float*)alloc((size_t)N * HID * 4);   // running h

    const int gN = (N + THREADS - 1) / THREADS;
    const int gE = (E + THREADS - 1) / THREADS;
    const int gAgg = (N * 12 + THREADS - 1) / THREADS;
    const int gGM = (N + GM_BM - 1) / GM_BM;

    // graph prep: count -> scan -> fill pairs -> deg/dinv -> scale
    hipMemsetAsync(cnt, 0, (size_t)N * 4, stream);
    k_count<<<gE, THREADS, 0, stream>>>(col, cnt, E);
    k_scan<<<1, 1024, 0, stream>>>(cnt, off, cur, N);
    k_fill<<<gE, THREADS, 0, stream>>>(row, col, ew, cur, pairs, E);
    k_deg_dinv<<<gN, THREADS, 0, stream>>>(pairs, off, dinv, N);
    k_scale<<<gN, THREADS, 0, stream>>>(pairs, off, dinv, N);

    // fused: A = bf16(x@Wc1), C = elu(x@Wl1 + bl1)
    k_gemm2_fin<<<gGM, 256, 0, stream>>>(x, Wc1, Wl1, bl1, (__hip_bfloat16*)A, C, N);

    // conv1: x1 = elu(agg(A) + b1) -> B
    k_aggregate<<<gAgg, THREADS, 0, stream>>>(A, off, pairs, dinv, bc1, nullptr, B, N);

    // conv2: h = elu(agg(C@Wc2) + b2) -> C
    k_gemm<<<gGM, 256, 0, stream>>>(C, Wc2, nullptr, A, N, HID, 0, 1);
    k_aggregate<<<gAgg, THREADS, 0, stream>>>(A, off, pairs, dinv, bc2, nullptr, C, N);

    // conv3: h = x1 + elu(agg(h@Wc3) + b3) -> C
    k_gemm<<<gGM, 256, 0, stream>>>(C, Wc3, nullptr, A, N, HID, 0, 1);
    k_aggregate<<<gAgg, THREADS, 0, stream>>>(A, off, pairs, dinv, bc3, B, C, N);

    // lin2 + log_softmax -> d_out
    k_lin2_lsm<<<(N + 127) / 128, 128, 0, stream>>>(C, Wl2, bl2, (float*)d_out, N);
}

// Round 6
// 429.142 us; speedup vs baseline: 1.8374x; 1.0233x over previous
//
#include <hip/hip_runtime.h>
#include <hip/hip_bf16.h>

static __device__ __forceinline__ float elu_f(float x) {
    return x > 0.f ? x : expm1f(x);
}

static __device__ __forceinline__ ushort f2bf(float x) {
    __hip_bfloat16 h = __float2bfloat16(x);
    ushort u;
    __builtin_memcpy(&u, &h, 2);
    return u;
}

// ================= GEMM body: out[N,96] = X[N,K]@W[K,96] (+bias)(+elu) =================
// BM=64, 128 threads, per-thread 8 rows x 6 cols. Double-buffered LDS.
// X-tile stored transposed [k][row]; reads broadcast-heavy, conflict-free.
#define GBM 64
#define GBK 16

__device__ __forceinline__ void gemm_body(
    const float* __restrict__ X, const float* __restrict__ W,
    const float* __restrict__ bias, void* __restrict__ outp,
    int N, int K, int act, int obf16, int bid)
{
    __shared__ float Xs[2][GBK][GBM];   // 8 KiB
    __shared__ float Ws[2][GBK][96];    // 12 KiB
    const int tid  = threadIdx.x;
    const int rg   = tid >> 4;          // 0..7  -> rows rg*8..+7
    const int cg   = tid & 15;          // 0..15 -> cols cg*6..+5
    const int srow = tid & 63;
    const int skq  = tid >> 6;          // 0..1
    const int n0   = bid * GBM;
    const int KT   = K >> 4;

    float acc[8][6];
    #pragma unroll
    for (int j = 0; j < 6; ++j) {
        const float b = bias ? bias[cg * 6 + j] : 0.f;
        #pragma unroll
        for (int r = 0; r < 8; ++r) acc[r][j] = b;
    }

    const int nload = (n0 + srow < N) ? (n0 + srow) : (N - 1);
    const float* xrow = X + (size_t)nload * K;

    // prologue: stage k-tile 0
    #pragma unroll
    for (int q = 0; q < 2; ++q) {
        const int k = (skq + 2 * q) * 4;
        float4 v = *reinterpret_cast<const float4*>(xrow + k);
        Xs[0][k + 0][srow] = v.x; Xs[0][k + 1][srow] = v.y;
        Xs[0][k + 2][srow] = v.z; Xs[0][k + 3][srow] = v.w;
    }
    #pragma unroll
    for (int p = 0; p < 3; ++p) {
        const int i4 = tid + p * 128;    // 384 float4s = 16x96
        float4 v = *reinterpret_cast<const float4*>(W + (size_t)i4 * 4);
        *reinterpret_cast<float4*>(&Ws[0][0][0] + i4 * 4) = v;
    }
    __syncthreads();

    int cb = 0;
    for (int kt = 0; kt < KT; ++kt) {
        const bool more = (kt + 1 < KT);
        float4 xn0, xn1, wn0, wn1, wn2;
        if (more) {
            const int kb = (kt + 1) * GBK;
            xn0 = *reinterpret_cast<const float4*>(xrow + kb + skq * 4);
            xn1 = *reinterpret_cast<const float4*>(xrow + kb + (skq + 2) * 4);
            const float* wb = W + (size_t)kb * 96;
            wn0 = *reinterpret_cast<const float4*>(wb + (size_t)(tid      ) * 4);
            wn1 = *reinterpret_cast<const float4*>(wb + (size_t)(tid + 128) * 4);
            wn2 = *reinterpret_cast<const float4*>(wb + (size_t)(tid + 256) * 4);
        }
        #pragma unroll
        for (int ki = 0; ki < GBK; ++ki) {
            float4 xa = *reinterpret_cast<const float4*>(&Xs[cb][ki][rg * 8]);
            float4 xb = *reinterpret_cast<const float4*>(&Xs[cb][ki][rg * 8 + 4]);
            float2 w01 = *reinterpret_cast<const float2*>(&Ws[cb][ki][cg * 6]);
            float2 w23 = *reinterpret_cast<const float2*>(&Ws[cb][ki][cg * 6 + 2]);
            float2 w45 = *reinterpret_cast<const float2*>(&Ws[cb][ki][cg * 6 + 4]);
            const float xs[8] = {xa.x, xa.y, xa.z, xa.w, xb.x, xb.y, xb.z, xb.w};
            const float wv[6] = {w01.x, w01.y, w23.x, w23.y, w45.x, w45.y};
            #pragma unroll
            for (int r = 0; r < 8; ++r)
                #pragma unroll
                for (int j = 0; j < 6; ++j)
                    acc[r][j] = fmaf(xs[r], wv[j], acc[r][j]);
        }
        if (more) {
            const int nb = cb ^ 1;
            const int k = skq * 4, k2 = (skq + 2) * 4;
            Xs[nb][k  + 0][srow] = xn0.x; Xs[nb][k  + 1][srow] = xn0.y;
            Xs[nb][k  + 2][srow] = xn0.z; Xs[nb][k  + 3][srow] = xn0.w;
            Xs[nb][k2 + 0][srow] = xn1.x; Xs[nb][k2 + 1][srow] = xn1.y;
            Xs[nb][k2 + 2][srow] = xn1.z; Xs[nb][k2 + 3][srow] = xn1.w;
            *reinterpret_cast<float4*>(&Ws[nb][0][0] + (size_t)(tid      ) * 4) = wn0;
            *reinterpret_cast<float4*>(&Ws[nb][0][0] + (size_t)(tid + 128) * 4) = wn1;
            *reinterpret_cast<float4*>(&Ws[nb][0][0] + (size_t)(tid + 256) * 4) = wn2;
            cb = nb;
        }
        __syncthreads();
    }

    #pragma unroll
    for (int r = 0; r < 8; ++r) {
        const int n = n0 + rg * 8 + r;
        if (n < N) {
            float a[6];
            #pragma unroll
            for (int j = 0; j < 6; ++j) { a[j] = acc[r][j]; if (act) a[j] = elu_f(a[j]); }
            if (obf16) {
                uint* op = (uint*)((ushort*)outp + (size_t)n * 96 + cg * 6);
                op[0] = (uint)f2bf(a[0]) | ((uint)f2bf(a[1]) << 16);
                op[1] = (uint)f2bf(a[2]) | ((uint)f2bf(a[3]) << 16);
                op[2] = (uint)f2bf(a[4]) | ((uint)f2bf(a[5]) << 16);
            } else {
                float* op = (float*)outp + (size_t)n * 96 + cg * 6;
                *reinterpret_cast<float2*>(op)     = make_float2(a[0], a[1]);
                *reinterpret_cast<float2*>(op + 2) = make_float2(a[2], a[3]);
                *reinterpret_cast<float2*>(op + 4) = make_float2(a[4], a[5]);
            }
        }
    }
}

__global__ __launch_bounds__(128) void
k_gemm(const float* __restrict__ X, const float* __restrict__ W,
       const float* __restrict__ bias, void* __restrict__ outp,
       int N, int K, int act, int obf16) {
    gemm_body(X, W, bias, outp, N, K, act, obf16, blockIdx.x);
}

// ================= aggregation body (bf16 message table) =================
static __device__ __forceinline__ void bf8_unpack(uint4 v, float* f) {
    f[0] = __uint_as_float(v.x << 16);
    f[1] = __uint_as_float(v.x & 0xffff0000u);
    f[2] = __uint_as_float(v.y << 16);
    f[3] = __uint_as_float(v.y & 0xffff0000u);
    f[4] = __uint_as_float(v.z << 16);
    f[5] = __uint_as_float(v.z & 0xffff0000u);
    f[6] = __uint_as_float(v.w << 16);
    f[7] = __uint_as_float(v.w & 0xffff0000u);
}

__device__ __forceinline__ void agg_body(
    const ushort* __restrict__ tmp, const int* __restrict__ off,
    const int2* __restrict__ pairs, const float* __restrict__ dinv,
    const float* __restrict__ bias, const float* __restrict__ addsrc,
    float* __restrict__ out, int N, int t)
{
    int n = t / 12;
    if (n >= N) return;
    int c = (t % 12) * 8;
    float di = dinv[n];
    float sn = di * di;
    float f[8], acc[8];
    uint4 sv = *reinterpret_cast<const uint4*>(tmp + (size_t)n * 96 + c);
    bf8_unpack(sv, f);
    #pragma unroll
    for (int i = 0; i < 8; ++i) acc[i] = sn * f[i];
    int e1 = off[n + 1];
    for (int e = off[n]; e < e1; ++e) {
        int2 p = pairs[e];
        float wv = __int_as_float(p.y);
        uint4 hv = *reinterpret_cast<const uint4*>(tmp + (size_t)p.x * 96 + c);
        bf8_unpack(hv, f);
        #pragma unroll
        for (int i = 0; i < 8; ++i) acc[i] = fmaf(wv, f[i], acc[i]);
    }
    float4 bv0 = *reinterpret_cast<const float4*>(bias + c);
    float4 bv1 = *reinterpret_cast<const float4*>(bias + c + 4);
    acc[0] = elu_f(acc[0] + bv0.x);
    acc[1] = elu_f(acc[1] + bv0.y);
    acc[2] = elu_f(acc[2] + bv0.z);
    acc[3] = elu_f(acc[3] + bv0.w);
    acc[4] = elu_f(acc[4] + bv1.x);
    acc[5] = elu_f(acc[5] + bv1.y);
    acc[6] = elu_f(acc[6] + bv1.z);
    acc[7] = elu_f(acc[7] + bv1.w);
    if (addsrc) {
        float4 r0 = *reinterpret_cast<const float4*>(addsrc + (size_t)n * 96 + c);
        float4 r1 = *reinterpret_cast<const float4*>(addsrc + (size_t)n * 96 + c + 4);
        acc[0] += r0.x; acc[1] += r0.y; acc[2] += r0.z; acc[3] += r0.w;
        acc[4] += r1.x; acc[5] += r1.y; acc[6] += r1.z; acc[7] += r1.w;
    }
    float* op = out + (size_t)n * 96 + c;
    *reinterpret_cast<float4*>(op)     = make_float4(acc[0], acc[1], acc[2], acc[3]);
    *reinterpret_cast<float4*>(op + 4) = make_float4(acc[4], acc[5], acc[6], acc[7]);
}

__global__ void k_aggregate(const ushort* __restrict__ tmp, const int* __restrict__ off,
                            const int2* __restrict__ pairs, const float* __restrict__ dinv,
                            const float* __restrict__ bias, const float* __restrict__ addsrc,
                            float* __restrict__ out, int N) {
    agg_body(tmp, off, pairs, dinv, bias, addsrc, out, N,
             blockIdx.x * blockDim.x + threadIdx.x);
}

// ================= hybrid kernels (blockIdx-range dispatch for overlap) =================

// conv1 GEMM (x@Wc1 -> bf16 M1)  ||  degree count (atomics)
__global__ __launch_bounds__(128) void
k_hyb_gemm_count(const float* __restrict__ X, const float* __restrict__ W,
                 ushort* __restrict__ M1, int N,
                 const int* __restrict__ col, int* __restrict__ cnt, int E,
                 int nGemm, int nTot) {
    if ((int)blockIdx.x < nGemm) {
        gemm_body(X, W, nullptr, M1, N, 128, 0, 1, blockIdx.x);
    } else {
        const int stride = (nTot - nGemm) * 128;
        for (int e = ((int)blockIdx.x - nGemm) * 128 + (int)threadIdx.x; e < E; e += stride)
            atomicAdd(&cnt[col[e]], 1);
    }
}

// lin1 GEMM (x@Wl1+b, elu -> C)  ||  CSR fill (atomics + scattered 8B writes)
__global__ __launch_bounds__(128) void
k_hyb_gemm_fill(const float* __restrict__ X, const float* __restrict__ W,
                const float* __restrict__ bias, float* __restrict__ C, int N,
                const int* __restrict__ row, const int* __restrict__ col,
                const float* __restrict__ w, int* __restrict__ cur,
                int2* __restrict__ pairs, int E, int nGemm, int nTot) {
    if ((int)blockIdx.x < nGemm) {
        gemm_body(X, W, bias, C, N, 128, 1, 0, blockIdx.x);
    } else {
        const int stride = (nTot - nGemm) * 128;
        for (int e = ((int)blockIdx.x - nGemm) * 128 + (int)threadIdx.x; e < E; e += stride) {
            int c = col[e];
            int pos = atomicAdd(&cur[c], 1);
            pairs[pos] = make_int2(row[e], __float_as_int(w[e]));
        }
    }
}

// conv2 GEMM (C@Wc2 -> bf16 M2)  ||  conv1 aggregate (M1 -> B)
__global__ __launch_bounds__(128) void
k_hyb_gemm_agg(const float* __restrict__ X, const float* __restrict__ W,
               ushort* __restrict__ M2, int N,
               const ushort* __restrict__ M1, const int* __restrict__ off,
               const int2* __restrict__ pairs, const float* __restrict__ dinv,
               const float* __restrict__ bias, float* __restrict__ B, int nGemm) {
    if ((int)blockIdx.x < nGemm) {
        gemm_body(X, W, nullptr, M2, N, 96, 0, 1, blockIdx.x);
    } else {
        agg_body(M1, off, pairs, dinv, bias, nullptr, B, N,
                 ((int)blockIdx.x - nGemm) * 128 + (int)threadIdx.x);
    }
}

// ================= parallel scan (3 launches) =================

__global__ void k_scan_local(const int* __restrict__ cnt, int* __restrict__ off,
                             int* __restrict__ totals, int N) {
    const int tid = threadIdx.x, lane = tid & 63, wid = tid >> 6;
    __shared__ int ws[4];
    int i = blockIdx.x * 256 + tid;
    int v = (i < N) ? cnt[i] : 0;
    int s = v;
    #pragma unroll
    for (int d = 1; d < 64; d <<= 1) {
        int t = __shfl_up(s, d);
        if (lane >= d) s += t;
    }
    if (lane == 63) ws[wid] = s;
    __syncthreads();
    int wbase = 0;
    #pragma unroll
    for (int k = 0; k < 3; ++k) if (k < wid) wbase += ws[k];
    int excl = s - v + wbase;
    if (i < N) off[i] = excl;
    if (tid == 255) totals[blockIdx.x] = excl + v;
}

__global__ void k_scan_tot(int* __restrict__ totals, int nb, int* __restrict__ offN) {
    const int tid = threadIdx.x, lane = tid & 63, wid = tid >> 6;
    __shared__ int ws[4];
    int v = (tid < nb) ? totals[tid] : 0;
    int s = v;
    #pragma unroll
    for (int d = 1; d < 64; d <<= 1) {
        int t = __shfl_up(s, d);
        if (lane >= d) s += t;
    }
    if (lane == 63) ws[wid] = s;
    __syncthreads();
    int wbase = 0;
    #pragma unroll
    for (int k = 0; k < 3; ++k) if (k < wid) wbase += ws[k];
    int excl = s - v + wbase;
    if (tid < nb) totals[tid] = excl;
    if (tid == nb - 1) offN[0] = excl + v;
}

__global__ void k_scan_add(int* __restrict__ off, const int* __restrict__ totals,
                           int* __restrict__ cur, int N) {
    int i = blockIdx.x * blockDim.x + threadIdx.x;
    if (i < N) {
        int o = off[i] + totals[i >> 8];
        off[i] = o;
        cur[i] = o;
    }
}

// ================= remaining prep =================

__global__ void k_deg_dinv(const int2* __restrict__ pairs, const int* __restrict__ off,
                           float* __restrict__ dinv, int N) {
    int n = blockIdx.x * blockDim.x + threadIdx.x;
    if (n >= N) return;
    float d = 1.0f;
    int e1 = off[n + 1];
    for (int e = off[n]; e < e1; ++e) d += __int_as_float(pairs[e].y);
    dinv[n] = rsqrtf(d);
}

__global__ void k_scale(int2* __restrict__ pairs, const int* __restrict__ off,
                        const float* __restrict__ dinv, int N) {
    int n = blockIdx.x * blockDim.x + threadIdx.x;
    if (n >= N) return;
    const float dn = dinv[n];
    int e1 = off[n + 1];
    for (int e = off[n]; e < e1; ++e) {
        int2 p = pairs[e];
        pairs[e].y = __float_as_int(__int_as_float(p.y) * dinv[p.x] * dn);
    }
}

// ================= final: logits + log_softmax (lane = node) =================
__global__ __launch_bounds__(128) void
k_lin2_lsm(const float* __restrict__ h, const float* __restrict__ W2,
           const float* __restrict__ b2, float* __restrict__ out, int N) {
    __shared__ float hsT[96][128];
    const int tid = threadIdx.x;
    const int n0 = blockIdx.x * 128;
    const int nn = (N - n0 < 128) ? (N - n0) : 128;

    if (tid < nn) {
        const float* hr = h + (size_t)(n0 + tid) * 96;
        #pragma unroll
        for (int q = 0; q < 24; ++q) {
            float4 v = *reinterpret_cast<const float4*>(hr + q * 4);
            hsT[q * 4 + 0][tid] = v.x;
            hsT[q * 4 + 1][tid] = v.y;
            hsT[q * 4 + 2][tid] = v.z;
            hsT[q * 4 + 3][tid] = v.w;
        }
    }
    __syncthreads();

    float acc[40];
    #pragma unroll
    for (int c = 0; c < 40; ++c) acc[c] = b2[c];
    for (int k = 0; k < 96; ++k) {
        const float hv = hsT[k][tid];
        const float* wr = W2 + k * 40;
        #pragma unroll
        for (int c = 0; c < 40; ++c) acc[c] = fmaf(hv, wr[c], acc[c]);
    }

    float m = acc[0];
    #pragma unroll
    for (int c = 1; c < 40; ++c) m = fmaxf(m, acc[c]);
    float s = 0.f;
    #pragma unroll
    for (int c = 0; c < 40; ++c) s += expf(acc[c] - m);
    const float lse = m + logf(s);

    if (tid < nn) {
        float* op = out + (size_t)(n0 + tid) * 40;
        #pragma unroll
        for (int q = 0; q < 10; ++q) {
            float4 v = make_float4(acc[q * 4 + 0] - lse, acc[q * 4 + 1] - lse,
                                   acc[q * 4 + 2] - lse, acc[q * 4 + 3] - lse);
            *reinterpret_cast<float4*>(op + q * 4) = v;
        }
    }
}

// ================= launch =================

extern "C" void kernel_launch(void* const* d_in, const int* in_sizes, int n_in,
                              void* d_out, int out_size, void* d_ws, size_t ws_size,
                              hipStream_t stream) {
    const float* x   = (const float*)d_in[0];
    const int*   ei  = (const int*)d_in[1];
    const float* ew  = (const float*)d_in[2];
    const float* Wc1 = (const float*)d_in[3];
    const float* bc1 = (const float*)d_in[4];
    const float* Wc2 = (const float*)d_in[5];
    const float* bc2 = (const float*)d_in[6];
    const float* Wc3 = (const float*)d_in[7];
    const float* bc3 = (const float*)d_in[8];
    const float* Wl1 = (const float*)d_in[9];
    const float* bl1 = (const float*)d_in[10];
    const float* Wl2 = (const float*)d_in[11];
    const float* bl2 = (const float*)d_in[12];

    const int FIN = 128, HID = 96;
    const int N = in_sizes[0] / FIN;
    const int E = in_sizes[2];
    const int* row = ei;
    const int* col = ei + E;

    char* ws = (char*)d_ws;
    size_t o = 0;
    auto alloc = [&](size_t bytes) -> void* {
        void* p = ws + o;
        o += (bytes + 255) & ~(size_t)255;
        return p;
    };
    float*  dinv   = (float*)alloc((size_t)N * 4);
    int*    cnt    = (int*)  alloc((size_t)N * 4);
    int*    off    = (int*)  alloc((size_t)(N + 1) * 4);
    int*    cur    = (int*)  alloc((size_t)N * 4);
    int*    totals = (int*)  alloc(1024);
    int2*   pairs  = (int2*) alloc((size_t)E * 8);
    ushort* M1     = (ushort*)alloc((size_t)N * HID * 2);
    ushort* M2     = (ushort*)alloc((size_t)N * HID * 2);
    float*  B      = (float*)alloc((size_t)N * HID * 4);
    float*  C      = (float*)alloc((size_t)N * HID * 4);

    const int nGemm   = (N + GBM - 1) / GBM;                 // 782
    const int nSide   = 448;                                 // grid-stride edge blocks
    const int nScanL  = (N + 255) / 256;                     // 196
    const int nAdd    = (N + 127) / 128;                     // 391
    const int nAgg128 = (N * 12 + 127) / 128;                // 4688
    const int nAgg256 = (N * 12 + 255) / 256;                // 2344

    hipMemsetAsync(cnt, 0, (size_t)N * 4, stream);

    // conv1 GEMM || count
    k_hyb_gemm_count<<<nGemm + nSide, 128, 0, stream>>>(
        x, Wc1, M1, N, col, cnt, E, nGemm, nGemm + nSide);

    // parallel scan -> off, cur
    k_scan_local<<<nScanL, 256, 0, stream>>>(cnt, off, totals, N);
    k_scan_tot<<<1, 256, 0, stream>>>(totals, nScanL, off + N);
    k_scan_add<<<nAdd, 128, 0, stream>>>(off, totals, cur, N);

    // lin1 GEMM || CSR fill
    k_hyb_gemm_fill<<<nGemm + nSide, 128, 0, stream>>>(
        x, Wl1, bl1, C, N, row, col, ew, cur, pairs, E, nGemm, nGemm + nSide);

    k_deg_dinv<<<nAdd, 128, 0, stream>>>(pairs, off, dinv, N);
    k_scale<<<nAdd, 128, 0, stream>>>(pairs, off, dinv, N);

    // conv2 GEMM || conv1 aggregate
    k_hyb_gemm_agg<<<nGemm + nAgg128, 128, 0, stream>>>(
        C, Wc2, M2, N, M1, off, pairs, dinv, bc1, B, nGemm);

    // conv2 aggregate -> C
    k_aggregate<<<nAgg256, 256, 0, stream>>>(M2, off, pairs, dinv, bc2, nullptr, C, N);

    // conv3 GEMM -> M1
    k_gemm<<<nGemm, 128, 0, stream>>>(C, Wc3, nullptr, M1, N, HID, 0, 1);

    // conv3 aggregate (+residual B) -> C
    k_aggregate<<<nAgg256, 256, 0, stream>>>(M1, off, pairs, dinv, bc3, B, C, N);

    // lin2 + log_softmax
    k_lin2_lsm<<<(N + 127) / 128, 128, 0, stream>>>(C, Wl2, bl2, (float*)d_out, N);
}

// Round 7
// 389.457 us; speedup vs baseline: 2.0247x; 1.1019x over previous
//
#include <hip/hip_runtime.h>
#include <hip/hip_bf16.h>

static __device__ __forceinline__ float elu_f(float x) {
    return x > 0.f ? x : expm1f(x);
}

static __device__ __forceinline__ ushort f2bf(float x) {
    __hip_bfloat16 h = __float2bfloat16(x);
    ushort u;
    __builtin_memcpy(&u, &h, 2);
    return u;
}

// ================= GEMM: out[N,96] = X[N,K]@W[K,96] (+bias)(+elu) =================
// BM=64, 128 threads, per-thread 8 rows x 6 cols (48 FMA per k-step).
// Double-buffered LDS; X-tile transposed [k][row].
#define GBM 64
#define GBK 16

__global__ __launch_bounds__(128) void
k_gemm(const float* __restrict__ X, const float* __restrict__ W,
       const float* __restrict__ bias, void* __restrict__ outp,
       int N, int K, int act, int obf16) {
    __shared__ float Xs[2][GBK][GBM];   // 8 KiB
    __shared__ float Ws[2][GBK][96];    // 12 KiB
    const int tid  = threadIdx.x;
    const int rg   = tid >> 4;          // 0..7  -> rows rg*8..+7
    const int cg   = tid & 15;          // 0..15 -> cols cg*6..+5
    const int srow = tid & 63;
    const int skq  = tid >> 6;          // 0..1
    const int n0   = blockIdx.x * GBM;
    const int KT   = K >> 4;

    float acc[8][6];
    #pragma unroll
    for (int j = 0; j < 6; ++j) {
        const float b = bias ? bias[cg * 6 + j] : 0.f;
        #pragma unroll
        for (int r = 0; r < 8; ++r) acc[r][j] = b;
    }

    const int nload = (n0 + srow < N) ? (n0 + srow) : (N - 1);
    const float* xrow = X + (size_t)nload * K;

    // prologue: stage k-tile 0
    #pragma unroll
    for (int q = 0; q < 2; ++q) {
        const int k = (skq + 2 * q) * 4;
        float4 v = *reinterpret_cast<const float4*>(xrow + k);
        Xs[0][k + 0][srow] = v.x; Xs[0][k + 1][srow] = v.y;
        Xs[0][k + 2][srow] = v.z; Xs[0][k + 3][srow] = v.w;
    }
    #pragma unroll
    for (int p = 0; p < 3; ++p) {
        const int i4 = tid + p * 128;    // 384 float4s = 16x96
        float4 v = *reinterpret_cast<const float4*>(W + (size_t)i4 * 4);
        *reinterpret_cast<float4*>(&Ws[0][0][0] + i4 * 4) = v;
    }
    __syncthreads();

    int cb = 0;
    for (int kt = 0; kt < KT; ++kt) {
        const bool more = (kt + 1 < KT);
        float4 xn0, xn1, wn0, wn1, wn2;
        if (more) {
            const int kb = (kt + 1) * GBK;
            xn0 = *reinterpret_cast<const float4*>(xrow + kb + skq * 4);
            xn1 = *reinterpret_cast<const float4*>(xrow + kb + (skq + 2) * 4);
            const float* wb = W + (size_t)kb * 96;
            wn0 = *reinterpret_cast<const float4*>(wb + (size_t)(tid      ) * 4);
            wn1 = *reinterpret_cast<const float4*>(wb + (size_t)(tid + 128) * 4);
            wn2 = *reinterpret_cast<const float4*>(wb + (size_t)(tid + 256) * 4);
        }
        #pragma unroll
        for (int ki = 0; ki < GBK; ++ki) {
            float4 xa = *reinterpret_cast<const float4*>(&Xs[cb][ki][rg * 8]);
            float4 xb = *reinterpret_cast<const float4*>(&Xs[cb][ki][rg * 8 + 4]);
            float2 w01 = *reinterpret_cast<const float2*>(&Ws[cb][ki][cg * 6]);
            float2 w23 = *reinterpret_cast<const float2*>(&Ws[cb][ki][cg * 6 + 2]);
            float2 w45 = *reinterpret_cast<const float2*>(&Ws[cb][ki][cg * 6 + 4]);
            const float xs[8] = {xa.x, xa.y, xa.z, xa.w, xb.x, xb.y, xb.z, xb.w};
            const float wv[6] = {w01.x, w01.y, w23.x, w23.y, w45.x, w45.y};
            #pragma unroll
            for (int r = 0; r < 8; ++r)
                #pragma unroll
                for (int j = 0; j < 6; ++j)
                    acc[r][j] = fmaf(xs[r], wv[j], acc[r][j]);
        }
        if (more) {
            const int nb = cb ^ 1;
            const int k = skq * 4, k2 = (skq + 2) * 4;
            Xs[nb][k  + 0][srow] = xn0.x; Xs[nb][k  + 1][srow] = xn0.y;
            Xs[nb][k  + 2][srow] = xn0.z; Xs[nb][k  + 3][srow] = xn0.w;
            Xs[nb][k2 + 0][srow] = xn1.x; Xs[nb][k2 + 1][srow] = xn1.y;
            Xs[nb][k2 + 2][srow] = xn1.z; Xs[nb][k2 + 3][srow] = xn1.w;
            *reinterpret_cast<float4*>(&Ws[nb][0][0] + (size_t)(tid      ) * 4) = wn0;
            *reinterpret_cast<float4*>(&Ws[nb][0][0] + (size_t)(tid + 128) * 4) = wn1;
            *reinterpret_cast<float4*>(&Ws[nb][0][0] + (size_t)(tid + 256) * 4) = wn2;
            cb = nb;
        }
        __syncthreads();
    }

    #pragma unroll
    for (int r = 0; r < 8; ++r) {
        const int n = n0 + rg * 8 + r;
        if (n < N) {
            float a[6];
            #pragma unroll
            for (int j = 0; j < 6; ++j) { a[j] = acc[r][j]; if (act) a[j] = elu_f(a[j]); }
            if (obf16) {
                uint* op = (uint*)((ushort*)outp + (size_t)n * 96 + cg * 6);
                op[0] = (uint)f2bf(a[0]) | ((uint)f2bf(a[1]) << 16);
                op[1] = (uint)f2bf(a[2]) | ((uint)f2bf(a[3]) << 16);
                op[2] = (uint)f2bf(a[4]) | ((uint)f2bf(a[5]) << 16);
            } else {
                float* op = (float*)outp + (size_t)n * 96 + cg * 6;
                *reinterpret_cast<float2*>(op)     = make_float2(a[0], a[1]);
                *reinterpret_cast<float2*>(op + 2) = make_float2(a[2], a[3]);
                *reinterpret_cast<float2*>(op + 4) = make_float2(a[4], a[5]);
            }
        }
    }
}

// ================= aggregation (bf16 message table, CSR gather) =================
static __device__ __forceinline__ void bf8_unpack(uint4 v, float* f) {
    f[0] = __uint_as_float(v.x << 16);
    f[1] = __uint_as_float(v.x & 0xffff0000u);
    f[2] = __uint_as_float(v.y << 16);
    f[3] = __uint_as_float(v.y & 0xffff0000u);
    f[4] = __uint_as_float(v.z << 16);
    f[5] = __uint_as_float(v.z & 0xffff0000u);
    f[6] = __uint_as_float(v.w << 16);
    f[7] = __uint_as_float(v.w & 0xffff0000u);
}

__global__ void k_aggregate(const ushort* __restrict__ tmp, const int* __restrict__ off,
                            const int2* __restrict__ pairs, const float* __restrict__ dinv,
                            const float* __restrict__ bias, const float* __restrict__ addsrc,
                            float* __restrict__ out, int N) {
    int t = blockIdx.x * blockDim.x + threadIdx.x;
    int n = t / 12;
    if (n >= N) return;
    int c = (t % 12) * 8;
    float di = dinv[n];
    float sn = di * di;    // self-loop norm
    float f[8], acc[8];
    uint4 sv = *reinterpret_cast<const uint4*>(tmp + (size_t)n * 96 + c);
    bf8_unpack(sv, f);
    #pragma unroll
    for (int i = 0; i < 8; ++i) acc[i] = sn * f[i];
    int e1 = off[n + 1];
    for (int e = off[n]; e < e1; ++e) {
        int2 p = pairs[e];
        float wv = __int_as_float(p.y);
        uint4 hv = *reinterpret_cast<const uint4*>(tmp + (size_t)p.x * 96 + c);
        bf8_unpack(hv, f);
        #pragma unroll
        for (int i = 0; i < 8; ++i) acc[i] = fmaf(wv, f[i], acc[i]);
    }
    float4 bv0 = *reinterpret_cast<const float4*>(bias + c);
    float4 bv1 = *reinterpret_cast<const float4*>(bias + c + 4);
    acc[0] = elu_f(acc[0] + bv0.x);
    acc[1] = elu_f(acc[1] + bv0.y);
    acc[2] = elu_f(acc[2] + bv0.z);
    acc[3] = elu_f(acc[3] + bv0.w);
    acc[4] = elu_f(acc[4] + bv1.x);
    acc[5] = elu_f(acc[5] + bv1.y);
    acc[6] = elu_f(acc[6] + bv1.z);
    acc[7] = elu_f(acc[7] + bv1.w);
    if (addsrc) {
        float4 r0 = *reinterpret_cast<const float4*>(addsrc + (size_t)n * 96 + c);
        float4 r1 = *reinterpret_cast<const float4*>(addsrc + (size_t)n * 96 + c + 4);
        acc[0] += r0.x; acc[1] += r0.y; acc[2] += r0.z; acc[3] += r0.w;
        acc[4] += r1.x; acc[5] += r1.y; acc[6] += r1.z; acc[7] += r1.w;
    }
    float* op = out + (size_t)n * 96 + c;
    *reinterpret_cast<float4*>(op)     = make_float4(acc[0], acc[1], acc[2], acc[3]);
    *reinterpret_cast<float4*>(op + 4) = make_float4(acc[4], acc[5], acc[6], acc[7]);
}

// ================= graph prep =================

__global__ void k_count(const int* __restrict__ col, int* __restrict__ cnt, int E) {
    int e = blockIdx.x * blockDim.x + threadIdx.x;
    if (e < E) atomicAdd(&cnt[col[e]], 1);
}

__global__ void k_fill(const int* __restrict__ row, const int* __restrict__ col,
                       const float* __restrict__ w, int* __restrict__ cur,
                       int2* __restrict__ pairs, int E) {
    int e = blockIdx.x * blockDim.x + threadIdx.x;
    if (e < E) {
        int c = col[e];
        int pos = atomicAdd(&cur[c], 1);
        pairs[pos] = make_int2(row[e], __float_as_int(w[e]));
    }
}

__global__ void k_deg_dinv(const int2* __restrict__ pairs, const int* __restrict__ off,
                           float* __restrict__ dinv, int N) {
    int n = blockIdx.x * blockDim.x + threadIdx.x;
    if (n >= N) return;
    float d = 1.0f;
    int e1 = off[n + 1];
    for (int e = off[n]; e < e1; ++e) d += __int_as_float(pairs[e].y);
    dinv[n] = rsqrtf(d);
}

__global__ void k_scale(int2* __restrict__ pairs, const int* __restrict__ off,
                        const float* __restrict__ dinv, int N) {
    int n = blockIdx.x * blockDim.x + threadIdx.x;
    if (n >= N) return;
    const float dn = dinv[n];
    int e1 = off[n + 1];
    for (int e = off[n]; e < e1; ++e) {
        int2 p = pairs[e];
        pairs[e].y = __float_as_int(__int_as_float(p.y) * dinv[p.x] * dn);
    }
}

// ================= parallel scan (3 launches) =================

__global__ void k_scan_local(const int* __restrict__ cnt, int* __restrict__ off,
                             int* __restrict__ totals, int N) {
    const int tid = threadIdx.x, lane = tid & 63, wid = tid >> 6;
    __shared__ int ws[4];
    int i = blockIdx.x * 256 + tid;
    int v = (i < N) ? cnt[i] : 0;
    int s = v;
    #pragma unroll
    for (int d = 1; d < 64; d <<= 1) {
        int t = __shfl_up(s, d);
        if (lane >= d) s += t;
    }
    if (lane == 63) ws[wid] = s;
    __syncthreads();
    int wbase = 0;
    #pragma unroll
    for (int k = 0; k < 3; ++k) if (k < wid) wbase += ws[k];
    int excl = s - v + wbase;
    if (i < N) off[i] = excl;
    if (tid == 255) totals[blockIdx.x] = excl + v;
}

__global__ void k_scan_tot(int* __restrict__ totals, int nb, int* __restrict__ offN) {
    const int tid = threadIdx.x, lane = tid & 63, wid = tid >> 6;
    __shared__ int ws[4];
    int v = (tid < nb) ? totals[tid] : 0;
    int s = v;
    #pragma unroll
    for (int d = 1; d < 64; d <<= 1) {
        int t = __shfl_up(s, d);
        if (lane >= d) s += t;
    }
    if (lane == 63) ws[wid] = s;
    __syncthreads();
    int wbase = 0;
    #pragma unroll
    for (int k = 0; k < 3; ++k) if (k < wid) wbase += ws[k];
    int excl = s - v + wbase;
    if (tid < nb) totals[tid] = excl;
    if (tid == nb - 1) offN[0] = excl + v;
}

__global__ void k_scan_add(int* __restrict__ off, const int* __restrict__ totals,
                           int* __restrict__ cur, int N) {
    int i = blockIdx.x * blockDim.x + threadIdx.x;
    if (i < N) {
        int o = off[i] + totals[i >> 8];
        off[i] = o;
        cur[i] = o;
    }
}

// ================= final: logits + log_softmax (lane = node) =================
__global__ __launch_bounds__(128) void
k_lin2_lsm(const float* __restrict__ h, const float* __restrict__ W2,
           const float* __restrict__ b2, float* __restrict__ out, int N) {
    __shared__ float hsT[96][128];
    const int tid = threadIdx.x;
    const int n0 = blockIdx.x * 128;
    const int nn = (N - n0 < 128) ? (N - n0) : 128;

    if (tid < nn) {
        const float* hr = h + (size_t)(n0 + tid) * 96;
        #pragma unroll
        for (int q = 0; q < 24; ++q) {
            float4 v = *reinterpret_cast<const float4*>(hr + q * 4);
            hsT[q * 4 + 0][tid] = v.x;
            hsT[q * 4 + 1][tid] = v.y;
            hsT[q * 4 + 2][tid] = v.z;
            hsT[q * 4 + 3][tid] = v.w;
        }
    }
    __syncthreads();

    float acc[40];
    #pragma unroll
    for (int c = 0; c < 40; ++c) acc[c] = b2[c];
    for (int k = 0; k < 96; ++k) {
        const float hv = hsT[k][tid];
        const float* wr = W2 + k * 40;
        #pragma unroll
        for (int c = 0; c < 40; ++c) acc[c] = fmaf(hv, wr[c], acc[c]);
    }

    float m = acc[0];
    #pragma unroll
    for (int c = 1; c < 40; ++c) m = fmaxf(m, acc[c]);
    float s = 0.f;
    #pragma unroll
    for (int c = 0; c < 40; ++c) s += expf(acc[c] - m);
    const float lse = m + logf(s);

    if (tid < nn) {
        float* op = out + (size_t)(n0 + tid) * 40;
        #pragma unroll
        for (int q = 0; q < 10; ++q) {
            float4 v = make_float4(acc[q * 4 + 0] - lse, acc[q * 4 + 1] - lse,
                                   acc[q * 4 + 2] - lse, acc[q * 4 + 3] - lse);
            *reinterpret_cast<float4*>(op + q * 4) = v;
        }
    }
}

// ================= launch =================

extern "C" void kernel_launch(void* const* d_in, const int* in_sizes, int n_in,
                              void* d_out, int out_size, void* d_ws, size_t ws_size,
                              hipStream_t stream) {
    const float* x   = (const float*)d_in[0];
    const int*   ei  = (const int*)d_in[1];
    const float* ew  = (const float*)d_in[2];
    const float* Wc1 = (const float*)d_in[3];
    const float* bc1 = (const float*)d_in[4];
    const float* Wc2 = (const float*)d_in[5];
    const float* bc2 = (const float*)d_in[6];
    const float* Wc3 = (const float*)d_in[7];
    const float* bc3 = (const float*)d_in[8];
    const float* Wl1 = (const float*)d_in[9];
    const float* bl1 = (const float*)d_in[10];
    const float* Wl2 = (const float*)d_in[11];
    const float* bl2 = (const float*)d_in[12];

    const int FIN = 128, HID = 96;
    const int N = in_sizes[0] / FIN;
    const int E = in_sizes[2];
    const int* row = ei;
    const int* col = ei + E;

    char* ws = (char*)d_ws;
    size_t o = 0;
    auto alloc = [&](size_t bytes) -> void* {
        void* p = ws + o;
        o += (bytes + 255) & ~(size_t)255;
        return p;
    };
    float*  dinv   = (float*)alloc((size_t)N * 4);
    int*    cnt    = (int*)  alloc((size_t)N * 4);
    int*    off    = (int*)  alloc((size_t)(N + 1) * 4);
    int*    cur    = (int*)  alloc((size_t)N * 4);
    int*    totals = (int*)  alloc(1024);
    int2*   pairs  = (int2*) alloc((size_t)E * 8);
    ushort* M1     = (ushort*)alloc((size_t)N * HID * 2);
    ushort* M2     = (ushort*)alloc((size_t)N * HID * 2);
    float*  B      = (float*)alloc((size_t)N * HID * 4);
    float*  C      = (float*)alloc((size_t)N * HID * 4);

    const int gE      = (E + 255) / 256;
    const int nGemm   = (N + GBM - 1) / GBM;
    const int nScanL  = (N + 255) / 256;
    const int nAdd    = (N + 127) / 128;
    const int nAgg256 = (N * 12 + 255) / 256;

    // graph prep
    hipMemsetAsync(cnt, 0, (size_t)N * 4, stream);
    k_count<<<gE, 256, 0, stream>>>(col, cnt, E);
    k_scan_local<<<nScanL, 256, 0, stream>>>(cnt, off, totals, N);
    k_scan_tot<<<1, 256, 0, stream>>>(totals, nScanL, off + N);
    k_scan_add<<<nAdd, 128, 0, stream>>>(off, totals, cur, N);
    k_fill<<<gE, 256, 0, stream>>>(row, col, ew, cur, pairs, E);
    k_deg_dinv<<<nAdd, 128, 0, stream>>>(pairs, off, dinv, N);
    k_scale<<<nAdd, 128, 0, stream>>>(pairs, off, dinv, N);

    // conv1 GEMM + lin1 GEMM (both read x)
    k_gemm<<<nGemm, 128, 0, stream>>>(x, Wc1, nullptr, M1, N, FIN, 0, 1);
    k_gemm<<<nGemm, 128, 0, stream>>>(x, Wl1, bl1, C, N, FIN, 1, 0);

    // conv1 aggregate -> B (residual)
    k_aggregate<<<nAgg256, 256, 0, stream>>>(M1, off, pairs, dinv, bc1, nullptr, B, N);

    // conv2
    k_gemm<<<nGemm, 128, 0, stream>>>(C, Wc2, nullptr, M2, N, HID, 0, 1);
    k_aggregate<<<nAgg256, 256, 0, stream>>>(M2, off, pairs, dinv, bc2, nullptr, C, N);

    // conv3 (+residual B)
    k_gemm<<<nGemm, 128, 0, stream>>>(C, Wc3, nullptr, M1, N, HID, 0, 1);
    k_aggregate<<<nAgg256, 256, 0, stream>>>(M1, off, pairs, dinv, bc3, B, C, N);

    // lin2 + log_softmax
    k_lin2_lsm<<<(N + 127) / 128, 128, 0, stream>>>(C, Wl2, bl2, (float*)d_out, N);
}

// Round 8
// 364.516 us; speedup vs baseline: 2.1632x; 1.0684x over previous
//
#include <hip/hip_runtime.h>
#include <hip/hip_bf16.h>

static __device__ __forceinline__ float elu_f(float x) {
    return x > 0.f ? x : expm1f(x);
}

static __device__ __forceinline__ ushort f2bf(float x) {
    __hip_bfloat16 h = __float2bfloat16(x);
    ushort u;
    __builtin_memcpy(&u, &h, 2);
    return u;
}

// ================= GEMM: out[N,96] = X[N,K]@W[K,96] (+bias)(+elu) =================
// BM=64, 128 threads, per-thread 8 rows x 6 cols (48 FMA per k-step).
// Double-buffered LDS; X-tile transposed [k][row].
#define GBM 64
#define GBK 16

__global__ __launch_bounds__(128) void
k_gemm(const float* __restrict__ X, const float* __restrict__ W,
       const float* __restrict__ bias, void* __restrict__ outp,
       int N, int K, int act, int obf16) {
    __shared__ float Xs[2][GBK][GBM];   // 8 KiB
    __shared__ float Ws[2][GBK][96];    // 12 KiB
    const int tid  = threadIdx.x;
    const int rg   = tid >> 4;          // 0..7  -> rows rg*8..+7
    const int cg   = tid & 15;          // 0..15 -> cols cg*6..+5
    const int srow = tid & 63;
    const int skq  = tid >> 6;          // 0..1
    const int n0   = blockIdx.x * GBM;
    const int KT   = K >> 4;

    float acc[8][6];
    #pragma unroll
    for (int j = 0; j < 6; ++j) {
        const float b = bias ? bias[cg * 6 + j] : 0.f;
        #pragma unroll
        for (int r = 0; r < 8; ++r) acc[r][j] = b;
    }

    const int nload = (n0 + srow < N) ? (n0 + srow) : (N - 1);
    const float* xrow = X + (size_t)nload * K;

    // prologue: stage k-tile 0
    #pragma unroll
    for (int q = 0; q < 2; ++q) {
        const int k = (skq + 2 * q) * 4;
        float4 v = *reinterpret_cast<const float4*>(xrow + k);
        Xs[0][k + 0][srow] = v.x; Xs[0][k + 1][srow] = v.y;
        Xs[0][k + 2][srow] = v.z; Xs[0][k + 3][srow] = v.w;
    }
    #pragma unroll
    for (int p = 0; p < 3; ++p) {
        const int i4 = tid + p * 128;    // 384 float4s = 16x96
        float4 v = *reinterpret_cast<const float4*>(W + (size_t)i4 * 4);
        *reinterpret_cast<float4*>(&Ws[0][0][0] + i4 * 4) = v;
    }
    __syncthreads();

    int cb = 0;
    for (int kt = 0; kt < KT; ++kt) {
        const bool more = (kt + 1 < KT);
        float4 xn0, xn1, wn0, wn1, wn2;
        if (more) {
            const int kb = (kt + 1) * GBK;
            xn0 = *reinterpret_cast<const float4*>(xrow + kb + skq * 4);
            xn1 = *reinterpret_cast<const float4*>(xrow + kb + (skq + 2) * 4);
            const float* wb = W + (size_t)kb * 96;
            wn0 = *reinterpret_cast<const float4*>(wb + (size_t)(tid      ) * 4);
            wn1 = *reinterpret_cast<const float4*>(wb + (size_t)(tid + 128) * 4);
            wn2 = *reinterpret_cast<const float4*>(wb + (size_t)(tid + 256) * 4);
        }
        #pragma unroll
        for (int ki = 0; ki < GBK; ++ki) {
            float4 xa = *reinterpret_cast<const float4*>(&Xs[cb][ki][rg * 8]);
            float4 xb = *reinterpret_cast<const float4*>(&Xs[cb][ki][rg * 8 + 4]);
            float2 w01 = *reinterpret_cast<const float2*>(&Ws[cb][ki][cg * 6]);
            float2 w23 = *reinterpret_cast<const float2*>(&Ws[cb][ki][cg * 6 + 2]);
            float2 w45 = *reinterpret_cast<const float2*>(&Ws[cb][ki][cg * 6 + 4]);
            const float xs[8] = {xa.x, xa.y, xa.z, xa.w, xb.x, xb.y, xb.z, xb.w};
            const float wv[6] = {w01.x, w01.y, w23.x, w23.y, w45.x, w45.y};
            #pragma unroll
            for (int r = 0; r < 8; ++r)
                #pragma unroll
                for (int j = 0; j < 6; ++j)
                    acc[r][j] = fmaf(xs[r], wv[j], acc[r][j]);
        }
        if (more) {
            const int nb = cb ^ 1;
            const int k = skq * 4, k2 = (skq + 2) * 4;
            Xs[nb][k  + 0][srow] = xn0.x; Xs[nb][k  + 1][srow] = xn0.y;
            Xs[nb][k  + 2][srow] = xn0.z; Xs[nb][k  + 3][srow] = xn0.w;
            Xs[nb][k2 + 0][srow] = xn1.x; Xs[nb][k2 + 1][srow] = xn1.y;
            Xs[nb][k2 + 2][srow] = xn1.z; Xs[nb][k2 + 3][srow] = xn1.w;
            *reinterpret_cast<float4*>(&Ws[nb][0][0] + (size_t)(tid      ) * 4) = wn0;
            *reinterpret_cast<float4*>(&Ws[nb][0][0] + (size_t)(tid + 128) * 4) = wn1;
            *reinterpret_cast<float4*>(&Ws[nb][0][0] + (size_t)(tid + 256) * 4) = wn2;
            cb = nb;
        }
        __syncthreads();
    }

    #pragma unroll
    for (int r = 0; r < 8; ++r) {
        const int n = n0 + rg * 8 + r;
        if (n < N) {
            float a[6];
            #pragma unroll
            for (int j = 0; j < 6; ++j) { a[j] = acc[r][j]; if (act) a[j] = elu_f(a[j]); }
            if (obf16) {
                uint* op = (uint*)((ushort*)outp + (size_t)n * 96 + cg * 6);
                op[0] = (uint)f2bf(a[0]) | ((uint)f2bf(a[1]) << 16);
                op[1] = (uint)f2bf(a[2]) | ((uint)f2bf(a[3]) << 16);
                op[2] = (uint)f2bf(a[4]) | ((uint)f2bf(a[5]) << 16);
            } else {
                float* op = (float*)outp + (size_t)n * 96 + cg * 6;
                *reinterpret_cast<float2*>(op)     = make_float2(a[0], a[1]);
                *reinterpret_cast<float2*>(op + 2) = make_float2(a[2], a[3]);
                *reinterpret_cast<float2*>(op + 4) = make_float2(a[4], a[5]);
            }
        }
    }
}

// ================= aggregation (bf16 message table, CSR gather) =================
// Depth-3 software pipeline: keep 3 (pair, row) stages in flight so the
// pairs[e] -> tmp[src] dependent-gather latency overlaps the FMA consume.
static __device__ __forceinline__ void bf8_unpack(uint4 v, float* f) {
    f[0] = __uint_as_float(v.x << 16);
    f[1] = __uint_as_float(v.x & 0xffff0000u);
    f[2] = __uint_as_float(v.y << 16);
    f[3] = __uint_as_float(v.y & 0xffff0000u);
    f[4] = __uint_as_float(v.z << 16);
    f[5] = __uint_as_float(v.z & 0xffff0000u);
    f[6] = __uint_as_float(v.w << 16);
    f[7] = __uint_as_float(v.w & 0xffff0000u);
}

__global__ __launch_bounds__(256) void
k_aggregate(const ushort* __restrict__ tmp, const int* __restrict__ off,
            const int2* __restrict__ pairs, const float* __restrict__ dinv,
            const float* __restrict__ bias, const float* __restrict__ addsrc,
            float* __restrict__ out, int N) {
    int t = blockIdx.x * blockDim.x + threadIdx.x;
    int n = t / 12;
    if (n >= N) return;
    const int c = (t % 12) * 8;
    const ushort* base = tmp + c;

    float di = dinv[n];
    float sn = di * di;    // self-loop norm
    float f[8], acc[8];
    uint4 sv = *reinterpret_cast<const uint4*>(base + (size_t)n * 96);
    bf8_unpack(sv, f);
    #pragma unroll
    for (int i = 0; i < 8; ++i) acc[i] = sn * f[i];

    const int e0 = off[n];
    const int e1 = off[n + 1];
    const int m  = e1 - e0;

    int2 pA, pB, pC;
    uint4 hA, hB, hC;
    if (m > 0) { pA = pairs[e0];     hA = *reinterpret_cast<const uint4*>(base + (size_t)pA.x * 96); }
    if (m > 1) { pB = pairs[e0 + 1]; hB = *reinterpret_cast<const uint4*>(base + (size_t)pB.x * 96); }
    if (m > 2) { pC = pairs[e0 + 2]; hC = *reinterpret_cast<const uint4*>(base + (size_t)pC.x * 96); }

    for (int e = e0 + 3; e < e1; ++e) {
        int2 pD = pairs[e];
        uint4 hD = *reinterpret_cast<const uint4*>(base + (size_t)pD.x * 96);
        float w = __int_as_float(pA.y);
        bf8_unpack(hA, f);
        #pragma unroll
        for (int i = 0; i < 8; ++i) acc[i] = fmaf(w, f[i], acc[i]);
        pA = pB; hA = hB;
        pB = pC; hB = hC;
        pC = pD; hC = hD;
    }
    if (m > 0) {
        float w = __int_as_float(pA.y);
        bf8_unpack(hA, f);
        #pragma unroll
        for (int i = 0; i < 8; ++i) acc[i] = fmaf(w, f[i], acc[i]);
    }
    if (m > 1) {
        float w = __int_as_float(pB.y);
        bf8_unpack(hB, f);
        #pragma unroll
        for (int i = 0; i < 8; ++i) acc[i] = fmaf(w, f[i], acc[i]);
    }
    if (m > 2) {
        float w = __int_as_float(pC.y);
        bf8_unpack(hC, f);
        #pragma unroll
        for (int i = 0; i < 8; ++i) acc[i] = fmaf(w, f[i], acc[i]);
    }

    float4 bv0 = *reinterpret_cast<const float4*>(bias + c);
    float4 bv1 = *reinterpret_cast<const float4*>(bias + c + 4);
    acc[0] = elu_f(acc[0] + bv0.x);
    acc[1] = elu_f(acc[1] + bv0.y);
    acc[2] = elu_f(acc[2] + bv0.z);
    acc[3] = elu_f(acc[3] + bv0.w);
    acc[4] = elu_f(acc[4] + bv1.x);
    acc[5] = elu_f(acc[5] + bv1.y);
    acc[6] = elu_f(acc[6] + bv1.z);
    acc[7] = elu_f(acc[7] + bv1.w);
    if (addsrc) {
        float4 r0 = *reinterpret_cast<const float4*>(addsrc + (size_t)n * 96 + c);
        float4 r1 = *reinterpret_cast<const float4*>(addsrc + (size_t)n * 96 + c + 4);
        acc[0] += r0.x; acc[1] += r0.y; acc[2] += r0.z; acc[3] += r0.w;
        acc[4] += r1.x; acc[5] += r1.y; acc[6] += r1.z; acc[7] += r1.w;
    }
    float* op = out + (size_t)n * 96 + c;
    *reinterpret_cast<float4*>(op)     = make_float4(acc[0], acc[1], acc[2], acc[3]);
    *reinterpret_cast<float4*>(op + 4) = make_float4(acc[4], acc[5], acc[6], acc[7]);
}

// ================= graph prep =================

__global__ void k_count(const int* __restrict__ col, int* __restrict__ cnt, int E) {
    int e = blockIdx.x * blockDim.x + threadIdx.x;
    if (e < E) atomicAdd(&cnt[col[e]], 1);
}

__global__ void k_fill(const int* __restrict__ row, const int* __restrict__ col,
                       const float* __restrict__ w, int* __restrict__ cur,
                       int2* __restrict__ pairs, int E) {
    int e = blockIdx.x * blockDim.x + threadIdx.x;
    if (e < E) {
        int c = col[e];
        int pos = atomicAdd(&cur[c], 1);
        pairs[pos] = make_int2(row[e], __float_as_int(w[e]));
    }
}

__global__ void k_deg_dinv(const int2* __restrict__ pairs, const int* __restrict__ off,
                           float* __restrict__ dinv, int N) {
    int n = blockIdx.x * blockDim.x + threadIdx.x;
    if (n >= N) return;
    float d = 1.0f;
    int e1 = off[n + 1];
    for (int e = off[n]; e < e1; ++e) d += __int_as_float(pairs[e].y);
    dinv[n] = rsqrtf(d);
}

__global__ void k_scale(int2* __restrict__ pairs, const int* __restrict__ off,
                        const float* __restrict__ dinv, int N) {
    int n = blockIdx.x * blockDim.x + threadIdx.x;
    if (n >= N) return;
    const float dn = dinv[n];
    int e1 = off[n + 1];
    for (int e = off[n]; e < e1; ++e) {
        int2 p = pairs[e];
        pairs[e].y = __float_as_int(__int_as_float(p.y) * dinv[p.x] * dn);
    }
}

// ================= parallel scan (2 launches) =================

__global__ void k_scan_local(const int* __restrict__ cnt, int* __restrict__ off,
                             int* __restrict__ totals, int N) {
    const int tid = threadIdx.x, lane = tid & 63, wid = tid >> 6;
    __shared__ int ws[4];
    int i = blockIdx.x * 256 + tid;
    int v = (i < N) ? cnt[i] : 0;
    int s = v;
    #pragma unroll
    for (int d = 1; d < 64; d <<= 1) {
        int t = __shfl_up(s, d);
        if (lane >= d) s += t;
    }
    if (lane == 63) ws[wid] = s;
    __syncthreads();
    int wbase = 0;
    #pragma unroll
    for (int k = 0; k < 3; ++k) if (k < wid) wbase += ws[k];
    int excl = s - v + wbase;
    if (i < N) off[i] = excl;
    if (tid == 255) totals[blockIdx.x] = excl + v;
}

// fixup: block b adds sum(totals[0..b)); also copies to cur and writes off[N]=E.
// Requires gridDim == number of scan_local blocks (<= 256).
__global__ __launch_bounds__(256) void
k_scan_add(int* __restrict__ off, const int* __restrict__ totals,
           int* __restrict__ cur, int N, int E) {
    __shared__ int ws[4];
    const int tid = threadIdx.x, lane = tid & 63, wid = tid >> 6;
    const int b = blockIdx.x;
    int v = (tid < b) ? totals[tid] : 0;
    #pragma unroll
    for (int d = 32; d > 0; d >>= 1) v += __shfl_xor(v, d);
    if (lane == 0) ws[wid] = v;
    __syncthreads();
    const int base = ws[0] + ws[1] + ws[2] + ws[3];
    const int i = b * 256 + tid;
    if (i < N) {
        int o = off[i] + base;
        off[i] = o;
        cur[i] = o;
    }
    if (b == 0 && tid == 0) off[N] = E;
}

// ================= final: logits + log_softmax (lane = node) =================
__global__ __launch_bounds__(128) void
k_lin2_lsm(const float* __restrict__ h, const float* __restrict__ W2,
           const float* __restrict__ b2, float* __restrict__ out, int N) {
    __shared__ float hsT[96][128];
    const int tid = threadIdx.x;
    const int n0 = blockIdx.x * 128;
    const int nn = (N - n0 < 128) ? (N - n0) : 128;

    if (tid < nn) {
        const float* hr = h + (size_t)(n0 + tid) * 96;
        #pragma unroll
        for (int q = 0; q < 24; ++q) {
            float4 v = *reinterpret_cast<const float4*>(hr + q * 4);
            hsT[q * 4 + 0][tid] = v.x;
            hsT[q * 4 + 1][tid] = v.y;
            hsT[q * 4 + 2][tid] = v.z;
            hsT[q * 4 + 3][tid] = v.w;
        }
    }
    __syncthreads();

    float acc[40];
    #pragma unroll
    for (int c = 0; c < 40; ++c) acc[c] = b2[c];
    for (int k = 0; k < 96; ++k) {
        const float hv = hsT[k][tid];
        const float* wr = W2 + k * 40;
        #pragma unroll
        for (int c = 0; c < 40; ++c) acc[c] = fmaf(hv, wr[c], acc[c]);
    }

    float m = acc[0];
    #pragma unroll
    for (int c = 1; c < 40; ++c) m = fmaxf(m, acc[c]);
    float s = 0.f;
    #pragma unroll
    for (int c = 0; c < 40; ++c) s += expf(acc[c] - m);
    const float lse = m + logf(s);

    if (tid < nn) {
        float* op = out + (size_t)(n0 + tid) * 40;
        #pragma unroll
        for (int q = 0; q < 10; ++q) {
            float4 v = make_float4(acc[q * 4 + 0] - lse, acc[q * 4 + 1] - lse,
                                   acc[q * 4 + 2] - lse, acc[q * 4 + 3] - lse);
            *reinterpret_cast<float4*>(op + q * 4) = v;
        }
    }
}

// ================= launch =================

extern "C" void kernel_launch(void* const* d_in, const int* in_sizes, int n_in,
                              void* d_out, int out_size, void* d_ws, size_t ws_size,
                              hipStream_t stream) {
    const float* x   = (const float*)d_in[0];
    const int*   ei  = (const int*)d_in[1];
    const float* ew  = (const float*)d_in[2];
    const float* Wc1 = (const float*)d_in[3];
    const float* bc1 = (const float*)d_in[4];
    const float* Wc2 = (const float*)d_in[5];
    const float* bc2 = (const float*)d_in[6];
    const float* Wc3 = (const float*)d_in[7];
    const float* bc3 = (const float*)d_in[8];
    const float* Wl1 = (const float*)d_in[9];
    const float* bl1 = (const float*)d_in[10];
    const float* Wl2 = (const float*)d_in[11];
    const float* bl2 = (const float*)d_in[12];

    const int FIN = 128, HID = 96;
    const int N = in_sizes[0] / FIN;
    const int E = in_sizes[2];
    const int* row = ei;
    const int* col = ei + E;

    char* ws = (char*)d_ws;
    size_t o = 0;
    auto alloc = [&](size_t bytes) -> void* {
        void* p = ws + o;
        o += (bytes + 255) & ~(size_t)255;
        return p;
    };
    float*  dinv   = (float*)alloc((size_t)N * 4);
    int*    cnt    = (int*)  alloc((size_t)N * 4);
    int*    off    = (int*)  alloc((size_t)(N + 1) * 4);
    int*    cur    = (int*)  alloc((size_t)N * 4);
    int*    totals = (int*)  alloc(1024);
    int2*   pairs  = (int2*) alloc((size_t)E * 8);
    ushort* M1     = (ushort*)alloc((size_t)N * HID * 2);
    ushort* M2     = (ushort*)alloc((size_t)N * HID * 2);
    float*  B      = (float*)alloc((size_t)N * HID * 4);
    float*  C      = (float*)alloc((size_t)N * HID * 4);

    const int gE      = (E + 255) / 256;
    const int nGemm   = (N + GBM - 1) / GBM;
    const int nScan   = (N + 255) / 256;   // 196 blocks (must be <= 256)
    const int nAdd    = (N + 127) / 128;
    const int nAgg256 = (N * 12 + 255) / 256;

    // graph prep
    hipMemsetAsync(cnt, 0, (size_t)N * 4, stream);
    k_count<<<gE, 256, 0, stream>>>(col, cnt, E);
    k_scan_local<<<nScan, 256, 0, stream>>>(cnt, off, totals, N);
    k_scan_add<<<nScan, 256, 0, stream>>>(off, totals, cur, N, E);
    k_fill<<<gE, 256, 0, stream>>>(row, col, ew, cur, pairs, E);
    k_deg_dinv<<<nAdd, 128, 0, stream>>>(pairs, off, dinv, N);
    k_scale<<<nAdd, 128, 0, stream>>>(pairs, off, dinv, N);

    // conv1 GEMM + lin1 GEMM (both read x)
    k_gemm<<<nGemm, 128, 0, stream>>>(x, Wc1, nullptr, M1, N, FIN, 0, 1);
    k_gemm<<<nGemm, 128, 0, stream>>>(x, Wl1, bl1, C, N, FIN, 1, 0);

    // conv1 aggregate -> B (residual)
    k_aggregate<<<nAgg256, 256, 0, stream>>>(M1, off, pairs, dinv, bc1, nullptr, B, N);

    // conv2
    k_gemm<<<nGemm, 128, 0, stream>>>(C, Wc2, nullptr, M2, N, HID, 0, 1);
    k_aggregate<<<nAgg256, 256, 0, stream>>>(M2, off, pairs, dinv, bc2, nullptr, C, N);

    // conv3 (+residual B)
    k_gemm<<<nGemm, 128, 0, stream>>>(C, Wc3, nullptr, M1, N, HID, 0, 1);
    k_aggregate<<<nAgg256, 256, 0, stream>>>(M1, off, pairs, dinv, bc3, B, C, N);

    // lin2 + log_softmax
    k_lin2_lsm<<<(N + 127) / 128, 128, 0, stream>>>(C, Wl2, bl2, (float*)d_out, N);
}

// Round 9
// 307.599 us; speedup vs baseline: 2.5635x; 1.1850x over previous
//
#include <hip/hip_runtime.h>
#include <hip/hip_bf16.h>

static __device__ __forceinline__ float elu_f(float x) {
    return x > 0.f ? x : expm1f(x);
}

static __device__ __forceinline__ ushort f2bf(float x) {
    __hip_bfloat16 h = __float2bfloat16(x);
    ushort u;
    __builtin_memcpy(&u, &h, 2);
    return u;
}

typedef short bf16x8 __attribute__((ext_vector_type(8)));
typedef float f32x4  __attribute__((ext_vector_type(4)));

// ================= W prep: Wt[c][k] = bf16(W[k][c]) for all 4 weights =================
// Exact block counts: 96*128/256=48, 48, 96*96/256=36, 36.
__global__ void k_wprep4(const float* __restrict__ W1, const float* __restrict__ W2,
                         const float* __restrict__ W3, const float* __restrict__ W4,
                         ushort* __restrict__ T1, ushort* __restrict__ T2,
                         ushort* __restrict__ T3, ushort* __restrict__ T4) {
    const int b = blockIdx.x;
    const float* W; ushort* T; int K, base;
    if      (b < 48)  { W = W1; T = T1; K = 128; base = b;       }
    else if (b < 96)  { W = W2; T = T2; K = 128; base = b - 48;  }
    else if (b < 132) { W = W3; T = T3; K = 96;  base = b - 96;  }
    else              { W = W4; T = T4; K = 96;  base = b - 132; }
    const int i = base * 256 + threadIdx.x;   // i < 96*K exactly
    const int kk = i / 96, c = i - kk * 96;
    T[c * K + kk] = f2bf(W[i]);
}

// ================= MFMA GEMM: out[N,96] = X[N,K] @ W[K,96] (+bias)(+elu) =================
// 256 thr = 4 waves; block = 64 rows x 96 cols. Whole X-tile + W^T staged in LDS
// as bf16 with +8 row padding (2-way bank aliasing = free). fp32 accumulate.
// Fragment layouts (16x16x32 bf16, m89/m91-verified):
//   A: row = l&15, k = (l>>4)*8 + j   B: col = l&15, same k
//   D: col = lane&15, row = (lane>>4)*4 + reg
template<int K>
__global__ __launch_bounds__(256) void
k_gemm_mfma(const float* __restrict__ X, const ushort* __restrict__ Wt,
            const float* __restrict__ bias, void* __restrict__ outp,
            int N, int act, int obf16) {
    constexpr int KP = K + 8;
    __shared__ ushort XT[64 * KP];   // [row][k]
    __shared__ ushort WT[96 * KP];   // [col][k]
    const int tid = threadIdx.x;
    const int n0  = blockIdx.x * 64;

    // stage W^T (bf16, coalesced 16B loads)
    #pragma unroll
    for (int i = tid; i < 96 * K / 8; i += 256) {
        const int c = i / (K / 8), q = i - c * (K / 8);
        uint4 v = reinterpret_cast<const uint4*>(Wt)[i];
        *reinterpret_cast<uint4*>(&WT[c * KP + q * 8]) = v;
    }
    // stage X tile (fp32 -> bf16)
    #pragma unroll
    for (int i = tid; i < 64 * K / 4; i += 256) {
        const int row = i / (K / 4), q = i - row * (K / 4);
        const int n = (n0 + row < N) ? (n0 + row) : (N - 1);
        float4 v = *reinterpret_cast<const float4*>(X + (size_t)n * K + q * 4);
        uint lo = (uint)f2bf(v.x) | ((uint)f2bf(v.y) << 16);
        uint hi = (uint)f2bf(v.z) | ((uint)f2bf(v.w) << 16);
        *reinterpret_cast<uint2*>(&XT[row * KP + q * 4]) = make_uint2(lo, hi);
    }
    __syncthreads();

    const int lane = tid & 63;
    const int wv   = tid >> 6;       // wave -> rows wv*16..+15
    const int r16  = lane & 15;
    const int kh   = lane >> 4;      // 0..3 -> k-offset kh*8

    bf16x8 a[K / 32];
    const ushort* xbase = &XT[(wv * 16 + r16) * KP + kh * 8];
    #pragma unroll
    for (int ks = 0; ks < K / 32; ++ks)
        a[ks] = *reinterpret_cast<const bf16x8*>(xbase + ks * 32);

    f32x4 acc[6];
    #pragma unroll
    for (int ct = 0; ct < 6; ++ct) {
        f32x4 c = {0.f, 0.f, 0.f, 0.f};
        const ushort* wbase = &WT[(ct * 16 + r16) * KP + kh * 8];
        #pragma unroll
        for (int ks = 0; ks < K / 32; ++ks) {
            bf16x8 b = *reinterpret_cast<const bf16x8*>(wbase + ks * 32);
            c = __builtin_amdgcn_mfma_f32_16x16x32_bf16(a[ks], b, c, 0, 0, 0);
        }
        acc[ct] = c;
    }

    // epilogue: D col = lane&15, row = (lane>>4)*4 + reg
    #pragma unroll
    for (int ct = 0; ct < 6; ++ct) {
        const int col = ct * 16 + r16;
        const float bv = bias ? bias[col] : 0.f;
        #pragma unroll
        for (int r = 0; r < 4; ++r) {
            const int n = n0 + wv * 16 + kh * 4 + r;
            if (n < N) {
                float v = acc[ct][r] + bv;
                if (act) v = elu_f(v);
                if (obf16) ((ushort*)outp)[(size_t)n * 96 + col] = f2bf(v);
                else       ((float*)outp)[(size_t)n * 96 + col] = v;
            }
        }
    }
}

// ================= aggregation (bf16 message table, CSR gather) =================
// Depth-3 software pipeline over the dependent pairs->gather chain.
static __device__ __forceinline__ void bf8_unpack(uint4 v, float* f) {
    f[0] = __uint_as_float(v.x << 16);
    f[1] = __uint_as_float(v.x & 0xffff0000u);
    f[2] = __uint_as_float(v.y << 16);
    f[3] = __uint_as_float(v.y & 0xffff0000u);
    f[4] = __uint_as_float(v.z << 16);
    f[5] = __uint_as_float(v.z & 0xffff0000u);
    f[6] = __uint_as_float(v.w << 16);
    f[7] = __uint_as_float(v.w & 0xffff0000u);
}

__global__ __launch_bounds__(256) void
k_aggregate(const ushort* __restrict__ tmp, const int* __restrict__ off,
            const int2* __restrict__ pairs, const float* __restrict__ dinv,
            const float* __restrict__ bias, const float* __restrict__ addsrc,
            float* __restrict__ out, int N) {
    int t = blockIdx.x * blockDim.x + threadIdx.x;
    int n = t / 12;
    if (n >= N) return;
    const int c = (t % 12) * 8;
    const ushort* base = tmp + c;

    float di = dinv[n];
    float sn = di * di;
    float f[8], acc[8];
    uint4 sv = *reinterpret_cast<const uint4*>(base + (size_t)n * 96);
    bf8_unpack(sv, f);
    #pragma unroll
    for (int i = 0; i < 8; ++i) acc[i] = sn * f[i];

    const int e0 = off[n];
    const int e1 = off[n + 1];
    const int m  = e1 - e0;

    int2 pA, pB, pC;
    uint4 hA, hB, hC;
    if (m > 0) { pA = pairs[e0];     hA = *reinterpret_cast<const uint4*>(base + (size_t)pA.x * 96); }
    if (m > 1) { pB = pairs[e0 + 1]; hB = *reinterpret_cast<const uint4*>(base + (size_t)pB.x * 96); }
    if (m > 2) { pC = pairs[e0 + 2]; hC = *reinterpret_cast<const uint4*>(base + (size_t)pC.x * 96); }

    for (int e = e0 + 3; e < e1; ++e) {
        int2 pD = pairs[e];
        uint4 hD = *reinterpret_cast<const uint4*>(base + (size_t)pD.x * 96);
        float w = __int_as_float(pA.y);
        bf8_unpack(hA, f);
        #pragma unroll
        for (int i = 0; i < 8; ++i) acc[i] = fmaf(w, f[i], acc[i]);
        pA = pB; hA = hB;
        pB = pC; hB = hC;
        pC = pD; hC = hD;
    }
    if (m > 0) {
        float w = __int_as_float(pA.y);
        bf8_unpack(hA, f);
        #pragma unroll
        for (int i = 0; i < 8; ++i) acc[i] = fmaf(w, f[i], acc[i]);
    }
    if (m > 1) {
        float w = __int_as_float(pB.y);
        bf8_unpack(hB, f);
        #pragma unroll
        for (int i = 0; i < 8; ++i) acc[i] = fmaf(w, f[i], acc[i]);
    }
    if (m > 2) {
        float w = __int_as_float(pC.y);
        bf8_unpack(hC, f);
        #pragma unroll
        for (int i = 0; i < 8; ++i) acc[i] = fmaf(w, f[i], acc[i]);
    }

    float4 bv0 = *reinterpret_cast<const float4*>(bias + c);
    float4 bv1 = *reinterpret_cast<const float4*>(bias + c + 4);
    acc[0] = elu_f(acc[0] + bv0.x);
    acc[1] = elu_f(acc[1] + bv0.y);
    acc[2] = elu_f(acc[2] + bv0.z);
    acc[3] = elu_f(acc[3] + bv0.w);
    acc[4] = elu_f(acc[4] + bv1.x);
    acc[5] = elu_f(acc[5] + bv1.y);
    acc[6] = elu_f(acc[6] + bv1.z);
    acc[7] = elu_f(acc[7] + bv1.w);
    if (addsrc) {
        float4 r0 = *reinterpret_cast<const float4*>(addsrc + (size_t)n * 96 + c);
        float4 r1 = *reinterpret_cast<const float4*>(addsrc + (size_t)n * 96 + c + 4);
        acc[0] += r0.x; acc[1] += r0.y; acc[2] += r0.z; acc[3] += r0.w;
        acc[4] += r1.x; acc[5] += r1.y; acc[6] += r1.z; acc[7] += r1.w;
    }
    float* op = out + (size_t)n * 96 + c;
    *reinterpret_cast<float4*>(op)     = make_float4(acc[0], acc[1], acc[2], acc[3]);
    *reinterpret_cast<float4*>(op + 4) = make_float4(acc[4], acc[5], acc[6], acc[7]);
}

// ================= graph prep =================

__global__ void k_count(const int* __restrict__ col, int* __restrict__ cnt, int E) {
    int e = blockIdx.x * blockDim.x + threadIdx.x;
    if (e < E) atomicAdd(&cnt[col[e]], 1);
}

__global__ void k_fill(const int* __restrict__ row, const int* __restrict__ col,
                       const float* __restrict__ w, int* __restrict__ cur,
                       int2* __restrict__ pairs, int E) {
    int e = blockIdx.x * blockDim.x + threadIdx.x;
    if (e < E) {
        int c = col[e];
        int pos = atomicAdd(&cur[c], 1);
        pairs[pos] = make_int2(row[e], __float_as_int(w[e]));
    }
}

__global__ void k_deg_dinv(const int2* __restrict__ pairs, const int* __restrict__ off,
                           float* __restrict__ dinv, int N) {
    int n = blockIdx.x * blockDim.x + threadIdx.x;
    if (n >= N) return;
    float d = 1.0f;
    int e1 = off[n + 1];
    for (int e = off[n]; e < e1; ++e) d += __int_as_float(pairs[e].y);
    dinv[n] = rsqrtf(d);
}

__global__ void k_scale(int2* __restrict__ pairs, const int* __restrict__ off,
                        const float* __restrict__ dinv, int N) {
    int n = blockIdx.x * blockDim.x + threadIdx.x;
    if (n >= N) return;
    const float dn = dinv[n];
    int e1 = off[n + 1];
    for (int e = off[n]; e < e1; ++e) {
        int2 p = pairs[e];
        pairs[e].y = __float_as_int(__int_as_float(p.y) * dinv[p.x] * dn);
    }
}

// ================= parallel scan (2 launches) =================

__global__ void k_scan_local(const int* __restrict__ cnt, int* __restrict__ off,
                             int* __restrict__ totals, int N) {
    const int tid = threadIdx.x, lane = tid & 63, wid = tid >> 6;
    __shared__ int ws[4];
    int i = blockIdx.x * 256 + tid;
    int v = (i < N) ? cnt[i] : 0;
    int s = v;
    #pragma unroll
    for (int d = 1; d < 64; d <<= 1) {
        int t = __shfl_up(s, d);
        if (lane >= d) s += t;
    }
    if (lane == 63) ws[wid] = s;
    __syncthreads();
    int wbase = 0;
    #pragma unroll
    for (int k = 0; k < 3; ++k) if (k < wid) wbase += ws[k];
    int excl = s - v + wbase;
    if (i < N) off[i] = excl;
    if (tid == 255) totals[blockIdx.x] = excl + v;
}

__global__ __launch_bounds__(256) void
k_scan_add(int* __restrict__ off, const int* __restrict__ totals,
           int* __restrict__ cur, int N, int E) {
    __shared__ int ws[4];
    const int tid = threadIdx.x, lane = tid & 63, wid = tid >> 6;
    const int b = blockIdx.x;
    int v = (tid < b) ? totals[tid] : 0;
    #pragma unroll
    for (int d = 32; d > 0; d >>= 1) v += __shfl_xor(v, d);
    if (lane == 0) ws[wid] = v;
    __syncthreads();
    const int base = ws[0] + ws[1] + ws[2] + ws[3];
    const int i = b * 256 + tid;
    if (i < N) {
        int o = off[i] + base;
        off[i] = o;
        cur[i] = o;
    }
    if (b == 0 && tid == 0) off[N] = E;
}

// ================= final: logits + log_softmax (lane = node) =================
__global__ __launch_bounds__(128) void
k_lin2_lsm(const float* __restrict__ h, const float* __restrict__ W2,
           const float* __restrict__ b2, float* __restrict__ out, int N) {
    __shared__ float hsT[96][128];
    const int tid = threadIdx.x;
    const int n0 = blockIdx.x * 128;
    const int nn = (N - n0 < 128) ? (N - n0) : 128;

    if (tid < nn) {
        const float* hr = h + (size_t)(n0 + tid) * 96;
        #pragma unroll
        for (int q = 0; q < 24; ++q) {
            float4 v = *reinterpret_cast<const float4*>(hr + q * 4);
            hsT[q * 4 + 0][tid] = v.x;
            hsT[q * 4 + 1][tid] = v.y;
            hsT[q * 4 + 2][tid] = v.z;
            hsT[q * 4 + 3][tid] = v.w;
        }
    }
    __syncthreads();

    float acc[40];
    #pragma unroll
    for (int c = 0; c < 40; ++c) acc[c] = b2[c];
    for (int k = 0; k < 96; ++k) {
        const float hv = hsT[k][tid];
        const float* wr = W2 + k * 40;
        #pragma unroll
        for (int c = 0; c < 40; ++c) acc[c] = fmaf(hv, wr[c], acc[c]);
    }

    float m = acc[0];
    #pragma unroll
    for (int c = 1; c < 40; ++c) m = fmaxf(m, acc[c]);
    float s = 0.f;
    #pragma unroll
    for (int c = 0; c < 40; ++c) s += expf(acc[c] - m);
    const float lse = m + logf(s);

    if (tid < nn) {
        float* op = out + (size_t)(n0 + tid) * 40;
        #pragma unroll
        for (int q = 0; q < 10; ++q) {
            float4 v = make_float4(acc[q * 4 + 0] - lse, acc[q * 4 + 1] - lse,
                                   acc[q * 4 + 2] - lse, acc[q * 4 + 3] - lse);
            *reinterpret_cast<float4*>(op + q * 4) = v;
        }
    }
}

// ================= launch =================

extern "C" void kernel_launch(void* const* d_in, const int* in_sizes, int n_in,
                              void* d_out, int out_size, void* d_ws, size_t ws_size,
                              hipStream_t stream) {
    const float* x   = (const float*)d_in[0];
    const int*   ei  = (const int*)d_in[1];
    const float* ew  = (const float*)d_in[2];
    const float* Wc1 = (const float*)d_in[3];
    const float* bc1 = (const float*)d_in[4];
    const float* Wc2 = (const float*)d_in[5];
    const float* bc2 = (const float*)d_in[6];
    const float* Wc3 = (const float*)d_in[7];
    const float* bc3 = (const float*)d_in[8];
    const float* Wl1 = (const float*)d_in[9];
    const float* bl1 = (const float*)d_in[10];
    const float* Wl2 = (const float*)d_in[11];
    const float* bl2 = (const float*)d_in[12];

    const int FIN = 128, HID = 96;
    const int N = in_sizes[0] / FIN;
    const int E = in_sizes[2];
    const int* row = ei;
    const int* col = ei + E;

    char* ws = (char*)d_ws;
    size_t o = 0;
    auto alloc = [&](size_t bytes) -> void* {
        void* p = ws + o;
        o += (bytes + 255) & ~(size_t)255;
        return p;
    };
    float*  dinv   = (float*)alloc((size_t)N * 4);
    int*    cnt    = (int*)  alloc((size_t)N * 4);
    int*    off    = (int*)  alloc((size_t)(N + 1) * 4);
    int*    cur    = (int*)  alloc((size_t)N * 4);
    int*    totals = (int*)  alloc(1024);
    int2*   pairs  = (int2*) alloc((size_t)E * 8);
    ushort* M1     = (ushort*)alloc((size_t)N * HID * 2);
    ushort* M2     = (ushort*)alloc((size_t)N * HID * 2);
    float*  B      = (float*)alloc((size_t)N * HID * 4);
    float*  C      = (float*)alloc((size_t)N * HID * 4);
    ushort* Wt_c1  = (ushort*)alloc(96 * 128 * 2);
    ushort* Wt_l1  = (ushort*)alloc(96 * 128 * 2);
    ushort* Wt_c2  = (ushort*)alloc(96 * 96 * 2);
    ushort* Wt_c3  = (ushort*)alloc(96 * 96 * 2);

    const int gE      = (E + 255) / 256;
    const int nGemm   = (N + 63) / 64;
    const int nScan   = (N + 255) / 256;   // must be <= 256
    const int nAdd    = (N + 127) / 128;
    const int nAgg256 = (N * 12 + 255) / 256;

    // weight prep (independent of everything)
    k_wprep4<<<168, 256, 0, stream>>>(Wc1, Wl1, Wc2, Wc3, Wt_c1, Wt_l1, Wt_c2, Wt_c3);

    // graph prep
    hipMemsetAsync(cnt, 0, (size_t)N * 4, stream);
    k_count<<<gE, 256, 0, stream>>>(col, cnt, E);
    k_scan_local<<<nScan, 256, 0, stream>>>(cnt, off, totals, N);
    k_scan_add<<<nScan, 256, 0, stream>>>(off, totals, cur, N, E);
    k_fill<<<gE, 256, 0, stream>>>(row, col, ew, cur, pairs, E);
    k_deg_dinv<<<nAdd, 128, 0, stream>>>(pairs, off, dinv, N);
    k_scale<<<nAdd, 128, 0, stream>>>(pairs, off, dinv, N);

    // conv1 GEMM + lin1 GEMM (both read x)
    k_gemm_mfma<128><<<nGemm, 256, 0, stream>>>(x, Wt_c1, nullptr, M1, N, 0, 1);
    k_gemm_mfma<128><<<nGemm, 256, 0, stream>>>(x, Wt_l1, bl1, C, N, 1, 0);

    // conv1 aggregate -> B (residual)
    k_aggregate<<<nAgg256, 256, 0, stream>>>(M1, off, pairs, dinv, bc1, nullptr, B, N);

    // conv2
    k_gemm_mfma<96><<<nGemm, 256, 0, stream>>>(C, Wt_c2, nullptr, M2, N, 0, 1);
    k_aggregate<<<nAgg256, 256, 0, stream>>>(M2, off, pairs, dinv, bc2, nullptr, C, N);

    // conv3 (+residual B)
    k_gemm_mfma<96><<<nGemm, 256, 0, stream>>>(C, Wt_c3, nullptr, M1, N, 0, 1);
    k_aggregate<<<nAgg256, 256, 0, stream>>>(M1, off, pairs, dinv, bc3, B, C, N);

    // lin2 + log_softmax
    k_lin2_lsm<<<(N + 127) / 128, 128, 0, stream>>>(C, Wl2, bl2, (float*)d_out, N);
}

// Round 10
// 240.734 us; speedup vs baseline: 3.2755x; 1.2778x over previous
//
#include <hip/hip_runtime.h>
#include <hip/hip_bf16.h>

static __device__ __forceinline__ float elu_f(float x) {
    return x > 0.f ? x : expm1f(x);
}

static __device__ __forceinline__ ushort f2bf(float x) {
    __hip_bfloat16 h = __float2bfloat16(x);
    ushort u;
    __builtin_memcpy(&u, &h, 2);
    return u;
}

typedef short bf16x8 __attribute__((ext_vector_type(8)));
typedef float f32x4  __attribute__((ext_vector_type(4)));

// ================= W prep: Wt[c][k] = bf16(W[k][c]) for all 4 weights =================
__global__ void k_wprep4(const float* __restrict__ W1, const float* __restrict__ W2,
                         const float* __restrict__ W3, const float* __restrict__ W4,
                         ushort* __restrict__ T1, ushort* __restrict__ T2,
                         ushort* __restrict__ T3, ushort* __restrict__ T4) {
    const int b = blockIdx.x;
    const float* W; ushort* T; int K, base;
    if      (b < 48)  { W = W1; T = T1; K = 128; base = b;       }
    else if (b < 96)  { W = W2; T = T2; K = 128; base = b - 48;  }
    else if (b < 132) { W = W3; T = T3; K = 96;  base = b - 96;  }
    else              { W = W4; T = T4; K = 96;  base = b - 132; }
    const int i = base * 256 + threadIdx.x;
    const int kk = i / 96, c = i - kk * 96;
    T[c * K + kk] = f2bf(W[i]);
}

// ================= bucketed CSR build (no global per-node atomics) =================
// buckets: dst / bspan, bspan = ceil(N/256). 4096 edges per block.

__global__ __launch_bounds__(256) void
k_bcount(const int* __restrict__ col, int* __restrict__ bcnt, int E, int bspan) {
    __shared__ int h[256];
    const int tid = threadIdx.x;
    h[tid] = 0;
    __syncthreads();
    const int e0 = blockIdx.x * 4096;
    #pragma unroll
    for (int j = 0; j < 16; ++j) {
        int e = e0 + j * 256 + tid;
        if (e < E) atomicAdd(&h[col[e] / bspan], 1);
    }
    __syncthreads();
    if (h[tid] > 0) atomicAdd(&bcnt[tid], h[tid]);
}

__global__ __launch_bounds__(256) void
k_bscan(const int* __restrict__ bcnt, int* __restrict__ bOff, int* __restrict__ bCur) {
    __shared__ int wsum[4];
    const int tid = threadIdx.x, lane = tid & 63, wid = tid >> 6;
    int v = bcnt[tid];
    int s = v;
    #pragma unroll
    for (int d = 1; d < 64; d <<= 1) {
        int t = __shfl_up(s, d);
        if (lane >= d) s += t;
    }
    if (lane == 63) wsum[wid] = s;
    __syncthreads();
    int wb = 0;
    #pragma unroll
    for (int k = 0; k < 3; ++k) if (k < wid) wb += wsum[k];
    int excl = s - v + wb;
    bOff[tid] = excl;
    bCur[tid] = excl;
    if (tid == 255) bOff[256] = excl + v;
}

__global__ __launch_bounds__(256) void
k_bscatter(const int* __restrict__ row, const int* __restrict__ col,
           const float* __restrict__ w, int* __restrict__ bCur,
           int2* __restrict__ ebuf, int* __restrict__ edst, int E, int bspan) {
    __shared__ int h[256];
    __shared__ int base[256];
    const int tid = threadIdx.x;
    h[tid] = 0;
    __syncthreads();
    const int e0 = blockIdx.x * 4096;
    int bk[16], rk[16];
    #pragma unroll
    for (int j = 0; j < 16; ++j) {
        int e = e0 + j * 256 + tid;
        if (e < E) {
            int b = col[e] / bspan;
            bk[j] = b;
            rk[j] = atomicAdd(&h[b], 1);
        }
    }
    __syncthreads();
    base[tid] = (h[tid] > 0) ? atomicAdd(&bCur[tid], h[tid]) : 0;
    __syncthreads();
    #pragma unroll
    for (int j = 0; j < 16; ++j) {
        int e = e0 + j * 256 + tid;
        if (e < E) {
            int pos = base[bk[j]] + rk[j];
            ebuf[pos] = make_int2(row[e], __float_as_int(w[e]));
            edst[pos] = col[e];
        }
    }
}

// one block per bucket: exact per-node offsets, deg->dinv, pairs scatter (all LDS-ranked)
__global__ __launch_bounds__(256) void
k_csrify(const int2* __restrict__ ebuf, const int* __restrict__ edst,
         const int* __restrict__ bOff, int* __restrict__ off, float* __restrict__ dinv,
         int2* __restrict__ pairs, int N, int E, int bspan) {
    __shared__ int hist[256];
    __shared__ float degs[256];
    __shared__ int curl[256];
    __shared__ int wsum[4];
    const int tid = threadIdx.x, b = blockIdx.x;
    const int base = b * bspan;
    const int lnodes = (N - base < bspan) ? (N - base) : bspan;
    if (b == 0 && tid == 0) off[N] = E;
    if (lnodes <= 0) return;
    hist[tid] = 0;
    degs[tid] = 0.f;
    __syncthreads();
    const int e0 = bOff[b], e1 = bOff[b + 1];
    for (int e = e0 + tid; e < e1; e += 256) {
        int d = edst[e] - base;
        atomicAdd(&hist[d], 1);
        atomicAdd(&degs[d], __int_as_float(ebuf[e].y));
    }
    __syncthreads();
    // exclusive scan of hist
    const int lane = tid & 63, wid = tid >> 6;
    int v = hist[tid];
    int s = v;
    #pragma unroll
    for (int d = 1; d < 64; d <<= 1) {
        int t = __shfl_up(s, d);
        if (lane >= d) s += t;
    }
    if (lane == 63) wsum[wid] = s;
    __syncthreads();
    int wb = 0;
    #pragma unroll
    for (int k = 0; k < 3; ++k) if (k < wid) wb += wsum[k];
    int excl = s - v + wb;
    if (tid < lnodes) {
        off[base + tid] = e0 + excl;
        dinv[base + tid] = rsqrtf(1.0f + degs[tid]);   // self-loop weight 1
    }
    curl[tid] = excl;
    __syncthreads();
    for (int e = e0 + tid; e < e1; e += 256) {
        int d = edst[e] - base;
        int p = atomicAdd(&curl[d], 1);
        pairs[e0 + p] = ebuf[e];
    }
}

// ================= MFMA GEMM: out[N,96] = X[N,K]@W[K,96]; optional row-scale/bias/elu ====
template<int K>
__global__ __launch_bounds__(256) void
k_gemm_mfma(const float* __restrict__ X, const ushort* __restrict__ Wt,
            const float* __restrict__ bias, const float* __restrict__ dscale,
            void* __restrict__ outp, int N, int act, int obf16) {
    constexpr int KP = K + 8;
    __shared__ ushort XT[64 * KP];
    __shared__ ushort WT[96 * KP];
    const int tid = threadIdx.x;
    const int n0  = blockIdx.x * 64;

    #pragma unroll
    for (int i = tid; i < 96 * K / 8; i += 256) {
        const int c = i / (K / 8), q = i - c * (K / 8);
        uint4 v = reinterpret_cast<const uint4*>(Wt)[i];
        *reinterpret_cast<uint4*>(&WT[c * KP + q * 8]) = v;
    }
    #pragma unroll
    for (int i = tid; i < 64 * K / 4; i += 256) {
        const int row = i / (K / 4), q = i - row * (K / 4);
        const int n = (n0 + row < N) ? (n0 + row) : (N - 1);
        float4 v = *reinterpret_cast<const float4*>(X + (size_t)n * K + q * 4);
        uint lo = (uint)f2bf(v.x) | ((uint)f2bf(v.y) << 16);
        uint hi = (uint)f2bf(v.z) | ((uint)f2bf(v.w) << 16);
        *reinterpret_cast<uint2*>(&XT[row * KP + q * 4]) = make_uint2(lo, hi);
    }
    __syncthreads();

    const int lane = tid & 63;
    const int wv   = tid >> 6;
    const int r16  = lane & 15;
    const int kh   = lane >> 4;

    bf16x8 a[K / 32];
    const ushort* xbase = &XT[(wv * 16 + r16) * KP + kh * 8];
    #pragma unroll
    for (int ks = 0; ks < K / 32; ++ks)
        a[ks] = *reinterpret_cast<const bf16x8*>(xbase + ks * 32);

    f32x4 acc[6];
    #pragma unroll
    for (int ct = 0; ct < 6; ++ct) {
        f32x4 c = {0.f, 0.f, 0.f, 0.f};
        const ushort* wbase = &WT[(ct * 16 + r16) * KP + kh * 8];
        #pragma unroll
        for (int ks = 0; ks < K / 32; ++ks) {
            bf16x8 bfr = *reinterpret_cast<const bf16x8*>(wbase + ks * 32);
            c = __builtin_amdgcn_mfma_f32_16x16x32_bf16(a[ks], bfr, c, 0, 0, 0);
        }
        acc[ct] = c;
    }

    #pragma unroll
    for (int r = 0; r < 4; ++r) {
        const int n = n0 + wv * 16 + kh * 4 + r;
        if (n >= N) continue;
        const float ds = dscale ? dscale[n] : 1.f;
        #pragma unroll
        for (int ct = 0; ct < 6; ++ct) {
            const int col = ct * 16 + r16;
            float v = acc[ct][r] * ds;
            if (bias) v += bias[col];
            if (act) v = elu_f(v);
            if (obf16) ((ushort*)outp)[(size_t)n * 96 + col] = f2bf(v);
            else       ((float*)outp)[(size_t)n * 96 + col] = v;
        }
    }
}

// ================= aggregation: out = elu(dinv[n]*(M'[n] + sum w*M'[src]) + bias) =========
static __device__ __forceinline__ void bf8_unpack(uint4 v, float* f) {
    f[0] = __uint_as_float(v.x << 16);
    f[1] = __uint_as_float(v.x & 0xffff0000u);
    f[2] = __uint_as_float(v.y << 16);
    f[3] = __uint_as_float(v.y & 0xffff0000u);
    f[4] = __uint_as_float(v.z << 16);
    f[5] = __uint_as_float(v.z & 0xffff0000u);
    f[6] = __uint_as_float(v.w << 16);
    f[7] = __uint_as_float(v.w & 0xffff0000u);
}

__global__ __launch_bounds__(256) void
k_aggregate(const ushort* __restrict__ tmp, const int* __restrict__ off,
            const int2* __restrict__ pairs, const float* __restrict__ dinv,
            const float* __restrict__ bias, const float* __restrict__ addsrc,
            float* __restrict__ out, int N) {
    int t = blockIdx.x * blockDim.x + threadIdx.x;
    int n = t / 12;
    if (n >= N) return;
    const int c = (t % 12) * 8;
    const ushort* base = tmp + c;

    const float di = dinv[n];
    float f[8], acc[8];
    uint4 sv = *reinterpret_cast<const uint4*>(base + (size_t)n * 96);
    bf8_unpack(sv, f);
    #pragma unroll
    for (int i = 0; i < 8; ++i) acc[i] = f[i];   // self-loop, raw weight 1

    const int e0 = off[n];
    const int e1 = off[n + 1];
    const int m  = e1 - e0;

    int2 pA, pB, pC;
    uint4 hA, hB, hC;
    if (m > 0) { pA = pairs[e0];     hA = *reinterpret_cast<const uint4*>(base + (size_t)pA.x * 96); }
    if (m > 1) { pB = pairs[e0 + 1]; hB = *reinterpret_cast<const uint4*>(base + (size_t)pB.x * 96); }
    if (m > 2) { pC = pairs[e0 + 2]; hC = *reinterpret_cast<const uint4*>(base + (size_t)pC.x * 96); }

    for (int e = e0 + 3; e < e1; ++e) {
        int2 pD = pairs[e];
        uint4 hD = *reinterpret_cast<const uint4*>(base + (size_t)pD.x * 96);
        float w = __int_as_float(pA.y);
        bf8_unpack(hA, f);
        #pragma unroll
        for (int i = 0; i < 8; ++i) acc[i] = fmaf(w, f[i], acc[i]);
        pA = pB; hA = hB;
        pB = pC; hB = hC;
        pC = pD; hC = hD;
    }
    if (m > 0) {
        float w = __int_as_float(pA.y);
        bf8_unpack(hA, f);
        #pragma unroll
        for (int i = 0; i < 8; ++i) acc[i] = fmaf(w, f[i], acc[i]);
    }
    if (m > 1) {
        float w = __int_as_float(pB.y);
        bf8_unpack(hB, f);
        #pragma unroll
        for (int i = 0; i < 8; ++i) acc[i] = fmaf(w, f[i], acc[i]);
    }
    if (m > 2) {
        float w = __int_as_float(pC.y);
        bf8_unpack(hC, f);
        #pragma unroll
        for (int i = 0; i < 8; ++i) acc[i] = fmaf(w, f[i], acc[i]);
    }

    float4 bv0 = *reinterpret_cast<const float4*>(bias + c);
    float4 bv1 = *reinterpret_cast<const float4*>(bias + c + 4);
    acc[0] = elu_f(fmaf(di, acc[0], bv0.x));
    acc[1] = elu_f(fmaf(di, acc[1], bv0.y));
    acc[2] = elu_f(fmaf(di, acc[2], bv0.z));
    acc[3] = elu_f(fmaf(di, acc[3], bv0.w));
    acc[4] = elu_f(fmaf(di, acc[4], bv1.x));
    acc[5] = elu_f(fmaf(di, acc[5], bv1.y));
    acc[6] = elu_f(fmaf(di, acc[6], bv1.z));
    acc[7] = elu_f(fmaf(di, acc[7], bv1.w));
    if (addsrc) {
        float4 r0 = *reinterpret_cast<const float4*>(addsrc + (size_t)n * 96 + c);
        float4 r1 = *reinterpret_cast<const float4*>(addsrc + (size_t)n * 96 + c + 4);
        acc[0] += r0.x; acc[1] += r0.y; acc[2] += r0.z; acc[3] += r0.w;
        acc[4] += r1.x; acc[5] += r1.y; acc[6] += r1.z; acc[7] += r1.w;
    }
    float* op = out + (size_t)n * 96 + c;
    *reinterpret_cast<float4*>(op)     = make_float4(acc[0], acc[1], acc[2], acc[3]);
    *reinterpret_cast<float4*>(op + 4) = make_float4(acc[4], acc[5], acc[6], acc[7]);
}

// ================= final: logits + log_softmax (lane = node) =================
__global__ __launch_bounds__(128) void
k_lin2_lsm(const float* __restrict__ h, const float* __restrict__ W2,
           const float* __restrict__ b2, float* __restrict__ out, int N) {
    __shared__ float hsT[96][128];
    const int tid = threadIdx.x;
    const int n0 = blockIdx.x * 128;
    const int nn = (N - n0 < 128) ? (N - n0) : 128;

    if (tid < nn) {
        const float* hr = h + (size_t)(n0 + tid) * 96;
        #pragma unroll
        for (int q = 0; q < 24; ++q) {
            float4 v = *reinterpret_cast<const float4*>(hr + q * 4);
            hsT[q * 4 + 0][tid] = v.x;
            hsT[q * 4 + 1][tid] = v.y;
            hsT[q * 4 + 2][tid] = v.z;
            hsT[q * 4 + 3][tid] = v.w;
        }
    }
    __syncthreads();

    float acc[40];
    #pragma unroll
    for (int c = 0; c < 40; ++c) acc[c] = b2[c];
    for (int k = 0; k < 96; ++k) {
        const float hv = hsT[k][tid];
        const float* wr = W2 + k * 40;
        #pragma unroll
        for (int c = 0; c < 40; ++c) acc[c] = fmaf(hv, wr[c], acc[c]);
    }

    float m = acc[0];
    #pragma unroll
    for (int c = 1; c < 40; ++c) m = fmaxf(m, acc[c]);
    float s = 0.f;
    #pragma unroll
    for (int c = 0; c < 40; ++c) s += expf(acc[c] - m);
    const float lse = m + logf(s);

    if (tid < nn) {
        float* op = out + (size_t)(n0 + tid) * 40;
        #pragma unroll
        for (int q = 0; q < 10; ++q) {
            float4 v = make_float4(acc[q * 4 + 0] - lse, acc[q * 4 + 1] - lse,
                                   acc[q * 4 + 2] - lse, acc[q * 4 + 3] - lse);
            *reinterpret_cast<float4*>(op + q * 4) = v;
        }
    }
}

// ================= launch =================

extern "C" void kernel_launch(void* const* d_in, const int* in_sizes, int n_in,
                              void* d_out, int out_size, void* d_ws, size_t ws_size,
                              hipStream_t stream) {
    const float* x   = (const float*)d_in[0];
    const int*   ei  = (const int*)d_in[1];
    const float* ew  = (const float*)d_in[2];
    const float* Wc1 = (const float*)d_in[3];
    const float* bc1 = (const float*)d_in[4];
    const float* Wc2 = (const float*)d_in[5];
    const float* bc2 = (const float*)d_in[6];
    const float* Wc3 = (const float*)d_in[7];
    const float* bc3 = (const float*)d_in[8];
    const float* Wl1 = (const float*)d_in[9];
    const float* bl1 = (const float*)d_in[10];
    const float* Wl2 = (const float*)d_in[11];
    const float* bl2 = (const float*)d_in[12];

    const int FIN = 128, HID = 96;
    const int N = in_sizes[0] / FIN;
    const int E = in_sizes[2];
    const int* row = ei;
    const int* col = ei + E;
    const int bspan = (N + 255) / 256;

    char* ws = (char*)d_ws;
    size_t o = 0;
    auto alloc = [&](size_t bytes) -> void* {
        void* p = ws + o;
        o += (bytes + 255) & ~(size_t)255;
        return p;
    };
    float*  dinv   = (float*)alloc((size_t)N * 4);
    int*    off    = (int*)  alloc((size_t)(N + 1) * 4);
    int*    bcnt   = (int*)  alloc(256 * 4);
    int*    bOff   = (int*)  alloc(257 * 4);
    int*    bCur   = (int*)  alloc(256 * 4);
    int2*   pairs  = (int2*) alloc((size_t)E * 8);
    ushort* M1     = (ushort*)alloc((size_t)N * HID * 2);
    ushort* M2     = (ushort*)alloc((size_t)N * HID * 2);
    float*  B      = (float*)alloc((size_t)N * HID * 4);
    float*  C      = (float*)alloc((size_t)N * HID * 4);
    ushort* Wt_c1  = (ushort*)alloc(96 * 128 * 2);
    ushort* Wt_l1  = (ushort*)alloc(96 * 128 * 2);
    ushort* Wt_c2  = (ushort*)alloc(96 * 96 * 2);
    ushort* Wt_c3  = (ushort*)alloc(96 * 96 * 2);
    // prep scratch aliases the message tables (dead until GEMMs run)
    int2*   ebuf   = (int2*)M1;   // E*8  <= N*96*2
    int*    edst   = (int*)M2;    // E*4  <= N*96*2

    const int gBkt    = (E + 4095) / 4096;
    const int nGemm   = (N + 63) / 64;
    const int nAgg256 = (N * 12 + 255) / 256;

    // weight prep
    k_wprep4<<<168, 256, 0, stream>>>(Wc1, Wl1, Wc2, Wc3, Wt_c1, Wt_l1, Wt_c2, Wt_c3);

    // bucketed CSR build
    hipMemsetAsync(bcnt, 0, 256 * 4, stream);
    k_bcount<<<gBkt, 256, 0, stream>>>(col, bcnt, E, bspan);
    k_bscan<<<1, 256, 0, stream>>>(bcnt, bOff, bCur);
    k_bscatter<<<gBkt, 256, 0, stream>>>(row, col, ew, bCur, ebuf, edst, E, bspan);
    k_csrify<<<256, 256, 0, stream>>>(ebuf, edst, bOff, off, dinv, pairs, N, E, bspan);

    // conv1 GEMM (messages scaled by dinv) + lin1 GEMM
    k_gemm_mfma<128><<<nGemm, 256, 0, stream>>>(x, Wt_c1, nullptr, dinv, M1, N, 0, 1);
    k_gemm_mfma<128><<<nGemm, 256, 0, stream>>>(x, Wt_l1, bl1, nullptr, C, N, 1, 0);

    // conv1 aggregate -> B (residual)
    k_aggregate<<<nAgg256, 256, 0, stream>>>(M1, off, pairs, dinv, bc1, nullptr, B, N);

    // conv2
    k_gemm_mfma<96><<<nGemm, 256, 0, stream>>>(C, Wt_c2, nullptr, dinv, M2, N, 0, 1);
    k_aggregate<<<nAgg256, 256, 0, stream>>>(M2, off, pairs, dinv, bc2, nullptr, C, N);

    // conv3 (+residual B)
    k_gemm_mfma<96><<<nGemm, 256, 0, stream>>>(C, Wt_c3, nullptr, dinv, M1, N, 0, 1);
    k_aggregate<<<nAgg256, 256, 0, stream>>>(M1, off, pairs, dinv, bc3, B, C, N);

    // lin2 + log_softmax
    k_lin2_lsm<<<(N + 127) / 128, 128, 0, stream>>>(C, Wl2, bl2, (float*)d_out, N);
}

// Round 11
// 229.579 us; speedup vs baseline: 3.4346x; 1.0486x over previous
//
#include <hip/hip_runtime.h>
#include <hip/hip_bf16.h>

static __device__ __forceinline__ float elu_f(float x) {
    return x > 0.f ? x : expm1f(x);
}

static __device__ __forceinline__ ushort f2bf(float x) {
    __hip_bfloat16 h = __float2bfloat16(x);
    ushort u;
    __builtin_memcpy(&u, &h, 2);
    return u;
}

typedef short bf16x8 __attribute__((ext_vector_type(8)));
typedef float f32x4  __attribute__((ext_vector_type(4)));

static __device__ __forceinline__ void bf8_unpack(uint4 v, float* f) {
    f[0] = __uint_as_float(v.x << 16);
    f[1] = __uint_as_float(v.x & 0xffff0000u);
    f[2] = __uint_as_float(v.y << 16);
    f[3] = __uint_as_float(v.y & 0xffff0000u);
    f[4] = __uint_as_float(v.z << 16);
    f[5] = __uint_as_float(v.z & 0xffff0000u);
    f[6] = __uint_as_float(v.w << 16);
    f[7] = __uint_as_float(v.w & 0xffff0000u);
}

static __device__ __forceinline__ uint4 bf8_pack(const float* a) {
    uint4 o;
    o.x = (uint)f2bf(a[0]) | ((uint)f2bf(a[1]) << 16);
    o.y = (uint)f2bf(a[2]) | ((uint)f2bf(a[3]) << 16);
    o.z = (uint)f2bf(a[4]) | ((uint)f2bf(a[5]) << 16);
    o.w = (uint)f2bf(a[6]) | ((uint)f2bf(a[7]) << 16);
    return o;
}

// ================= W prep (also zeroes bcnt in block 0) =================
__global__ void k_wprep4(const float* __restrict__ W1, const float* __restrict__ W2,
                         const float* __restrict__ W3, const float* __restrict__ W4,
                         ushort* __restrict__ T1, ushort* __restrict__ T2,
                         ushort* __restrict__ T3, ushort* __restrict__ T4,
                         int* __restrict__ bcnt) {
    const int b = blockIdx.x;
    if (b == 0) bcnt[threadIdx.x] = 0;
    const float* W; ushort* T; int K, base;
    if      (b < 48)  { W = W1; T = T1; K = 128; base = b;       }
    else if (b < 96)  { W = W2; T = T2; K = 128; base = b - 48;  }
    else if (b < 132) { W = W3; T = T3; K = 96;  base = b - 96;  }
    else              { W = W4; T = T4; K = 96;  base = b - 132; }
    const int i = base * 256 + threadIdx.x;
    const int kk = i / 96, c = i - kk * 96;
    T[c * K + kk] = f2bf(W[i]);
}

// ================= bucketed CSR build (no global per-node atomics) =================
__global__ __launch_bounds__(256) void
k_bcount(const int* __restrict__ col, int* __restrict__ bcnt, int E, int bspan) {
    __shared__ int h[256];
    const int tid = threadIdx.x;
    h[tid] = 0;
    __syncthreads();
    const int e0 = blockIdx.x * 4096;
    #pragma unroll
    for (int j = 0; j < 16; ++j) {
        int e = e0 + j * 256 + tid;
        if (e < E) atomicAdd(&h[col[e] / bspan], 1);
    }
    __syncthreads();
    if (h[tid] > 0) atomicAdd(&bcnt[tid], h[tid]);
}

__global__ __launch_bounds__(256) void
k_bscan(const int* __restrict__ bcnt, int* __restrict__ bOff, int* __restrict__ bCur) {
    __shared__ int wsum[4];
    const int tid = threadIdx.x, lane = tid & 63, wid = tid >> 6;
    int v = bcnt[tid];
    int s = v;
    #pragma unroll
    for (int d = 1; d < 64; d <<= 1) {
        int t = __shfl_up(s, d);
        if (lane >= d) s += t;
    }
    if (lane == 63) wsum[wid] = s;
    __syncthreads();
    int wb = 0;
    #pragma unroll
    for (int k = 0; k < 3; ++k) if (k < wid) wb += wsum[k];
    int excl = s - v + wb;
    bOff[tid] = excl;
    bCur[tid] = excl;
    if (tid == 255) bOff[256] = excl + v;
}

__global__ __launch_bounds__(256) void
k_bscatter(const int* __restrict__ row, const int* __restrict__ col,
           const float* __restrict__ w, int* __restrict__ bCur,
           int2* __restrict__ ebuf, int* __restrict__ edst, int E, int bspan) {
    __shared__ int h[256];
    __shared__ int base[256];
    const int tid = threadIdx.x;
    h[tid] = 0;
    __syncthreads();
    const int e0 = blockIdx.x * 4096;
    int bk[16], rk[16];
    #pragma unroll
    for (int j = 0; j < 16; ++j) {
        int e = e0 + j * 256 + tid;
        if (e < E) {
            int b = col[e] / bspan;
            bk[j] = b;
            rk[j] = atomicAdd(&h[b], 1);
        }
    }
    __syncthreads();
    base[tid] = (h[tid] > 0) ? atomicAdd(&bCur[tid], h[tid]) : 0;
    __syncthreads();
    #pragma unroll
    for (int j = 0; j < 16; ++j) {
        int e = e0 + j * 256 + tid;
        if (e < E) {
            int pos = base[bk[j]] + rk[j];
            ebuf[pos] = make_int2(row[e], __float_as_int(w[e]));
            edst[pos] = col[e];
        }
    }
}

__global__ __launch_bounds__(256) void
k_csrify(const int2* __restrict__ ebuf, const int* __restrict__ edst,
         const int* __restrict__ bOff, int* __restrict__ off, float* __restrict__ dinv,
         int2* __restrict__ pairs, int N, int E, int bspan) {
    __shared__ int hist[256];
    __shared__ float degs[256];
    __shared__ int curl[256];
    __shared__ int wsum[4];
    const int tid = threadIdx.x, b = blockIdx.x;
    const int base = b * bspan;
    const int lnodes = (N - base < bspan) ? (N - base) : bspan;
    if (b == 0 && tid == 0) off[N] = E;
    if (lnodes <= 0) return;
    hist[tid] = 0;
    degs[tid] = 0.f;
    __syncthreads();
    const int e0 = bOff[b], e1 = bOff[b + 1];
    for (int e = e0 + tid; e < e1; e += 256) {
        int d = edst[e] - base;
        atomicAdd(&hist[d], 1);
        atomicAdd(&degs[d], __int_as_float(ebuf[e].y));
    }
    __syncthreads();
    const int lane = tid & 63, wid = tid >> 6;
    int v = hist[tid];
    int s = v;
    #pragma unroll
    for (int d = 1; d < 64; d <<= 1) {
        int t = __shfl_up(s, d);
        if (lane >= d) s += t;
    }
    if (lane == 63) wsum[wid] = s;
    __syncthreads();
    int wb = 0;
    #pragma unroll
    for (int k = 0; k < 3; ++k) if (k < wid) wb += wsum[k];
    int excl = s - v + wb;
    if (tid < lnodes) {
        off[base + tid] = e0 + excl;
        dinv[base + tid] = rsqrtf(1.0f + degs[tid]);
    }
    curl[tid] = excl;
    __syncthreads();
    for (int e = e0 + tid; e < e1; e += 256) {
        int d = edst[e] - base;
        int p = atomicAdd(&curl[d], 1);
        pairs[e0 + p] = ebuf[e];
    }
}

// ================= MFMA GEMM: out[N,96] = X[N,K]@W[K,96] =================
// XBF: input is bf16 (straight copy staging) vs fp32 (convert at staging).
template<int K, int XBF>
__global__ __launch_bounds__(256) void
k_gemm_mfma(const void* __restrict__ Xv, const ushort* __restrict__ Wt,
            const float* __restrict__ bias, const float* __restrict__ dscale,
            void* __restrict__ outp, int N, int act, int obf16) {
    constexpr int KP = K + 8;
    __shared__ ushort XT[64 * KP];
    __shared__ ushort WT[96 * KP];
    const int tid = threadIdx.x;
    const int n0  = blockIdx.x * 64;

    #pragma unroll
    for (int i = tid; i < 96 * K / 8; i += 256) {
        const int c = i / (K / 8), q = i - c * (K / 8);
        uint4 v = reinterpret_cast<const uint4*>(Wt)[i];
        *reinterpret_cast<uint4*>(&WT[c * KP + q * 8]) = v;
    }
    if (XBF) {
        const ushort* X = (const ushort*)Xv;
        #pragma unroll
        for (int i = tid; i < 64 * K / 8; i += 256) {
            const int row = i / (K / 8), q = i - row * (K / 8);
            const int n = (n0 + row < N) ? (n0 + row) : (N - 1);
            uint4 v = *reinterpret_cast<const uint4*>(X + (size_t)n * K + q * 8);
            *reinterpret_cast<uint4*>(&XT[row * KP + q * 8]) = v;
        }
    } else {
        const float* X = (const float*)Xv;
        #pragma unroll
        for (int i = tid; i < 64 * K / 4; i += 256) {
            const int row = i / (K / 4), q = i - row * (K / 4);
            const int n = (n0 + row < N) ? (n0 + row) : (N - 1);
            float4 v = *reinterpret_cast<const float4*>(X + (size_t)n * K + q * 4);
            uint lo = (uint)f2bf(v.x) | ((uint)f2bf(v.y) << 16);
            uint hi = (uint)f2bf(v.z) | ((uint)f2bf(v.w) << 16);
            *reinterpret_cast<uint2*>(&XT[row * KP + q * 4]) = make_uint2(lo, hi);
        }
    }
    __syncthreads();

    const int lane = tid & 63;
    const int wv   = tid >> 6;
    const int r16  = lane & 15;
    const int kh   = lane >> 4;

    bf16x8 a[K / 32];
    const ushort* xbase = &XT[(wv * 16 + r16) * KP + kh * 8];
    #pragma unroll
    for (int ks = 0; ks < K / 32; ++ks)
        a[ks] = *reinterpret_cast<const bf16x8*>(xbase + ks * 32);

    f32x4 acc[6];
    #pragma unroll
    for (int ct = 0; ct < 6; ++ct) {
        f32x4 c = {0.f, 0.f, 0.f, 0.f};
        const ushort* wbase = &WT[(ct * 16 + r16) * KP + kh * 8];
        #pragma unroll
        for (int ks = 0; ks < K / 32; ++ks) {
            bf16x8 bfr = *reinterpret_cast<const bf16x8*>(wbase + ks * 32);
            c = __builtin_amdgcn_mfma_f32_16x16x32_bf16(a[ks], bfr, c, 0, 0, 0);
        }
        acc[ct] = c;
    }

    #pragma unroll
    for (int r = 0; r < 4; ++r) {
        const int n = n0 + wv * 16 + kh * 4 + r;
        if (n >= N) continue;
        const float ds = dscale ? dscale[n] : 1.f;
        #pragma unroll
        for (int ct = 0; ct < 6; ++ct) {
            const int col = ct * 16 + r16;
            float v = acc[ct][r] * ds;
            if (bias) v += bias[col];
            if (act) v = elu_f(v);
            if (obf16) ((ushort*)outp)[(size_t)n * 96 + col] = f2bf(v);
            else       ((float*)outp)[(size_t)n * 96 + col] = v;
        }
    }
}

// ================= aggregation: out_bf16 = elu(dinv*(M'[n]+sum w*M'[src])+bias)(+res) ====
// 6 threads/node, 16 features (2x uint4) each; depth-3 pipeline -> 6 loads in flight.
__global__ __launch_bounds__(256) void
k_aggregate(const ushort* __restrict__ tmp, const int* __restrict__ off,
            const int2* __restrict__ pairs, const float* __restrict__ dinv,
            const float* __restrict__ bias, const ushort* __restrict__ addsrc,
            ushort* __restrict__ out, int N) {
    int t = blockIdx.x * blockDim.x + threadIdx.x;
    int n = t / 6;
    if (n >= N) return;
    const int c = (t % 6) * 16;
    const ushort* base = tmp + c;

    const float di = dinv[n];
    float f[16], acc[16];
    {
        uint4 s0 = *reinterpret_cast<const uint4*>(base + (size_t)n * 96);
        uint4 s1 = *reinterpret_cast<const uint4*>(base + (size_t)n * 96 + 8);
        bf8_unpack(s0, f);
        bf8_unpack(s1, f + 8);
        #pragma unroll
        for (int i = 0; i < 16; ++i) acc[i] = f[i];   // self-loop, raw weight 1
    }

    const int e0 = off[n];
    const int e1 = off[n + 1];
    const int m  = e1 - e0;

    int2 pA, pB, pC;
    uint4 hA0, hA1, hB0, hB1, hC0, hC1;
    if (m > 0) {
        pA = pairs[e0];
        const ushort* r = base + (size_t)pA.x * 96;
        hA0 = *reinterpret_cast<const uint4*>(r);
        hA1 = *reinterpret_cast<const uint4*>(r + 8);
    }
    if (m > 1) {
        pB = pairs[e0 + 1];
        const ushort* r = base + (size_t)pB.x * 96;
        hB0 = *reinterpret_cast<const uint4*>(r);
        hB1 = *reinterpret_cast<const uint4*>(r + 8);
    }
    if (m > 2) {
        pC = pairs[e0 + 2];
        const ushort* r = base + (size_t)pC.x * 96;
        hC0 = *reinterpret_cast<const uint4*>(r);
        hC1 = *reinterpret_cast<const uint4*>(r + 8);
    }

    for (int e = e0 + 3; e < e1; ++e) {
        int2 pD = pairs[e];
        const ushort* r = base + (size_t)pD.x * 96;
        uint4 hD0 = *reinterpret_cast<const uint4*>(r);
        uint4 hD1 = *reinterpret_cast<const uint4*>(r + 8);
        float w = __int_as_float(pA.y);
        bf8_unpack(hA0, f);
        bf8_unpack(hA1, f + 8);
        #pragma unroll
        for (int i = 0; i < 16; ++i) acc[i] = fmaf(w, f[i], acc[i]);
        pA = pB; hA0 = hB0; hA1 = hB1;
        pB = pC; hB0 = hC0; hB1 = hC1;
        pC = pD; hC0 = hD0; hC1 = hD1;
    }
    if (m > 0) {
        float w = __int_as_float(pA.y);
        bf8_unpack(hA0, f); bf8_unpack(hA1, f + 8);
        #pragma unroll
        for (int i = 0; i < 16; ++i) acc[i] = fmaf(w, f[i], acc[i]);
    }
    if (m > 1) {
        float w = __int_as_float(pB.y);
        bf8_unpack(hB0, f); bf8_unpack(hB1, f + 8);
        #pragma unroll
        for (int i = 0; i < 16; ++i) acc[i] = fmaf(w, f[i], acc[i]);
    }
    if (m > 2) {
        float w = __int_as_float(pC.y);
        bf8_unpack(hC0, f); bf8_unpack(hC1, f + 8);
        #pragma unroll
        for (int i = 0; i < 16; ++i) acc[i] = fmaf(w, f[i], acc[i]);
    }

    #pragma unroll
    for (int q = 0; q < 4; ++q) {
        float4 bv = *reinterpret_cast<const float4*>(bias + c + q * 4);
        acc[q * 4 + 0] = elu_f(fmaf(di, acc[q * 4 + 0], bv.x));
        acc[q * 4 + 1] = elu_f(fmaf(di, acc[q * 4 + 1], bv.y));
        acc[q * 4 + 2] = elu_f(fmaf(di, acc[q * 4 + 2], bv.z));
        acc[q * 4 + 3] = elu_f(fmaf(di, acc[q * 4 + 3], bv.w));
    }
    if (addsrc) {
        uint4 r0 = *reinterpret_cast<const uint4*>(addsrc + (size_t)n * 96 + c);
        uint4 r1 = *reinterpret_cast<const uint4*>(addsrc + (size_t)n * 96 + c + 8);
        bf8_unpack(r0, f); bf8_unpack(r1, f + 8);
        #pragma unroll
        for (int i = 0; i < 16; ++i) acc[i] += f[i];
    }
    ushort* op = out + (size_t)n * 96 + c;
    *reinterpret_cast<uint4*>(op)     = bf8_pack(acc);
    *reinterpret_cast<uint4*>(op + 8) = bf8_pack(acc + 8);
}

// ================= final: logits + log_softmax (lane = node, bf16 h) =================
__global__ __launch_bounds__(128) void
k_lin2_lsm(const ushort* __restrict__ h, const float* __restrict__ W2,
           const float* __restrict__ b2, float* __restrict__ out, int N) {
    __shared__ float hsT[96][128];
    const int tid = threadIdx.x;
    const int n0 = blockIdx.x * 128;
    const int nn = (N - n0 < 128) ? (N - n0) : 128;

    if (tid < nn) {
        const ushort* hr = h + (size_t)(n0 + tid) * 96;
        #pragma unroll
        for (int q = 0; q < 12; ++q) {
            uint4 v = *reinterpret_cast<const uint4*>(hr + q * 8);
            float f[8];
            bf8_unpack(v, f);
            #pragma unroll
            for (int j = 0; j < 8; ++j) hsT[q * 8 + j][tid] = f[j];
        }
    }
    __syncthreads();

    float acc[40];
    #pragma unroll
    for (int c = 0; c < 40; ++c) acc[c] = b2[c];
    for (int k = 0; k < 96; ++k) {
        const float hv = hsT[k][tid];
        const float* wr = W2 + k * 40;
        #pragma unroll
        for (int c = 0; c < 40; ++c) acc[c] = fmaf(hv, wr[c], acc[c]);
    }

    float m = acc[0];
    #pragma unroll
    for (int c = 1; c < 40; ++c) m = fmaxf(m, acc[c]);
    float s = 0.f;
    #pragma unroll
    for (int c = 0; c < 40; ++c) s += expf(acc[c] - m);
    const float lse = m + logf(s);

    if (tid < nn) {
        float* op = out + (size_t)(n0 + tid) * 40;
        #pragma unroll
        for (int q = 0; q < 10; ++q) {
            float4 v = make_float4(acc[q * 4 + 0] - lse, acc[q * 4 + 1] - lse,
                                   acc[q * 4 + 2] - lse, acc[q * 4 + 3] - lse);
            *reinterpret_cast<float4*>(op + q * 4) = v;
        }
    }
}

// ================= launch =================

extern "C" void kernel_launch(void* const* d_in, const int* in_sizes, int n_in,
                              void* d_out, int out_size, void* d_ws, size_t ws_size,
                              hipStream_t stream) {
    const float* x   = (const float*)d_in[0];
    const int*   ei  = (const int*)d_in[1];
    const float* ew  = (const float*)d_in[2];
    const float* Wc1 = (const float*)d_in[3];
    const float* bc1 = (const float*)d_in[4];
    const float* Wc2 = (const float*)d_in[5];
    const float* bc2 = (const float*)d_in[6];
    const float* Wc3 = (const float*)d_in[7];
    const float* bc3 = (const float*)d_in[8];
    const float* Wl1 = (const float*)d_in[9];
    const float* bl1 = (const float*)d_in[10];
    const float* Wl2 = (const float*)d_in[11];
    const float* bl2 = (const float*)d_in[12];

    const int FIN = 128, HID = 96;
    const int N = in_sizes[0] / FIN;
    const int E = in_sizes[2];
    const int* row = ei;
    const int* col = ei + E;
    const int bspan = (N + 255) / 256;

    char* ws = (char*)d_ws;
    size_t o = 0;
    auto alloc = [&](size_t bytes) -> void* {
        void* p = ws + o;
        o += (bytes + 255) & ~(size_t)255;
        return p;
    };
    float*  dinv   = (float*)alloc((size_t)N * 4);
    int*    off    = (int*)  alloc((size_t)(N + 1) * 4);
    int*    bcnt   = (int*)  alloc(256 * 4);
    int*    bOff   = (int*)  alloc(257 * 4);
    int*    bCur   = (int*)  alloc(256 * 4);
    int2*   pairs  = (int2*) alloc((size_t)E * 8);
    ushort* M1     = (ushort*)alloc((size_t)N * HID * 2);
    ushort* M2     = (ushort*)alloc((size_t)N * HID * 2);
    ushort* Bb     = (ushort*)alloc((size_t)N * HID * 2);   // residual x1 (bf16)
    ushort* Cb     = (ushort*)alloc((size_t)N * HID * 2);   // running h (bf16)
    ushort* Wt_c1  = (ushort*)alloc(96 * 128 * 2);
    ushort* Wt_l1  = (ushort*)alloc(96 * 128 * 2);
    ushort* Wt_c2  = (ushort*)alloc(96 * 96 * 2);
    ushort* Wt_c3  = (ushort*)alloc(96 * 96 * 2);
    // prep scratch aliases the message tables (dead until GEMMs run)
    int2*   ebuf   = (int2*)M1;   // E*8  <= N*96*2
    int*    edst   = (int*)M2;    // E*4  <= N*96*2

    const int gBkt  = (E + 4095) / 4096;
    const int nGemm = (N + 63) / 64;
    const int nAgg  = (N * 6 + 255) / 256;

    // weight prep (+ bcnt zero)
    k_wprep4<<<168, 256, 0, stream>>>(Wc1, Wl1, Wc2, Wc3, Wt_c1, Wt_l1, Wt_c2, Wt_c3, bcnt);

    // bucketed CSR build
    k_bcount<<<gBkt, 256, 0, stream>>>(col, bcnt, E, bspan);
    k_bscan<<<1, 256, 0, stream>>>(bcnt, bOff, bCur);
    k_bscatter<<<gBkt, 256, 0, stream>>>(row, col, ew, bCur, ebuf, edst, E, bspan);
    k_csrify<<<256, 256, 0, stream>>>(ebuf, edst, bOff, off, dinv, pairs, N, E, bspan);

    // conv1 GEMM (messages pre-scaled by dinv) + lin1 GEMM
    k_gemm_mfma<128, 0><<<nGemm, 256, 0, stream>>>(x, Wt_c1, nullptr, dinv, M1, N, 0, 1);
    k_gemm_mfma<128, 0><<<nGemm, 256, 0, stream>>>(x, Wt_l1, bl1, nullptr, Cb, N, 1, 1);

    // conv1 aggregate -> Bb (residual)
    k_aggregate<<<nAgg, 256, 0, stream>>>(M1, off, pairs, dinv, bc1, nullptr, Bb, N);

    // conv2
    k_gemm_mfma<96, 1><<<nGemm, 256, 0, stream>>>(Cb, Wt_c2, nullptr, dinv, M2, N, 0, 1);
    k_aggregate<<<nAgg, 256, 0, stream>>>(M2, off, pairs, dinv, bc2, nullptr, Cb, N);

    // conv3 (+residual Bb)
    k_gemm_mfma<96, 1><<<nGemm, 256, 0, stream>>>(Cb, Wt_c3, nullptr, dinv, M1, N, 0, 1);
    k_aggregate<<<nAgg, 256, 0, stream>>>(M1, off, pairs, dinv, bc3, Bb, Cb, N);

    // lin2 + log_softmax
    k_lin2_lsm<<<(N + 127) / 128, 128, 0, stream>>>(Cb, Wl2, bl2, (float*)d_out, N);
}

// Round 12
// 209.533 us; speedup vs baseline: 3.7632x; 1.0957x over previous
//
#include <hip/hip_runtime.h>
#include <hip/hip_bf16.h>

static __device__ __forceinline__ float elu_f(float x) {
    return x > 0.f ? x : expm1f(x);
}

static __device__ __forceinline__ ushort f2bf(float x) {
    __hip_bfloat16 h = __float2bfloat16(x);
    ushort u;
    __builtin_memcpy(&u, &h, 2);
    return u;
}

typedef short bf16x8 __attribute__((ext_vector_type(8)));
typedef float f32x4  __attribute__((ext_vector_type(4)));

static __device__ __forceinline__ void bf8_unpack(uint4 v, float* f) {
    f[0] = __uint_as_float(v.x << 16);
    f[1] = __uint_as_float(v.x & 0xffff0000u);
    f[2] = __uint_as_float(v.y << 16);
    f[3] = __uint_as_float(v.y & 0xffff0000u);
    f[4] = __uint_as_float(v.z << 16);
    f[5] = __uint_as_float(v.z & 0xffff0000u);
    f[6] = __uint_as_float(v.w << 16);
    f[7] = __uint_as_float(v.w & 0xffff0000u);
}

static __device__ __forceinline__ uint4 bf8_pack(const float* a) {
    uint4 o;
    o.x = (uint)f2bf(a[0]) | ((uint)f2bf(a[1]) << 16);
    o.y = (uint)f2bf(a[2]) | ((uint)f2bf(a[3]) << 16);
    o.z = (uint)f2bf(a[4]) | ((uint)f2bf(a[5]) << 16);
    o.w = (uint)f2bf(a[6]) | ((uint)f2bf(a[7]) << 16);
    return o;
}

// ================= W prep (blocks 0/1 also zero bcnt/bRes) =================
__global__ void k_wprep4(const float* __restrict__ W1, const float* __restrict__ W2,
                         const float* __restrict__ W3, const float* __restrict__ W4,
                         ushort* __restrict__ T1, ushort* __restrict__ T2,
                         ushort* __restrict__ T3, ushort* __restrict__ T4,
                         int* __restrict__ bcnt, int* __restrict__ bRes) {
    const int b = blockIdx.x;
    if (b == 0) bcnt[threadIdx.x] = 0;
    if (b == 1) bRes[threadIdx.x] = 0;
    const float* W; ushort* T; int K, base;
    if      (b < 48)  { W = W1; T = T1; K = 128; base = b;       }
    else if (b < 96)  { W = W2; T = T2; K = 128; base = b - 48;  }
    else if (b < 132) { W = W3; T = T3; K = 96;  base = b - 96;  }
    else              { W = W4; T = T4; K = 96;  base = b - 132; }
    const int i = base * 256 + threadIdx.x;
    const int kk = i / 96, c = i - kk * 96;
    T[c * K + kk] = f2bf(W[i]);
}

// ================= bucketed CSR build =================
__global__ __launch_bounds__(256) void
k_bcount(const int* __restrict__ col, int* __restrict__ bcnt, int E, int bspan) {
    __shared__ int h[256];
    const int tid = threadIdx.x;
    h[tid] = 0;
    __syncthreads();
    const int e0 = blockIdx.x * 4096;
    #pragma unroll
    for (int j = 0; j < 16; ++j) {
        int e = e0 + j * 256 + tid;
        if (e < E) atomicAdd(&h[col[e] / bspan], 1);
    }
    __syncthreads();
    if (h[tid] > 0) atomicAdd(&bcnt[tid], h[tid]);
}

// scatter edges into bucket regions; bucket bases computed from a local scan of bcnt,
// block reservation via bRes atomics.
__global__ __launch_bounds__(256) void
k_bscatter(const int* __restrict__ row, const int* __restrict__ col,
           const float* __restrict__ w, const int* __restrict__ bcnt,
           int* __restrict__ bRes, int2* __restrict__ ebuf, int* __restrict__ edst,
           int E, int bspan) {
    __shared__ int h[256];
    __shared__ int base[256];
    __shared__ int sOff[256];
    __shared__ int wsum[4];
    const int tid = threadIdx.x, lane = tid & 63, wid = tid >> 6;
    h[tid] = 0;
    const int bc = bcnt[tid];
    __syncthreads();
    const int e0 = blockIdx.x * 4096;
    int bk[16], rk[16];
    #pragma unroll
    for (int j = 0; j < 16; ++j) {
        int e = e0 + j * 256 + tid;
        if (e < E) {
            int b = col[e] / bspan;
            bk[j] = b;
            rk[j] = atomicAdd(&h[b], 1);
        }
    }
    // local exclusive scan of bcnt -> sOff
    {
        int s = bc;
        #pragma unroll
        for (int d = 1; d < 64; d <<= 1) {
            int t = __shfl_up(s, d);
            if (lane >= d) s += t;
        }
        if (lane == 63) wsum[wid] = s;
        __syncthreads();
        int wb = 0;
        #pragma unroll
        for (int k = 0; k < 3; ++k) if (k < wid) wb += wsum[k];
        sOff[tid] = s - bc + wb;
    }
    __syncthreads();
    base[tid] = (h[tid] > 0) ? (sOff[tid] + atomicAdd(&bRes[tid], h[tid])) : 0;
    __syncthreads();
    #pragma unroll
    for (int j = 0; j < 16; ++j) {
        int e = e0 + j * 256 + tid;
        if (e < E) {
            int pos = base[bk[j]] + rk[j];
            ebuf[pos] = make_int2(row[e], __float_as_int(w[e]));
            edst[pos] = col[e];
        }
    }
}

__global__ __launch_bounds__(256) void
k_csrify(const int2* __restrict__ ebuf, const int* __restrict__ edst,
         const int* __restrict__ bcnt, int* __restrict__ off, float* __restrict__ dinv,
         int2* __restrict__ pairs, int N, int E, int bspan) {
    __shared__ int hist[256];
    __shared__ float degs[256];
    __shared__ int curl[256];
    __shared__ int wsum[4];
    __shared__ int sE0;
    const int tid = threadIdx.x, b = blockIdx.x;
    const int lane = tid & 63, wid = tid >> 6;
    const int base = b * bspan;
    const int lnodes = (N - base < bspan) ? (N - base) : bspan;
    if (b == 0 && tid == 0) off[N] = E;
    if (lnodes <= 0) return;
    hist[tid] = 0;
    degs[tid] = 0.f;
    const int bc = bcnt[tid];
    // local exclusive scan of bcnt -> this block needs only element b
    {
        int s = bc;
        #pragma unroll
        for (int d = 1; d < 64; d <<= 1) {
            int t = __shfl_up(s, d);
            if (lane >= d) s += t;
        }
        if (lane == 63) wsum[wid] = s;
        __syncthreads();
        int wb = 0;
        #pragma unroll
        for (int k = 0; k < 3; ++k) if (k < wid) wb += wsum[k];
        if (tid == b) sE0 = s - bc + wb;
    }
    __syncthreads();
    const int e0 = sE0, e1 = sE0 + bcnt[b];
    for (int e = e0 + tid; e < e1; e += 256) {
        int d = edst[e] - base;
        atomicAdd(&hist[d], 1);
        atomicAdd(&degs[d], __int_as_float(ebuf[e].y));
    }
    __syncthreads();
    int v = hist[tid];
    int s = v;
    #pragma unroll
    for (int d = 1; d < 64; d <<= 1) {
        int t = __shfl_up(s, d);
        if (lane >= d) s += t;
    }
    if (lane == 63) wsum[wid] = s;
    __syncthreads();
    int wb = 0;
    #pragma unroll
    for (int k = 0; k < 3; ++k) if (k < wid) wb += wsum[k];
    int excl = s - v + wb;
    if (tid < lnodes) {
        off[base + tid] = e0 + excl;
        dinv[base + tid] = rsqrtf(1.0f + degs[tid]);
    }
    curl[tid] = excl;
    __syncthreads();
    for (int e = e0 + tid; e < e1; e += 256) {
        int d = edst[e] - base;
        int p = atomicAdd(&curl[d], 1);
        pairs[e0 + p] = ebuf[e];
    }
}

// ================= MFMA GEMM body =================
template<int K, int XBF>
__device__ __forceinline__ void gemm_body(
    const void* __restrict__ Xv, const ushort* __restrict__ Wt,
    const float* __restrict__ bias, const float* __restrict__ dscale,
    void* __restrict__ outp, int N, int act, int obf16, int bid) {
    constexpr int KP = K + 8;
    __shared__ ushort XT[64 * KP];
    __shared__ ushort WT[96 * KP];
    const int tid = threadIdx.x;
    const int n0  = bid * 64;

    #pragma unroll
    for (int i = tid; i < 96 * K / 8; i += 256) {
        const int c = i / (K / 8), q = i - c * (K / 8);
        uint4 v = reinterpret_cast<const uint4*>(Wt)[i];
        *reinterpret_cast<uint4*>(&WT[c * KP + q * 8]) = v;
    }
    if (XBF) {
        const ushort* X = (const ushort*)Xv;
        #pragma unroll
        for (int i = tid; i < 64 * K / 8; i += 256) {
            const int row = i / (K / 8), q = i - row * (K / 8);
            const int n = (n0 + row < N) ? (n0 + row) : (N - 1);
            uint4 v = *reinterpret_cast<const uint4*>(X + (size_t)n * K + q * 8);
            *reinterpret_cast<uint4*>(&XT[row * KP + q * 8]) = v;
        }
    } else {
        const float* X = (const float*)Xv;
        #pragma unroll
        for (int i = tid; i < 64 * K / 4; i += 256) {
            const int row = i / (K / 4), q = i - row * (K / 4);
            const int n = (n0 + row < N) ? (n0 + row) : (N - 1);
            float4 v = *reinterpret_cast<const float4*>(X + (size_t)n * K + q * 4);
            uint lo = (uint)f2bf(v.x) | ((uint)f2bf(v.y) << 16);
            uint hi = (uint)f2bf(v.z) | ((uint)f2bf(v.w) << 16);
            *reinterpret_cast<uint2*>(&XT[row * KP + q * 4]) = make_uint2(lo, hi);
        }
    }
    __syncthreads();

    const int lane = tid & 63;
    const int wv   = tid >> 6;
    const int r16  = lane & 15;
    const int kh   = lane >> 4;

    bf16x8 a[K / 32];
    const ushort* xbase = &XT[(wv * 16 + r16) * KP + kh * 8];
    #pragma unroll
    for (int ks = 0; ks < K / 32; ++ks)
        a[ks] = *reinterpret_cast<const bf16x8*>(xbase + ks * 32);

    f32x4 acc[6];
    #pragma unroll
    for (int ct = 0; ct < 6; ++ct) {
        f32x4 c = {0.f, 0.f, 0.f, 0.f};
        const ushort* wbase = &WT[(ct * 16 + r16) * KP + kh * 8];
        #pragma unroll
        for (int ks = 0; ks < K / 32; ++ks) {
            bf16x8 bfr = *reinterpret_cast<const bf16x8*>(wbase + ks * 32);
            c = __builtin_amdgcn_mfma_f32_16x16x32_bf16(a[ks], bfr, c, 0, 0, 0);
        }
        acc[ct] = c;
    }

    #pragma unroll
    for (int r = 0; r < 4; ++r) {
        const int n = n0 + wv * 16 + kh * 4 + r;
        if (n >= N) continue;
        const float ds = dscale ? dscale[n] : 1.f;
        #pragma unroll
        for (int ct = 0; ct < 6; ++ct) {
            const int col = ct * 16 + r16;
            float v = acc[ct][r] * ds;
            if (bias) v += bias[col];
            if (act) v = elu_f(v);
            if (obf16) ((ushort*)outp)[(size_t)n * 96 + col] = f2bf(v);
            else       ((float*)outp)[(size_t)n * 96 + col] = v;
        }
    }
}

__global__ __launch_bounds__(256) void
k_gemm_mfma96(const ushort* __restrict__ X, const ushort* __restrict__ Wt,
              const float* __restrict__ dscale, void* __restrict__ outp, int N) {
    gemm_body<96, 1>(X, Wt, nullptr, dscale, outp, N, 0, 1, blockIdx.x);
}

// conv1 + lin1 in one dispatch (identical body -> identical regalloc)
__global__ __launch_bounds__(256) void
k_gemm_fin_dual(const float* __restrict__ X,
                const ushort* __restrict__ Wt1, const float* __restrict__ dscale1,
                void* __restrict__ out1,
                const ushort* __restrict__ Wt2, const float* __restrict__ bias2,
                void* __restrict__ out2, int N, int nHalf) {
    if ((int)blockIdx.x < nHalf)
        gemm_body<128, 0>(X, Wt1, nullptr, dscale1, out1, N, 0, 1, blockIdx.x);
    else
        gemm_body<128, 0>(X, Wt2, bias2, nullptr, out2, N, 1, 1, blockIdx.x - nHalf);
}

// ================= aggregation: LDS-staged pairs + depth-3 gather pipeline =================
#define AGG_CAP 2048

__global__ __launch_bounds__(256) void
k_aggregate(const ushort* __restrict__ tmp, const int* __restrict__ off,
            const int2* __restrict__ pairs, const float* __restrict__ dinv,
            const float* __restrict__ bias, const ushort* __restrict__ addsrc,
            ushort* __restrict__ out, int N) {
    __shared__ int2 eP[AGG_CAP];
    __shared__ int sFlag;   // 1 = pairs staged in LDS
    const int tid = threadIdx.x;
    const int t0  = blockIdx.x * 256;
    int n_first = t0 / 6;
    if (n_first >= N) return;
    int n_last = (t0 + 255) / 6;
    if (n_last >= N) n_last = N - 1;
    const int eb0 = off[n_first];
    const int eb1 = off[n_last + 1];
    const int tot = eb1 - eb0;
    if (tot <= AGG_CAP) {
        for (int i = tid; i < tot; i += 256) eP[i] = pairs[eb0 + i];
        if (tid == 0) sFlag = 1;
    } else {
        if (tid == 0) sFlag = 0;
    }
    __syncthreads();
    const bool lds = (sFlag != 0);

    const int n = (t0 + tid) / 6;
    if (n >= N) return;
    const int c = ((t0 + tid) % 6) * 16;
    const ushort* base = tmp + c;

    auto LOADP = [&](int e) -> int2 {
        return lds ? eP[e - eb0] : pairs[e];
    };

    const float di = dinv[n];
    float f[16], acc[16];
    {
        uint4 s0 = *reinterpret_cast<const uint4*>(base + (size_t)n * 96);
        uint4 s1 = *reinterpret_cast<const uint4*>(base + (size_t)n * 96 + 8);
        bf8_unpack(s0, f);
        bf8_unpack(s1, f + 8);
        #pragma unroll
        for (int i = 0; i < 16; ++i) acc[i] = f[i];   // self-loop, raw weight 1
    }

    const int e0 = off[n];
    const int e1 = off[n + 1];
    const int m  = e1 - e0;

    int2 pA, pB, pC;
    uint4 hA0, hA1, hB0, hB1, hC0, hC1;
    if (m > 0) {
        pA = LOADP(e0);
        const ushort* r = base + (size_t)pA.x * 96;
        hA0 = *reinterpret_cast<const uint4*>(r);
        hA1 = *reinterpret_cast<const uint4*>(r + 8);
    }
    if (m > 1) {
        pB = LOADP(e0 + 1);
        const ushort* r = base + (size_t)pB.x * 96;
        hB0 = *reinterpret_cast<const uint4*>(r);
        hB1 = *reinterpret_cast<const uint4*>(r + 8);
    }
    if (m > 2) {
        pC = LOADP(e0 + 2);
        const ushort* r = base + (size_t)pC.x * 96;
        hC0 = *reinterpret_cast<const uint4*>(r);
        hC1 = *reinterpret_cast<const uint4*>(r + 8);
    }

    for (int e = e0 + 3; e < e1; ++e) {
        int2 pD = LOADP(e);
        const ushort* r = base + (size_t)pD.x * 96;
        uint4 hD0 = *reinterpret_cast<const uint4*>(r);
        uint4 hD1 = *reinterpret_cast<const uint4*>(r + 8);
        float w = __int_as_float(pA.y);
        bf8_unpack(hA0, f);
        bf8_unpack(hA1, f + 8);
        #pragma unroll
        for (int i = 0; i < 16; ++i) acc[i] = fmaf(w, f[i], acc[i]);
        pA = pB; hA0 = hB0; hA1 = hB1;
        pB = pC; hB0 = hC0; hB1 = hC1;
        pC = pD; hC0 = hD0; hC1 = hD1;
    }
    if (m > 0) {
        float w = __int_as_float(pA.y);
        bf8_unpack(hA0, f); bf8_unpack(hA1, f + 8);
        #pragma unroll
        for (int i = 0; i < 16; ++i) acc[i] = fmaf(w, f[i], acc[i]);
    }
    if (m > 1) {
        float w = __int_as_float(pB.y);
        bf8_unpack(hB0, f); bf8_unpack(hB1, f + 8);
        #pragma unroll
        for (int i = 0; i < 16; ++i) acc[i] = fmaf(w, f[i], acc[i]);
    }
    if (m > 2) {
        float w = __int_as_float(pC.y);
        bf8_unpack(hC0, f); bf8_unpack(hC1, f + 8);
        #pragma unroll
        for (int i = 0; i < 16; ++i) acc[i] = fmaf(w, f[i], acc[i]);
    }

    #pragma unroll
    for (int q = 0; q < 4; ++q) {
        float4 bv = *reinterpret_cast<const float4*>(bias + c + q * 4);
        acc[q * 4 + 0] = elu_f(fmaf(di, acc[q * 4 + 0], bv.x));
        acc[q * 4 + 1] = elu_f(fmaf(di, acc[q * 4 + 1], bv.y));
        acc[q * 4 + 2] = elu_f(fmaf(di, acc[q * 4 + 2], bv.z));
        acc[q * 4 + 3] = elu_f(fmaf(di, acc[q * 4 + 3], bv.w));
    }
    if (addsrc) {
        uint4 r0 = *reinterpret_cast<const uint4*>(addsrc + (size_t)n * 96 + c);
        uint4 r1 = *reinterpret_cast<const uint4*>(addsrc + (size_t)n * 96 + c + 8);
        bf8_unpack(r0, f); bf8_unpack(r1, f + 8);
        #pragma unroll
        for (int i = 0; i < 16; ++i) acc[i] += f[i];
    }
    ushort* op = out + (size_t)n * 96 + c;
    *reinterpret_cast<uint4*>(op)     = bf8_pack(acc);
    *reinterpret_cast<uint4*>(op + 8) = bf8_pack(acc + 8);
}

// ================= final: logits + log_softmax (lane = node, bf16 h) =================
__global__ __launch_bounds__(128) void
k_lin2_lsm(const ushort* __restrict__ h, const float* __restrict__ W2,
           const float* __restrict__ b2, float* __restrict__ out, int N) {
    __shared__ float hsT[96][128];
    const int tid = threadIdx.x;
    const int n0 = blockIdx.x * 128;
    const int nn = (N - n0 < 128) ? (N - n0) : 128;

    if (tid < nn) {
        const ushort* hr = h + (size_t)(n0 + tid) * 96;
        #pragma unroll
        for (int q = 0; q < 12; ++q) {
            uint4 v = *reinterpret_cast<const uint4*>(hr + q * 8);
            float f[8];
            bf8_unpack(v, f);
            #pragma unroll
            for (int j = 0; j < 8; ++j) hsT[q * 8 + j][tid] = f[j];
        }
    }
    __syncthreads();

    float acc[40];
    #pragma unroll
    for (int c = 0; c < 40; ++c) acc[c] = b2[c];
    for (int k = 0; k < 96; ++k) {
        const float hv = hsT[k][tid];
        const float* wr = W2 + k * 40;
        #pragma unroll
        for (int c = 0; c < 40; ++c) acc[c] = fmaf(hv, wr[c], acc[c]);
    }

    float m = acc[0];
    #pragma unroll
    for (int c = 1; c < 40; ++c) m = fmaxf(m, acc[c]);
    float s = 0.f;
    #pragma unroll
    for (int c = 0; c < 40; ++c) s += expf(acc[c] - m);
    const float lse = m + logf(s);

    if (tid < nn) {
        float* op = out + (size_t)(n0 + tid) * 40;
        #pragma unroll
        for (int q = 0; q < 10; ++q) {
            float4 v = make_float4(acc[q * 4 + 0] - lse, acc[q * 4 + 1] - lse,
                                   acc[q * 4 + 2] - lse, acc[q * 4 + 3] - lse);
            *reinterpret_cast<float4*>(op + q * 4) = v;
        }
    }
}

// ================= launch =================

extern "C" void kernel_launch(void* const* d_in, const int* in_sizes, int n_in,
                              void* d_out, int out_size, void* d_ws, size_t ws_size,
                              hipStream_t stream) {
    const float* x   = (const float*)d_in[0];
    const int*   ei  = (const int*)d_in[1];
    const float* ew  = (const float*)d_in[2];
    const float* Wc1 = (const float*)d_in[3];
    const float* bc1 = (const float*)d_in[4];
    const float* Wc2 = (const float*)d_in[5];
    const float* bc2 = (const float*)d_in[6];
    const float* Wc3 = (const float*)d_in[7];
    const float* bc3 = (const float*)d_in[8];
    const float* Wl1 = (const float*)d_in[9];
    const float* bl1 = (const float*)d_in[10];
    const float* Wl2 = (const float*)d_in[11];
    const float* bl2 = (const float*)d_in[12];

    const int FIN = 128, HID = 96;
    const int N = in_sizes[0] / FIN;
    const int E = in_sizes[2];
    const int* row = ei;
    const int* col = ei + E;
    const int bspan = (N + 255) / 256;

    char* ws = (char*)d_ws;
    size_t o = 0;
    auto alloc = [&](size_t bytes) -> void* {
        void* p = ws + o;
        o += (bytes + 255) & ~(size_t)255;
        return p;
    };
    float*  dinv   = (float*)alloc((size_t)N * 4);
    int*    off    = (int*)  alloc((size_t)(N + 1) * 4);
    int*    bcnt   = (int*)  alloc(256 * 4);
    int*    bRes   = (int*)  alloc(256 * 4);
    int2*   pairs  = (int2*) alloc((size_t)E * 8);
    ushort* M1     = (ushort*)alloc((size_t)N * HID * 2);
    ushort* M2     = (ushort*)alloc((size_t)N * HID * 2);
    ushort* Bb     = (ushort*)alloc((size_t)N * HID * 2);   // residual x1 (bf16)
    ushort* Cb     = (ushort*)alloc((size_t)N * HID * 2);   // running h (bf16)
    ushort* Wt_c1  = (ushort*)alloc(96 * 128 * 2);
    ushort* Wt_l1  = (ushort*)alloc(96 * 128 * 2);
    ushort* Wt_c2  = (ushort*)alloc(96 * 96 * 2);
    ushort* Wt_c3  = (ushort*)alloc(96 * 96 * 2);
    // prep scratch aliases the message tables (dead until GEMMs run)
    int2*   ebuf   = (int2*)M1;   // E*8  <= N*96*2
    int*    edst   = (int*)M2;    // E*4  <= N*96*2

    const int gBkt  = (E + 4095) / 4096;
    const int nGemm = (N + 63) / 64;
    const int nAgg  = (N * 6 + 255) / 256;

    // weight prep (+ bcnt/bRes zero)
    k_wprep4<<<168, 256, 0, stream>>>(Wc1, Wl1, Wc2, Wc3, Wt_c1, Wt_l1, Wt_c2, Wt_c3,
                                      bcnt, bRes);

    // bucketed CSR build (scan folded into bscatter/csrify)
    k_bcount<<<gBkt, 256, 0, stream>>>(col, bcnt, E, bspan);
    k_bscatter<<<gBkt, 256, 0, stream>>>(row, col, ew, bcnt, bRes, ebuf, edst, E, bspan);
    k_csrify<<<256, 256, 0, stream>>>(ebuf, edst, bcnt, off, dinv, pairs, N, E, bspan);

    // conv1 GEMM (dinv-scaled messages) + lin1 GEMM, one dispatch
    k_gemm_fin_dual<<<2 * nGemm, 256, 0, stream>>>(x, Wt_c1, dinv, M1,
                                                   Wt_l1, bl1, Cb, N, nGemm);

    // conv1 aggregate -> Bb (residual)
    k_aggregate<<<nAgg, 256, 0, stream>>>(M1, off, pairs, dinv, bc1, nullptr, Bb, N);

    // conv2
    k_gemm_mfma96<<<nGemm, 256, 0, stream>>>(Cb, Wt_c2, dinv, M2, N);
    k_aggregate<<<nAgg, 256, 0, stream>>>(M2, off, pairs, dinv, bc2, nullptr, Cb, N);

    // conv3 (+residual Bb)
    k_gemm_mfma96<<<nGemm, 256, 0, stream>>>(Cb, Wt_c3, dinv, M1, N);
    k_aggregate<<<nAgg, 256, 0, stream>>>(M1, off, pairs, dinv, bc3, Bb, Cb, N);

    // lin2 + log_softmax
    k_lin2_lsm<<<(N + 127) / 128, 128, 0, stream>>>(Cb, Wl2, bl2, (float*)d_out, N);
}

// Round 13
// 185.988 us; speedup vs baseline: 4.2396x; 1.1266x over previous
//
#include <hip/hip_runtime.h>
#include <hip/hip_bf16.h>

static __device__ __forceinline__ float elu_f(float x) {
    return x > 0.f ? x : expm1f(x);
}

static __device__ __forceinline__ ushort f2bf(float x) {
    __hip_bfloat16 h = __float2bfloat16(x);
    ushort u;
    __builtin_memcpy(&u, &h, 2);
    return u;
}

typedef short bf16x8 __attribute__((ext_vector_type(8)));
typedef float f32x4  __attribute__((ext_vector_type(4)));
typedef float floatx2 __attribute__((ext_vector_type(2)));

#if __has_builtin(__builtin_amdgcn_cvt_pk_f32_fp8) && __has_builtin(__builtin_amdgcn_cvt_pk_fp8_f32)
#define FP8_HW 1
#else
#define FP8_HW 0
#endif

// -------- SW e4m3fn codec (fallback only; dead code when FP8_HW=1) --------
static __device__ __forceinline__ float fp8_to_f32_sw(uint b) {
    uint s = (b & 0x80u) << 24;
    uint e = (b >> 3) & 0xfu, m = b & 7u;
    float v = (e == 0) ? ((float)m * 0x1p-9f)
                       : __uint_as_float(((e + 120u) << 23) | (m << 20));
    return __uint_as_float(s | __float_as_uint(v));
}

static __device__ __forceinline__ uint f32_to_fp8_sw(float x) {
    float c = fminf(fmaxf(x, -448.f), 448.f);
    uint s = (__float_as_uint(c) >> 24) & 0x80u;
    float a = fabsf(c);
    uint bits;
    if (a < 0x1p-6f) {
        int mi = (int)rintf(a * 0x1p9f);            // 0..8
        bits = (mi >= 8) ? 0x08u : (uint)mi;
    } else {
        uint u = __float_as_uint(a);
        int eb = (int)((u >> 23) & 0xff) - 127;     // in [-6, 8]
        float sc = a * exp2f((float)(3 - eb));      // [8,16)
        int q = (int)rintf(sc);
        if (q >= 16) { q = 8; eb += 1; }
        bits = (eb > 8) ? 0x7eu : (((uint)(eb + 7) << 3) | (uint)(q - 8));
    }
    return s | bits;
}

static __device__ __forceinline__ uchar f2fp8(float v) {
#if FP8_HW
    return (uchar)((uint)__builtin_amdgcn_cvt_pk_fp8_f32(v, v, 0, false) & 0xffu);
#else
    return (uchar)f32_to_fp8_sw(v);
#endif
}

static __device__ __forceinline__ void fp8x4_unpack(uint w, float* f) {
#if FP8_HW
    floatx2 p0 = __builtin_amdgcn_cvt_pk_f32_fp8((int)w, false);
    floatx2 p1 = __builtin_amdgcn_cvt_pk_f32_fp8((int)w, true);
    f[0] = p0[0]; f[1] = p0[1]; f[2] = p1[0]; f[3] = p1[1];
#else
    f[0] = fp8_to_f32_sw(w & 0xffu);
    f[1] = fp8_to_f32_sw((w >> 8) & 0xffu);
    f[2] = fp8_to_f32_sw((w >> 16) & 0xffu);
    f[3] = fp8_to_f32_sw(w >> 24);
#endif
}

static __device__ __forceinline__ void fp8x16_unpack(uint4 v, float* f) {
    fp8x4_unpack(v.x, f);
    fp8x4_unpack(v.y, f + 4);
    fp8x4_unpack(v.z, f + 8);
    fp8x4_unpack(v.w, f + 12);
}

static __device__ __forceinline__ void bf8_unpack(uint4 v, float* f) {
    f[0] = __uint_as_float(v.x << 16);
    f[1] = __uint_as_float(v.x & 0xffff0000u);
    f[2] = __uint_as_float(v.y << 16);
    f[3] = __uint_as_float(v.y & 0xffff0000u);
    f[4] = __uint_as_float(v.z << 16);
    f[5] = __uint_as_float(v.z & 0xffff0000u);
    f[6] = __uint_as_float(v.w << 16);
    f[7] = __uint_as_float(v.w & 0xffff0000u);
}

static __device__ __forceinline__ uint4 bf8_pack(const float* a) {
    uint4 o;
    o.x = (uint)f2bf(a[0]) | ((uint)f2bf(a[1]) << 16);
    o.y = (uint)f2bf(a[2]) | ((uint)f2bf(a[3]) << 16);
    o.z = (uint)f2bf(a[4]) | ((uint)f2bf(a[5]) << 16);
    o.w = (uint)f2bf(a[6]) | ((uint)f2bf(a[7]) << 16);
    return o;
}

// ================= W prep + bucket count, one dispatch =================
// blocks [0, nW): transpose/convert weights; blocks [nW, ...): bucket histogram.
__global__ __launch_bounds__(256) void
k_wprep_count(const float* __restrict__ W1, const float* __restrict__ W2,
              const float* __restrict__ W3, const float* __restrict__ W4,
              ushort* __restrict__ T1, ushort* __restrict__ T2,
              ushort* __restrict__ T3, ushort* __restrict__ T4,
              const int* __restrict__ col, int* __restrict__ bcnt,
              int E, int bspan, int nW) {
    const int b = blockIdx.x;
    if (b < nW) {
        const float* W; ushort* T; int K, base;
        if      (b < 48)  { W = W1; T = T1; K = 128; base = b;       }
        else if (b < 96)  { W = W2; T = T2; K = 128; base = b - 48;  }
        else if (b < 132) { W = W3; T = T3; K = 96;  base = b - 96;  }
        else              { W = W4; T = T4; K = 96;  base = b - 132; }
        const int i = base * 256 + threadIdx.x;
        const int kk = i / 96, c = i - kk * 96;
        T[c * K + kk] = f2bf(W[i]);
    } else {
        __shared__ int h[256];
        const int tid = threadIdx.x;
        h[tid] = 0;
        __syncthreads();
        const int e0 = (b - nW) * 4096;
        #pragma unroll
        for (int j = 0; j < 16; ++j) {
            int e = e0 + j * 256 + tid;
            if (e < E) atomicAdd(&h[col[e] / bspan], 1);
        }
        __syncthreads();
        if (h[tid] > 0) atomicAdd(&bcnt[tid], h[tid]);
    }
}

// ================= bucketed CSR build =================
__global__ __launch_bounds__(256) void
k_bscatter(const int* __restrict__ row, const int* __restrict__ col,
           const float* __restrict__ w, const int* __restrict__ bcnt,
           int* __restrict__ bRes, int2* __restrict__ ebuf, int* __restrict__ edst,
           int E, int bspan) {
    __shared__ int h[256];
    __shared__ int base[256];
    __shared__ int sOff[256];
    __shared__ int wsum[4];
    const int tid = threadIdx.x, lane = tid & 63, wid = tid >> 6;
    h[tid] = 0;
    const int bc = bcnt[tid];
    __syncthreads();
    const int e0 = blockIdx.x * 4096;
    int bk[16], rk[16];
    #pragma unroll
    for (int j = 0; j < 16; ++j) {
        int e = e0 + j * 256 + tid;
        if (e < E) {
            int b = col[e] / bspan;
            bk[j] = b;
            rk[j] = atomicAdd(&h[b], 1);
        }
    }
    {
        int s = bc;
        #pragma unroll
        for (int d = 1; d < 64; d <<= 1) {
            int t = __shfl_up(s, d);
            if (lane >= d) s += t;
        }
        if (lane == 63) wsum[wid] = s;
        __syncthreads();
        int wb = 0;
        #pragma unroll
        for (int k = 0; k < 3; ++k) if (k < wid) wb += wsum[k];
        sOff[tid] = s - bc + wb;
    }
    __syncthreads();
    base[tid] = (h[tid] > 0) ? (sOff[tid] + atomicAdd(&bRes[tid], h[tid])) : 0;
    __syncthreads();
    #pragma unroll
    for (int j = 0; j < 16; ++j) {
        int e = e0 + j * 256 + tid;
        if (e < E) {
            int pos = base[bk[j]] + rk[j];
            ebuf[pos] = make_int2(row[e], __float_as_int(w[e]));
            edst[pos] = col[e];
        }
    }
}

__global__ __launch_bounds__(256) void
k_csrify(const int2* __restrict__ ebuf, const int* __restrict__ edst,
         const int* __restrict__ bcnt, int* __restrict__ off, float* __restrict__ dinv,
         int2* __restrict__ pairs, int N, int E, int bspan) {
    __shared__ int hist[256];
    __shared__ float degs[256];
    __shared__ int curl[256];
    __shared__ int wsum[4];
    __shared__ int sE0;
    const int tid = threadIdx.x, b = blockIdx.x;
    const int lane = tid & 63, wid = tid >> 6;
    const int base = b * bspan;
    const int lnodes = (N - base < bspan) ? (N - base) : bspan;
    if (b == 0 && tid == 0) off[N] = E;
    if (lnodes <= 0) return;
    hist[tid] = 0;
    degs[tid] = 0.f;
    const int bc = bcnt[tid];
    {
        int s = bc;
        #pragma unroll
        for (int d = 1; d < 64; d <<= 1) {
            int t = __shfl_up(s, d);
            if (lane >= d) s += t;
        }
        if (lane == 63) wsum[wid] = s;
        __syncthreads();
        int wb = 0;
        #pragma unroll
        for (int k = 0; k < 3; ++k) if (k < wid) wb += wsum[k];
        if (tid == b) sE0 = s - bc + wb;
    }
    __syncthreads();
    const int e0 = sE0, e1 = sE0 + bcnt[b];
    for (int e = e0 + tid; e < e1; e += 256) {
        int d = edst[e] - base;
        atomicAdd(&hist[d], 1);
        atomicAdd(&degs[d], __int_as_float(ebuf[e].y));
    }
    __syncthreads();
    int v = hist[tid];
    int s = v;
    #pragma unroll
    for (int d = 1; d < 64; d <<= 1) {
        int t = __shfl_up(s, d);
        if (lane >= d) s += t;
    }
    if (lane == 63) wsum[wid] = s;
    __syncthreads();
    int wb = 0;
    #pragma unroll
    for (int k = 0; k < 3; ++k) if (k < wid) wb += wsum[k];
    int excl = s - v + wb;
    if (tid < lnodes) {
        off[base + tid] = e0 + excl;
        dinv[base + tid] = rsqrtf(1.0f + degs[tid]);
    }
    curl[tid] = excl;
    __syncthreads();
    for (int e = e0 + tid; e < e1; e += 256) {
        int d = edst[e] - base;
        int p = atomicAdd(&curl[d], 1);
        pairs[e0 + p] = ebuf[e];
    }
}

// ================= MFMA GEMM body =================
// ofp8: output fp8 message table; else bf16.
template<int K, int XBF>
__device__ __forceinline__ void gemm_body(
    const void* __restrict__ Xv, const ushort* __restrict__ Wt,
    const float* __restrict__ bias, const float* __restrict__ dscale,
    void* __restrict__ outp, int N, int act, int ofp8, int bid) {
    constexpr int KP = K + 8;
    __shared__ ushort XT[64 * KP];
    __shared__ ushort WT[96 * KP];
    const int tid = threadIdx.x;
    const int n0  = bid * 64;

    #pragma unroll
    for (int i = tid; i < 96 * K / 8; i += 256) {
        const int c = i / (K / 8), q = i - c * (K / 8);
        uint4 v = reinterpret_cast<const uint4*>(Wt)[i];
        *reinterpret_cast<uint4*>(&WT[c * KP + q * 8]) = v;
    }
    if (XBF) {
        const ushort* X = (const ushort*)Xv;
        #pragma unroll
        for (int i = tid; i < 64 * K / 8; i += 256) {
            const int row = i / (K / 8), q = i - row * (K / 8);
            const int n = (n0 + row < N) ? (n0 + row) : (N - 1);
            uint4 v = *reinterpret_cast<const uint4*>(X + (size_t)n * K + q * 8);
            *reinterpret_cast<uint4*>(&XT[row * KP + q * 8]) = v;
        }
    } else {
        const float* X = (const float*)Xv;
        #pragma unroll
        for (int i = tid; i < 64 * K / 4; i += 256) {
            const int row = i / (K / 4), q = i - row * (K / 4);
            const int n = (n0 + row < N) ? (n0 + row) : (N - 1);
            float4 v = *reinterpret_cast<const float4*>(X + (size_t)n * K + q * 4);
            uint lo = (uint)f2bf(v.x) | ((uint)f2bf(v.y) << 16);
            uint hi = (uint)f2bf(v.z) | ((uint)f2bf(v.w) << 16);
            *reinterpret_cast<uint2*>(&XT[row * KP + q * 4]) = make_uint2(lo, hi);
        }
    }
    __syncthreads();

    const int lane = tid & 63;
    const int wv   = tid >> 6;
    const int r16  = lane & 15;
    const int kh   = lane >> 4;

    bf16x8 a[K / 32];
    const ushort* xbase = &XT[(wv * 16 + r16) * KP + kh * 8];
    #pragma unroll
    for (int ks = 0; ks < K / 32; ++ks)
        a[ks] = *reinterpret_cast<const bf16x8*>(xbase + ks * 32);

    f32x4 acc[6];
    #pragma unroll
    for (int ct = 0; ct < 6; ++ct) {
        f32x4 c = {0.f, 0.f, 0.f, 0.f};
        const ushort* wbase = &WT[(ct * 16 + r16) * KP + kh * 8];
        #pragma unroll
        for (int ks = 0; ks < K / 32; ++ks) {
            bf16x8 bfr = *reinterpret_cast<const bf16x8*>(wbase + ks * 32);
            c = __builtin_amdgcn_mfma_f32_16x16x32_bf16(a[ks], bfr, c, 0, 0, 0);
        }
        acc[ct] = c;
    }

    #pragma unroll
    for (int r = 0; r < 4; ++r) {
        const int n = n0 + wv * 16 + kh * 4 + r;
        if (n >= N) continue;
        const float ds = dscale ? dscale[n] : 1.f;
        #pragma unroll
        for (int ct = 0; ct < 6; ++ct) {
            const int col = ct * 16 + r16;
            float v = acc[ct][r] * ds;
            if (bias) v += bias[col];
            if (act) v = elu_f(v);
            if (ofp8) ((uchar*)outp)[(size_t)n * 96 + col] = f2fp8(v);
            else      ((ushort*)outp)[(size_t)n * 96 + col] = f2bf(v);
        }
    }
}

__global__ __launch_bounds__(256) void
k_gemm_mfma96(const ushort* __restrict__ X, const ushort* __restrict__ Wt,
              const float* __restrict__ dscale, void* __restrict__ outp, int N) {
    gemm_body<96, 1>(X, Wt, nullptr, dscale, outp, N, 0, 1, blockIdx.x);
}

__global__ __launch_bounds__(256) void
k_gemm_fin_dual(const float* __restrict__ X,
                const ushort* __restrict__ Wt1, const float* __restrict__ dscale1,
                void* __restrict__ out1,
                const ushort* __restrict__ Wt2, const float* __restrict__ bias2,
                void* __restrict__ out2, int N, int nHalf) {
    if ((int)blockIdx.x < nHalf)
        gemm_body<128, 0>(X, Wt1, nullptr, dscale1, out1, N, 0, 1, blockIdx.x);
    else
        gemm_body<128, 0>(X, Wt2, bias2, nullptr, out2, N, 1, 0, blockIdx.x - nHalf);
}

// ================= aggregation: fp8 messages, LDS pairs, depth-3 pipeline =================
// 6 threads/node, 16 feats each -> ONE uint4 (16 fp8) gather per edge per thread.
#define AGG_CAP 2048

__global__ __launch_bounds__(256) void
k_aggregate(const uchar* __restrict__ tmp, const int* __restrict__ off,
            const int2* __restrict__ pairs, const float* __restrict__ dinv,
            const float* __restrict__ bias, const ushort* __restrict__ addsrc,
            ushort* __restrict__ out, int N) {
    __shared__ int2 eP[AGG_CAP];
    __shared__ int sFlag;
    const int tid = threadIdx.x;
    const int t0  = blockIdx.x * 256;
    int n_first = t0 / 6;
    if (n_first >= N) return;
    int n_last = (t0 + 255) / 6;
    if (n_last >= N) n_last = N - 1;
    const int eb0 = off[n_first];
    const int eb1 = off[n_last + 1];
    const int tot = eb1 - eb0;
    if (tot <= AGG_CAP) {
        for (int i = tid; i < tot; i += 256) eP[i] = pairs[eb0 + i];
        if (tid == 0) sFlag = 1;
    } else if (tid == 0) sFlag = 0;
    __syncthreads();
    const bool lds = (sFlag != 0);

    const int n = (t0 + tid) / 6;
    if (n >= N) return;
    const int c = ((t0 + tid) % 6) * 16;
    const uchar* base = tmp + c;

    auto LOADP = [&](int e) -> int2 { return lds ? eP[e - eb0] : pairs[e]; };

    const float di = dinv[n];
    float f[16], acc[16];
    {
        uint4 sv = *reinterpret_cast<const uint4*>(base + (size_t)n * 96);
        fp8x16_unpack(sv, f);
        #pragma unroll
        for (int i = 0; i < 16; ++i) acc[i] = f[i];   // self-loop, raw weight 1
    }

    const int e0 = off[n];
    const int e1 = off[n + 1];
    const int m  = e1 - e0;

    int2 pA, pB, pC;
    uint4 hA, hB, hC;
    if (m > 0) { pA = LOADP(e0);     hA = *reinterpret_cast<const uint4*>(base + (size_t)pA.x * 96); }
    if (m > 1) { pB = LOADP(e0 + 1); hB = *reinterpret_cast<const uint4*>(base + (size_t)pB.x * 96); }
    if (m > 2) { pC = LOADP(e0 + 2); hC = *reinterpret_cast<const uint4*>(base + (size_t)pC.x * 96); }

    for (int e = e0 + 3; e < e1; ++e) {
        int2 pD = LOADP(e);
        uint4 hD = *reinterpret_cast<const uint4*>(base + (size_t)pD.x * 96);
        float w = __int_as_float(pA.y);
        fp8x16_unpack(hA, f);
        #pragma unroll
        for (int i = 0; i < 16; ++i) acc[i] = fmaf(w, f[i], acc[i]);
        pA = pB; hA = hB;
        pB = pC; hB = hC;
        pC = pD; hC = hD;
    }
    if (m > 0) {
        float w = __int_as_float(pA.y);
        fp8x16_unpack(hA, f);
        #pragma unroll
        for (int i = 0; i < 16; ++i) acc[i] = fmaf(w, f[i], acc[i]);
    }
    if (m > 1) {
        float w = __int_as_float(pB.y);
        fp8x16_unpack(hB, f);
        #pragma unroll
        for (int i = 0; i < 16; ++i) acc[i] = fmaf(w, f[i], acc[i]);
    }
    if (m > 2) {
        float w = __int_as_float(pC.y);
        fp8x16_unpack(hC, f);
        #pragma unroll
        for (int i = 0; i < 16; ++i) acc[i] = fmaf(w, f[i], acc[i]);
    }

    #pragma unroll
    for (int q = 0; q < 4; ++q) {
        float4 bv = *reinterpret_cast<const float4*>(bias + c + q * 4);
        acc[q * 4 + 0] = elu_f(fmaf(di, acc[q * 4 + 0], bv.x));
        acc[q * 4 + 1] = elu_f(fmaf(di, acc[q * 4 + 1], bv.y));
        acc[q * 4 + 2] = elu_f(fmaf(di, acc[q * 4 + 2], bv.z));
        acc[q * 4 + 3] = elu_f(fmaf(di, acc[q * 4 + 3], bv.w));
    }
    if (addsrc) {
        uint4 r0 = *reinterpret_cast<const uint4*>(addsrc + (size_t)n * 96 + c);
        uint4 r1 = *reinterpret_cast<const uint4*>(addsrc + (size_t)n * 96 + c + 8);
        bf8_unpack(r0, f);
        bf8_unpack(r1, f + 8);
        #pragma unroll
        for (int i = 0; i < 16; ++i) acc[i] += f[i];
    }
    ushort* op = out + (size_t)n * 96 + c;
    *reinterpret_cast<uint4*>(op)     = bf8_pack(acc);
    *reinterpret_cast<uint4*>(op + 8) = bf8_pack(acc + 8);
}

// ================= final: logits + log_softmax (lane = node, bf16 h) =================
__global__ __launch_bounds__(128) void
k_lin2_lsm(const ushort* __restrict__ h, const float* __restrict__ W2,
           const float* __restrict__ b2, float* __restrict__ out, int N) {
    __shared__ float hsT[96][128];
    const int tid = threadIdx.x;
    const int n0 = blockIdx.x * 128;
    const int nn = (N - n0 < 128) ? (N - n0) : 128;

    if (tid < nn) {
        const ushort* hr = h + (size_t)(n0 + tid) * 96;
        #pragma unroll
        for (int q = 0; q < 12; ++q) {
            uint4 v = *reinterpret_cast<const uint4*>(hr + q * 8);
            float f[8];
            bf8_unpack(v, f);
            #pragma unroll
            for (int j = 0; j < 8; ++j) hsT[q * 8 + j][tid] = f[j];
        }
    }
    __syncthreads();

    float acc[40];
    #pragma unroll
    for (int c = 0; c < 40; ++c) acc[c] = b2[c];
    for (int k = 0; k < 96; ++k) {
        const float hv = hsT[k][tid];
        const float* wr = W2 + k * 40;
        #pragma unroll
        for (int c = 0; c < 40; ++c) acc[c] = fmaf(hv, wr[c], acc[c]);
    }

    float m = acc[0];
    #pragma unroll
    for (int c = 1; c < 40; ++c) m = fmaxf(m, acc[c]);
    float s = 0.f;
    #pragma unroll
    for (int c = 0; c < 40; ++c) s += expf(acc[c] - m);
    const float lse = m + logf(s);

    if (tid < nn) {
        float* op = out + (size_t)(n0 + tid) * 40;
        #pragma unroll
        for (int q = 0; q < 10; ++q) {
            float4 v = make_float4(acc[q * 4 + 0] - lse, acc[q * 4 + 1] - lse,
                                   acc[q * 4 + 2] - lse, acc[q * 4 + 3] - lse);
            *reinterpret_cast<float4*>(op + q * 4) = v;
        }
    }
}

// ================= launch =================

extern "C" void kernel_launch(void* const* d_in, const int* in_sizes, int n_in,
                              void* d_out, int out_size, void* d_ws, size_t ws_size,
                              hipStream_t stream) {
    const float* x   = (const float*)d_in[0];
    const int*   ei  = (const int*)d_in[1];
    const float* ew  = (const float*)d_in[2];
    const float* Wc1 = (const float*)d_in[3];
    const float* bc1 = (const float*)d_in[4];
    const float* Wc2 = (const float*)d_in[5];
    const float* bc2 = (const float*)d_in[6];
    const float* Wc3 = (const float*)d_in[7];
    const float* bc3 = (const float*)d_in[8];
    const float* Wl1 = (const float*)d_in[9];
    const float* bl1 = (const float*)d_in[10];
    const float* Wl2 = (const float*)d_in[11];
    const float* bl2 = (const float*)d_in[12];

    const int FIN = 128, HID = 96;
    const int N = in_sizes[0] / FIN;
    const int E = in_sizes[2];
    const int* row = ei;
    const int* col = ei + E;
    const int bspan = (N + 255) / 256;

    char* ws = (char*)d_ws;
    size_t o = 0;
    auto alloc = [&](size_t bytes) -> void* {
        void* p = ws + o;
        o += (bytes + 255) & ~(size_t)255;
        return p;
    };
    float*  dinv   = (float*)alloc((size_t)N * 4);
    int*    off    = (int*)  alloc((size_t)(N + 1) * 4);
    int*    bmem   = (int*)  alloc(512 * 4);             // bcnt[256] + bRes[256]
    int*    bcnt   = bmem;
    int*    bRes   = bmem + 256;
    int2*   pairs  = (int2*) alloc((size_t)E * 8);
    uchar*  M1     = (uchar*)alloc((size_t)N * HID);     // fp8 message table
    uchar*  M2     = (uchar*)alloc((size_t)N * HID);
    ushort* Bb     = (ushort*)alloc((size_t)N * HID * 2);  // residual x1 (bf16)
    ushort* Cb     = (ushort*)alloc((size_t)N * HID * 2);  // running h (bf16)
    ushort* Wt_c1  = (ushort*)alloc(96 * 128 * 2);
    ushort* Wt_l1  = (ushort*)alloc(96 * 128 * 2);
    ushort* Wt_c2  = (ushort*)alloc(96 * 96 * 2);
    ushort* Wt_c3  = (ushort*)alloc(96 * 96 * 2);
    int2*   ebuf   = (int2*) alloc((size_t)E * 8);       // prep scratch
    int*    edst   = (int*)  alloc((size_t)E * 4);

    const int gBkt  = (E + 4095) / 4096;
    const int nGemm = (N + 63) / 64;
    const int nAgg  = (N * 6 + 255) / 256;

    // zero bucket counters, then weight-prep || bucket-count in one dispatch
    hipMemsetAsync(bmem, 0, 512 * 4, stream);
    k_wprep_count<<<168 + gBkt, 256, 0, stream>>>(Wc1, Wl1, Wc2, Wc3,
                                                  Wt_c1, Wt_l1, Wt_c2, Wt_c3,
                                                  col, bcnt, E, bspan, 168);

    // bucketed CSR build
    k_bscatter<<<gBkt, 256, 0, stream>>>(row, col, ew, bcnt, bRes, ebuf, edst, E, bspan);
    k_csrify<<<256, 256, 0, stream>>>(ebuf, edst, bcnt, off, dinv, pairs, N, E, bspan);

    // conv1 GEMM (dinv-scaled fp8 messages) + lin1 GEMM (bf16 h), one dispatch
    k_gemm_fin_dual<<<2 * nGemm, 256, 0, stream>>>(x, Wt_c1, dinv, M1,
                                                   Wt_l1, bl1, Cb, N, nGemm);

    // conv1 aggregate -> Bb (residual)
    k_aggregate<<<nAgg, 256, 0, stream>>>(M1, off, pairs, dinv, bc1, nullptr, Bb, N);

    // conv2
    k_gemm_mfma96<<<nGemm, 256, 0, stream>>>(Cb, Wt_c2, dinv, M2, N);
    k_aggregate<<<nAgg, 256, 0, stream>>>(M2, off, pairs, dinv, bc2, nullptr, Cb, N);

    // conv3 (+residual Bb)
    k_gemm_mfma96<<<nGemm, 256, 0, stream>>>(Cb, Wt_c3, dinv, M1, N);
    k_aggregate<<<nAgg, 256, 0, stream>>>(M1, off, pairs, dinv, bc3, Bb, Cb, N);

    // lin2 + log_softmax
    k_lin2_lsm<<<(N + 127) / 128, 128, 0, stream>>>(Cb, Wl2, bl2, (float*)d_out, N);
}